// Round 5
// baseline (508.406 us; speedup 1.0000x reference)
//
#include <hip/hip_runtime.h>
#include <cstdint>
#include <cstddef>

#define NN 100000
#define NE 1600000
#define NBB 391   // dst buckets of 256 nodes: ceil(100000/256)

typedef short short8 __attribute__((ext_vector_type(8)));
typedef float floatx4 __attribute__((ext_vector_type(4)));
typedef unsigned short u16;
typedef uint32_t u32;

// ---------------- graph preprocessing (bucketed, atomic-light) ----------------

static __global__ void k_zero(int* __restrict__ gh) {
    int i = threadIdx.x;
    if (i < NBB + 1) gh[i] = 0;
}

// histogram of dst>>8 ; 1024 thr x 4 edges/block -> 391 global atomics/block
static __global__ __launch_bounds__(1024) void k_bhist(const int* __restrict__ dst,
                                                       int* __restrict__ gh) {
    __shared__ int h[NBB + 1];
    int t = threadIdx.x;
    for (int i = t; i < NBB; i += 1024) h[i] = 0;
    __syncthreads();
    int e0 = blockIdx.x * 4096;
#pragma unroll
    for (int j = 0; j < 4; j++) {
        int e = e0 + j * 1024 + t;
        if (e < NE) atomicAdd(&h[dst[e] >> 8], 1);
    }
    __syncthreads();
    for (int i = t; i < NBB; i += 1024)
        if (h[i]) atomicAdd(&gh[i], h[i]);
}

// parallel single-block scan over NBB=391 bucket counts
static __global__ void k_bscan(const int* __restrict__ gh, int* __restrict__ gbase,
                               int* __restrict__ gcur) {
    __shared__ int sd[512];
    int t = threadIdx.x;
    int v = (t < NBB) ? gh[t] : 0;
    sd[t] = v;
    __syncthreads();
    for (int off = 1; off < 512; off <<= 1) {
        int x = (t >= off) ? sd[t - off] : 0;
        __syncthreads();
        sd[t] += x;
        __syncthreads();
    }
    int excl = (t > 0) ? sd[t - 1] : 0;
    if (t < NBB) {
        gbase[t] = excl;
        gcur[t] = excl;
    }
    if (t == NBB) gbase[NBB] = excl;  // == NE
}

// scatter edges into bucket-ordered staging (int2 = src,dst)
static __global__ __launch_bounds__(1024) void k_bscatter(const int* __restrict__ src,
                                                          const int* __restrict__ dst,
                                                          int* __restrict__ gcur,
                                                          int2* __restrict__ staging) {
    __shared__ int h[NBB + 1];
    __shared__ int base[NBB + 1];
    int t = threadIdx.x;
    for (int i = t; i < NBB; i += 1024) h[i] = 0;
    __syncthreads();
    int e0 = blockIdx.x * 4096;
    int b[4], l[4], sv[4], dv[4];
#pragma unroll
    for (int j = 0; j < 4; j++) {
        int e = e0 + j * 1024 + t;
        b[j] = -1;
        if (e < NE) {
            sv[j] = src[e];
            dv[j] = dst[e];
            b[j] = dv[j] >> 8;
            l[j] = atomicAdd(&h[b[j]], 1);
        }
    }
    __syncthreads();
    for (int i = t; i < NBB; i += 1024)
        if (h[i]) base[i] = atomicAdd(&gcur[i], h[i]);
    __syncthreads();
#pragma unroll
    for (int j = 0; j < 4; j++)
        if (b[j] >= 0) staging[base[b[j]] + l[j]] = make_int2(sv[j], dv[j]);
}

// per-bucket degree count via LDS -> deg/dinv written coalesced, no global atomics
static __global__ __launch_bounds__(1024) void k_blocal(const int2* __restrict__ staging,
                                                        const int* __restrict__ gbase,
                                                        int* __restrict__ deg,
                                                        float* __restrict__ dinv) {
    __shared__ int cnt[256];
    int b = blockIdx.x;
    int t = threadIdx.x;
    if (t < 256) cnt[t] = 0;
    __syncthreads();
    int end = gbase[b + 1];
    for (int i = gbase[b] + t; i < end; i += 1024)
        atomicAdd(&cnt[staging[i].y & 255], 1);
    __syncthreads();
    if (t < 256) {
        int node = (b << 8) + t;
        if (node < NN) {
            int d = cnt[t] + 1;  // +1 self loop
            deg[node] = d;
            dinv[node] = rsqrtf((float)d);
        }
    }
}

// exclusive scan of (deg[i]-1) -> row_ptr, chunk=1024/block
static __global__ void k_scan1(const int* __restrict__ deg, int* __restrict__ row_ptr,
                               int* __restrict__ bsums) {
    __shared__ int sd[256];
    int t = threadIdx.x;
    int base = blockIdx.x * 1024;
    int v[4];
    int s = 0;
#pragma unroll
    for (int j = 0; j < 4; j++) {
        int i = base + t * 4 + j;
        int c = (i < NN) ? (deg[i] - 1) : 0;
        v[j] = s;
        s += c;
    }
    sd[t] = s;
    __syncthreads();
    for (int off = 1; off < 256; off <<= 1) {
        int x = (t >= off) ? sd[t - off] : 0;
        __syncthreads();
        sd[t] += x;
        __syncthreads();
    }
    int excl = (t > 0) ? sd[t - 1] : 0;
#pragma unroll
    for (int j = 0; j < 4; j++) {
        int i = base + t * 4 + j;
        if (i < NN) row_ptr[i] = excl + v[j];
    }
    if (t == 255) bsums[blockIdx.x] = sd[255];
}

// parallel single-block scan over nb<=128 block sums
static __global__ void k_scan2(int* __restrict__ bsums, int nb) {
    __shared__ int sd[128];
    int t = threadIdx.x;
    int v = (t < nb) ? bsums[t] : 0;
    sd[t] = v;
    __syncthreads();
    for (int off = 1; off < 128; off <<= 1) {
        int x = (t >= off) ? sd[t - off] : 0;
        __syncthreads();
        sd[t] += x;
        __syncthreads();
    }
    if (t < nb) bsums[t] = sd[t] - v;  // exclusive
}

static __global__ void k_scan3(int* __restrict__ row_ptr, const int* __restrict__ bsums) {
    int i = blockIdx.x * 256 + threadIdx.x;
    if (i < NN) {
        row_ptr[i] += bsums[i >> 10];
    } else if (i == NN) {
        row_ptr[NN] = NE;
    }
}

// per-bucket CSR fill: ranks via LDS atomics
static __global__ __launch_bounds__(1024) void k_bfill(const int2* __restrict__ staging,
                                                       const int* __restrict__ gbase,
                                                       const int* __restrict__ row_ptr,
                                                       int* __restrict__ csr_src) {
    __shared__ int cnt[256];
    int b = blockIdx.x;
    int t = threadIdx.x;
    if (t < 256) cnt[t] = 0;
    __syncthreads();
    int end = gbase[b + 1];
    for (int i = gbase[b] + t; i < end; i += 1024) {
        int2 ed = staging[i];
        int r = atomicAdd(&cnt[ed.y & 255], 1);
        csr_src[row_ptr[ed.y] + r] = ed.x;
    }
}

// ---------------- bf16 helpers ----------------
__device__ __forceinline__ void split_bf16(float f, short& hi, short& lo) {
    union { float f; uint32_t u; } x;
    x.f = f;
    uint32_t uh = x.u + 0x7FFFu + ((x.u >> 16) & 1u);
    hi = (short)(uh >> 16);
    union { uint32_t u; float f; } hf;
    hf.u = (uh >> 16) << 16;
    float r = f - hf.f;
    union { float f; uint32_t u; } y;
    y.f = r;
    uint32_t ul = y.u + 0x7FFFu + ((y.u >> 16) & 1u);
    lo = (short)(ul >> 16);
}

__device__ __forceinline__ u16 f2bf(float f) {  // RNE (== hi part of split)
    union { float f; uint32_t u; } x;
    x.f = f;
    uint32_t r = x.u + 0x7FFFu + ((x.u >> 16) & 1u);
    return (u16)(r >> 16);
}

__device__ __forceinline__ float bf2f(u16 h) {
    union { uint32_t u; float f; } x;
    x.u = ((uint32_t)h) << 16;
    return x.f;
}

// accumulate a packed pair of bf16 channels (low half -> a0, high half -> a1)
__device__ __forceinline__ void acc2(uint32_t u, float& a0, float& a1) {
    union { uint32_t u; float f; } lo, hi;
    lo.u = u << 16;
    hi.u = u & 0xFFFF0000u;
    a0 += lo.f;
    a1 += hi.f;
}

// ---------------- weight pre-split into MFMA B-fragment layout ----------------
struct WDesc {
    const float* W;
    short* fh;
    short* fl;
    int din, dout, transb, base, total;  // base/total in short8 groups
};
struct WPrepArgs { WDesc d[6]; };

static __global__ void k_wprep(WPrepArgs args) {
    int tid = blockIdx.x * 256 + threadIdx.x;
#pragma unroll
    for (int i = 0; i < 6; i++) {
        const WDesc& D = args.d[i];
        if (tid >= D.base && tid < D.base + D.total) {
            int local = tid - D.base;
            int lane = local & 63;
            int rest = local >> 6;
            int kst = D.din >> 5;
            int ks = rest % kst;
            int ntile = rest / kst;
            int n = ntile * 16 + (lane & 15);
            int k0 = ks * 32 + (lane >> 4) * 8;
#pragma unroll
            for (int j = 0; j < 8; j++) {
                int k = k0 + j;
                float v = D.transb ? D.W[(size_t)n * D.din + k]
                                   : D.W[(size_t)k * D.dout + n];
                short h, l;
                split_bf16(v, h, l);
                D.fh[(size_t)local * 8 + j] = h;
                D.fl[(size_t)local * 8 + j] = l;
            }
        }
    }
}

// ---------------- MFMA GEMM: LDS-free, B in registers ------------------------
// Round-4 lesson: packed u32 (hi|lo<<16) activations cost ~16 VALU unpack ops
// per 8 K-elems per stage in the K-loop (VALU/latency-bound per round-1 PMC).
// Activations now live in TWO u16 PLANES (hi plane, lo plane at +NN*D): the
// A-fragment load is two short8 loads in MFMA element order, ZERO unpack VALU.
// hi plane == RNE bf16 of the value, so it doubles as the agg gather payload.
// AMODE: 1 = fp32 input, on-the-fly RNE, 2 MFMAs/K-step (G1 only)
//        2 = two-plane split input (3 MFMAs, lossless vs fp32 to 2^-16)
// OMODE: 0 = fp32 out, 1 = hi plane only (payload), 2 = hi+lo planes
template <int DIN, int DOUT, int MT, int AMODE, int OMODE, bool RESID, bool BIAS, bool SCALE>
__global__ __launch_bounds__(256) void k_mgemm(const void* __restrict__ Av,
                                               const short* __restrict__ fh,
                                               const short* __restrict__ fl,
                                               const float* __restrict__ bias,
                                               const float* __restrict__ dinv,
                                               void* __restrict__ C) {
    static_assert(!RESID || DIN == DOUT, "residual needs square");
    constexpr int KST = DIN / 32;
    constexpr int NTW = DOUT / 64;  // N-tiles per wave (block: 4 waves = DOUT/16 tiles)
    const int t = threadIdx.x;
    const int wave = t >> 6;
    const int lane = t & 63;
    const int r16 = lane & 15;
    const int kq = lane >> 4;

    const float* Af = (const float*)Av;
    const u16*   Ah = (const u16*)Av;
    const u16*   Al = Ah + (size_t)NN * DIN;

    short8 bh[NTW][KST], bl[NTW][KST];
#pragma unroll
    for (int nt = 0; nt < NTW; nt++) {
        int ntile = wave * NTW + nt;
#pragma unroll
        for (int ks = 0; ks < KST; ks++) {
            size_t o = ((size_t)(ntile * KST + ks) * 64 + lane) * 8;
            bh[nt][ks] = *(const short8*)(fh + o);
            bl[nt][ks] = *(const short8*)(fl + o);
        }
    }

    const int m0b = blockIdx.x * (MT * 16);
#pragma unroll 1
    for (int mt = 0; mt < MT; mt++) {
        const int m0 = m0b + mt * 16;
        if (m0 >= NN) break;
        const int ra = min(m0 + r16, NN - 1);  // clamp; stores guarded

        floatx4 acc[NTW];
#pragma unroll
        for (int nt = 0; nt < NTW; nt++) acc[nt] = (floatx4){0.f, 0.f, 0.f, 0.f};

        if constexpr (AMODE == 1) {
            const float* Ap = Af + (size_t)ra * DIN + kq * 8;
#pragma unroll
            for (int ks = 0; ks < KST; ks++) {
                float4 f0 = *(const float4*)(Ap + ks * 32);
                float4 f1 = *(const float4*)(Ap + ks * 32 + 4);
                float fe[8] = {f0.x, f0.y, f0.z, f0.w, f1.x, f1.y, f1.z, f1.w};
                short8 ah;
#pragma unroll
                for (int j = 0; j < 8; j++) ah[j] = (short)f2bf(fe[j]);
#pragma unroll
                for (int nt = 0; nt < NTW; nt++) {
                    acc[nt] = __builtin_amdgcn_mfma_f32_16x16x32_bf16(ah, bh[nt][ks], acc[nt], 0, 0, 0);
                    acc[nt] = __builtin_amdgcn_mfma_f32_16x16x32_bf16(ah, bl[nt][ks], acc[nt], 0, 0, 0);
                }
            }
        } else {
            const u16* Aph = Ah + (size_t)ra * DIN + kq * 8;
            const u16* Apl = Al + (size_t)ra * DIN + kq * 8;
#pragma unroll
            for (int ks = 0; ks < KST; ks++) {
                short8 ah = *(const short8*)(Aph + ks * 32);
                short8 al = *(const short8*)(Apl + ks * 32);
#pragma unroll
                for (int nt = 0; nt < NTW; nt++) {
                    acc[nt] = __builtin_amdgcn_mfma_f32_16x16x32_bf16(ah, bh[nt][ks], acc[nt], 0, 0, 0);
                    acc[nt] = __builtin_amdgcn_mfma_f32_16x16x32_bf16(ah, bl[nt][ks], acc[nt], 0, 0, 0);
                    acc[nt] = __builtin_amdgcn_mfma_f32_16x16x32_bf16(al, bh[nt][ks], acc[nt], 0, 0, 0);
                }
            }
        }

        // C/D layout: row = kq*4 + r, col = r16 (verified)
#pragma unroll
        for (int nt = 0; nt < NTW; nt++) {
            int col = (wave * NTW + nt) * 16 + r16;
#pragma unroll
            for (int r = 0; r < 4; r++) {
                int row = m0 + kq * 4 + r;
                if (row < NN) {
                    float v = acc[nt][r];
                    if constexpr (RESID) {
                        size_t ri = (size_t)row * DIN + col;
                        v = fmaxf(v + bf2f(Ah[ri]) + bf2f(Al[ri]), 0.f);
                    }
                    if constexpr (BIAS) v = fmaxf(v + bias[col], 0.f);
                    if constexpr (SCALE) v *= dinv[row];
                    size_t oi = (size_t)row * DOUT + col;
                    if constexpr (OMODE == 0) {
                        ((float*)C)[oi] = v;
                    } else if constexpr (OMODE == 1) {
                        ((u16*)C)[oi] = f2bf(v);
                    } else {
                        short h, l;
                        split_bf16(v, h, l);
                        ((u16*)C)[oi] = (u16)h;
                        ((u16*)C)[(size_t)NN * DOUT + oi] = (u16)l;
                    }
                }
            }
        }
    }
}

// ---------------- fused GEMM pair: C = ep2( ep1(A@W1') @ W2' ) ---------------
// Stages the 16xDMID intermediate through LDS as two u16 planes (split-bf16,
// numerically identical to the global two-plane path). Row stride DMID+8 u16
// = 272B (for DMID=128): 16B-aligned, rows advance 4 banks -> reads at the
// 2-lanes/bank wave64 minimum. A-frag from LDS = two short8 ds_reads, no unpack.
template <int DIN, int DMID, int DOUT, int MT, bool RESID1, bool BIAS1,
          bool SCALE2, bool RESID2, int OMODE2>
__global__ __launch_bounds__(256) void k_mfused(const u16* __restrict__ Ahp,
                                                const short* __restrict__ f1h,
                                                const short* __restrict__ f1l,
                                                const short* __restrict__ f2h,
                                                const short* __restrict__ f2l,
                                                const float* __restrict__ bias1,
                                                const float* __restrict__ dinv,
                                                void* __restrict__ C) {
    static_assert(!RESID1 || DIN == DMID, "resid1 needs square stage1");
    static_assert(!RESID2 || DMID == DOUT, "resid2 needs square stage2");
    constexpr int KST1 = DIN / 32;
    constexpr int NTW1 = DMID / 64;
    constexpr int KST2 = DMID / 32;
    constexpr int NTW2 = DOUT / 64;
    constexpr int LDW = DMID + 8;  // u16 stride: 16B-aligned rows, 4-bank skew
    __shared__ u16 ldsh[16][LDW];
    __shared__ u16 ldsl[16][LDW];

    const u16* Alp = Ahp + (size_t)NN * DIN;

    const int t = threadIdx.x;
    const int wave = t >> 6;
    const int lane = t & 63;
    const int r16 = lane & 15;
    const int kq = lane >> 4;

    short8 b1h[NTW1][KST1], b1l[NTW1][KST1];
#pragma unroll
    for (int nt = 0; nt < NTW1; nt++) {
        int ntile = wave * NTW1 + nt;
#pragma unroll
        for (int ks = 0; ks < KST1; ks++) {
            size_t o = ((size_t)(ntile * KST1 + ks) * 64 + lane) * 8;
            b1h[nt][ks] = *(const short8*)(f1h + o);
            b1l[nt][ks] = *(const short8*)(f1l + o);
        }
    }
    short8 b2h[NTW2][KST2], b2l[NTW2][KST2];
#pragma unroll
    for (int nt = 0; nt < NTW2; nt++) {
        int ntile = wave * NTW2 + nt;
#pragma unroll
        for (int ks = 0; ks < KST2; ks++) {
            size_t o = ((size_t)(ntile * KST2 + ks) * 64 + lane) * 8;
            b2h[nt][ks] = *(const short8*)(f2h + o);
            b2l[nt][ks] = *(const short8*)(f2l + o);
        }
    }

    const int m0b = blockIdx.x * (MT * 16);
#pragma unroll 1
    for (int mt = 0; mt < MT; mt++) {
        const int m0 = m0b + mt * 16;
        if (m0 >= NN) break;
        const int ra = min(m0 + r16, NN - 1);

        // ---- stage 1: acc1 = A @ W1' ----
        floatx4 acc1[NTW1];
#pragma unroll
        for (int nt = 0; nt < NTW1; nt++) acc1[nt] = (floatx4){0.f, 0.f, 0.f, 0.f};
        {
            const u16* Aph = Ahp + (size_t)ra * DIN + kq * 8;
            const u16* Apl = Alp + (size_t)ra * DIN + kq * 8;
#pragma unroll
            for (int ks = 0; ks < KST1; ks++) {
                short8 ah = *(const short8*)(Aph + ks * 32);
                short8 al = *(const short8*)(Apl + ks * 32);
#pragma unroll
                for (int nt = 0; nt < NTW1; nt++) {
                    acc1[nt] = __builtin_amdgcn_mfma_f32_16x16x32_bf16(ah, b1h[nt][ks], acc1[nt], 0, 0, 0);
                    acc1[nt] = __builtin_amdgcn_mfma_f32_16x16x32_bf16(ah, b1l[nt][ks], acc1[nt], 0, 0, 0);
                    acc1[nt] = __builtin_amdgcn_mfma_f32_16x16x32_bf16(al, b1h[nt][ks], acc1[nt], 0, 0, 0);
                }
            }
        }
        // ---- epilogue 1 -> LDS planes (split) ----
#pragma unroll
        for (int nt = 0; nt < NTW1; nt++) {
            int col = (wave * NTW1 + nt) * 16 + r16;
#pragma unroll
            for (int r = 0; r < 4; r++) {
                int row = m0 + kq * 4 + r;
                float v = acc1[nt][r];
                if constexpr (RESID1) {
                    if (row < NN) {
                        size_t ri = (size_t)row * DIN + col;
                        v = fmaxf(v + bf2f(Ahp[ri]) + bf2f(Alp[ri]), 0.f);
                    }
                }
                if constexpr (BIAS1) v = fmaxf(v + bias1[col], 0.f);
                short h, l;
                split_bf16(v, h, l);
                ldsh[kq * 4 + r][col] = (u16)h;
                ldsl[kq * 4 + r][col] = (u16)l;
            }
        }
        __syncthreads();

        // ---- stage 2: acc2 = mid @ W2' (A-frags from LDS planes) ----
        floatx4 acc2[NTW2];
#pragma unroll
        for (int nt = 0; nt < NTW2; nt++) acc2[nt] = (floatx4){0.f, 0.f, 0.f, 0.f};
#pragma unroll
        for (int ks = 0; ks < KST2; ks++) {
            short8 ah = *(const short8*)&ldsh[r16][ks * 32 + kq * 8];
            short8 al = *(const short8*)&ldsl[r16][ks * 32 + kq * 8];
#pragma unroll
            for (int nt = 0; nt < NTW2; nt++) {
                acc2[nt] = __builtin_amdgcn_mfma_f32_16x16x32_bf16(ah, b2h[nt][ks], acc2[nt], 0, 0, 0);
                acc2[nt] = __builtin_amdgcn_mfma_f32_16x16x32_bf16(ah, b2l[nt][ks], acc2[nt], 0, 0, 0);
                acc2[nt] = __builtin_amdgcn_mfma_f32_16x16x32_bf16(al, b2h[nt][ks], acc2[nt], 0, 0, 0);
            }
        }

        // ---- epilogue 2 -> C ----
#pragma unroll
        for (int nt = 0; nt < NTW2; nt++) {
            int col = (wave * NTW2 + nt) * 16 + r16;
#pragma unroll
            for (int r = 0; r < 4; r++) {
                int row = m0 + kq * 4 + r;
                if (row < NN) {
                    float v = acc2[nt][r];
                    if constexpr (RESID2)
                        v = fmaxf(v + bf2f(ldsh[kq * 4 + r][col]) + bf2f(ldsl[kq * 4 + r][col]), 0.f);
                    if constexpr (SCALE2) v *= dinv[row];
                    size_t oi = (size_t)row * DOUT + col;
                    if constexpr (OMODE2 == 0) {
                        ((float*)C)[oi] = v;
                    } else if constexpr (OMODE2 == 1) {
                        ((u16*)C)[oi] = f2bf(v);
                    } else {
                        short h, l;
                        split_bf16(v, h, l);
                        ((u16*)C)[oi] = (u16)h;
                        ((u16*)C)[(size_t)NN * DOUT + oi] = (u16)l;
                    }
                }
            }
        }
        __syncthreads();  // protect LDS before next mt overwrites
    }
}

// ---------------- GCN aggregation: bf16 gather payload, fp32 accumulate -------
// Output written as two u16 planes (hi = RNE bf16, lo = residual) for the
// consumer GEMM. D=64: split-wave scheme — halves process alternating edges,
// each lane reads a u32 (2 ch) so gather transactions are full 128B rows
// (was 2B/lane half-width); one shfl_xor(32) combines halves.
template <int D, bool BIAS_RELU>
__global__ __launch_bounds__(256) void k_agg(const u16* __restrict__ hs,
                                             const float* __restrict__ dinv,
                                             const int* __restrict__ row_ptr,
                                             const int* __restrict__ csr_src,
                                             const float* __restrict__ bias,
                                             u16* __restrict__ outh) {
    u16* outl = outh + (size_t)NN * D;
    int node = blockIdx.x * 4 + (threadIdx.x >> 6);
    int lane = threadIdx.x & 63;
    if (node >= NN) return;

    if constexpr (D == 128) {
        const int off = lane * 2;
        float a0 = 0.f, a1 = 0.f;
        {
            uint32_t u = ((const uint32_t*)(hs + (size_t)node * D))[lane];
            acc2(u, a0, a1);
        }
        int e = row_ptr[node];
        const int end = row_ptr[node + 1];
        for (; e + 8 <= end; e += 8) {
            int s[8];
#pragma unroll
            for (int i = 0; i < 8; i++) s[i] = csr_src[e + i];
            uint32_t v[8];
#pragma unroll
            for (int i = 0; i < 8; i++) v[i] = ((const uint32_t*)(hs + (size_t)s[i] * D))[lane];
#pragma unroll
            for (int i = 0; i < 8; i++) acc2(v[i], a0, a1);
        }
        for (; e + 4 <= end; e += 4) {
            int s[4];
#pragma unroll
            for (int i = 0; i < 4; i++) s[i] = csr_src[e + i];
            uint32_t v[4];
#pragma unroll
            for (int i = 0; i < 4; i++) v[i] = ((const uint32_t*)(hs + (size_t)s[i] * D))[lane];
#pragma unroll
            for (int i = 0; i < 4; i++) acc2(v[i], a0, a1);
        }
        for (; e < end; e++) {
            int s = csr_src[e];
            uint32_t u = ((const uint32_t*)(hs + (size_t)s * D))[lane];
            acc2(u, a0, a1);
        }
        const float di = dinv[node];
        a0 *= di;
        a1 *= di;
        if constexpr (BIAS_RELU) {
            a0 = fmaxf(a0 + bias[off], 0.f);
            a1 = fmaxf(a1 + bias[off + 1], 0.f);
        }
        short h0, l0, h1, l1;
        split_bf16(a0, h0, l0);
        split_bf16(a1, h1, l1);
        ushort2 wh, wl;
        wh.x = (u16)h0; wh.y = (u16)h1;
        wl.x = (u16)l0; wl.y = (u16)l1;
        *(ushort2*)(outh + (size_t)node * D + off) = wh;
        *(ushort2*)(outl + (size_t)node * D + off) = wl;
    } else {
        // D == 64: halves handle alternating edges; lane owns ch {2*l32, 2*l32+1}
        const int half = lane >> 5;
        const int l32 = lane & 31;
        float a0 = 0.f, a1 = 0.f;
        if (half == 0) {
            uint32_t u = ((const uint32_t*)(hs + (size_t)node * D))[l32];
            acc2(u, a0, a1);
        }
        int e = row_ptr[node];
        const int end = row_ptr[node + 1];
        for (; e + 8 <= end; e += 8) {
            int s[4];
#pragma unroll
            for (int i = 0; i < 4; i++) s[i] = csr_src[e + half + 2 * i];
            uint32_t v[4];
#pragma unroll
            for (int i = 0; i < 4; i++) v[i] = ((const uint32_t*)(hs + (size_t)s[i] * D))[l32];
#pragma unroll
            for (int i = 0; i < 4; i++) acc2(v[i], a0, a1);
        }
        for (; e + 2 <= end; e += 2) {
            int s = csr_src[e + half];
            uint32_t u = ((const uint32_t*)(hs + (size_t)s * D))[l32];
            acc2(u, a0, a1);
        }
        if (e < end && half == 0) {
            int s = csr_src[e];
            uint32_t u = ((const uint32_t*)(hs + (size_t)s * D))[l32];
            acc2(u, a0, a1);
        }
        a0 += __shfl_xor(a0, 32, 64);
        a1 += __shfl_xor(a1, 32, 64);
        if (half == 0) {
            const int off = l32 * 2;
            const float di = dinv[node];
            a0 *= di;
            a1 *= di;
            if constexpr (BIAS_RELU) {
                a0 = fmaxf(a0 + bias[off], 0.f);
                a1 = fmaxf(a1 + bias[off + 1], 0.f);
            }
            short h0, l0, h1, l1;
            split_bf16(a0, h0, l0);
            split_bf16(a1, h1, l1);
            ushort2 wh, wl;
            wh.x = (u16)h0; wh.y = (u16)h1;
            wl.x = (u16)l0; wl.y = (u16)l1;
            *(ushort2*)(outh + (size_t)node * D + off) = wh;
            *(ushort2*)(outl + (size_t)node * D + off) = wl;
        }
    }
}

// ---------------- launch ----------------

extern "C" void kernel_launch(void* const* d_in, const int* in_sizes, int n_in,
                              void* d_out, int out_size, void* d_ws, size_t ws_size,
                              hipStream_t stream) {
    const float* x   = (const float*)d_in[0];
    const int*   ei  = (const int*)d_in[1];
    const float* g1w = (const float*)d_in[2];
    const float* g1b = (const float*)d_in[3];
    const float* f2w = (const float*)d_in[4];
    const float* g3w = (const float*)d_in[5];
    const float* g3b = (const float*)d_in[6];
    const float* f4w = (const float*)d_in[7];
    const float* g5w = (const float*)d_in[8];
    const float* g5b = (const float*)d_in[9];
    const float* f6w = (const float*)d_in[10];
    float* out = (float*)d_out;

    const int* src = ei;       // edge_index[0]
    const int* dst = ei + NE;  // edge_index[1]

    char* p = (char*)d_ws;
    auto alloc = [&](size_t bytes) -> void* {
        void* r = (void*)p;
        p += (bytes + 255) & ~(size_t)255;
        return r;
    };
    int*   deg     = (int*)alloc(NN * 4);
    float* dinv    = (float*)alloc(NN * 4);
    int*   row_ptr = (int*)alloc((NN + 1) * 4);
    int*   bsums   = (int*)alloc(512);
    int*   gh      = (int*)alloc((NBB + 1) * 4);
    int*   gbase   = (int*)alloc((NBB + 1) * 4);
    int*   gcur    = (int*)alloc((NBB + 1) * 4);
    int*   csr     = (int*)alloc(NE * 4);
    short* wfh     = (short*)alloc(69632 * 2);
    short* wfl     = (short*)alloc(69632 * 2);
    // bufA/bufB: 4B/elem budget = room for hi+lo u16 planes at D=128
    char* bufA = (char*)alloc((size_t)NN * 128 * 4);
    char* bufB = (char*)alloc((size_t)NN * 128 * 4);
    // edge staging (12.8 MB) aliases bufB: fully consumed by k_blocal/k_bfill
    // before agg1 writes bufB (stream-ordered).
    int2* staging  = (int2*)bufB;

    const int gE4 = (NE + 4095) / 4096;      // 391
    const int gS  = (NN + 1023) / 1024;      // 98
    const int gN1 = (NN + 1 + 255) / 256;
    const int gA  = NN / 4;                  // 25000
    const int gM  = (NN + 31) / 32;          // 3125 (MT=2: 32 rows/block, exact)

    // graph preprocessing
    k_zero<<<1, 512, 0, stream>>>(gh);
    k_bhist<<<gE4, 1024, 0, stream>>>(dst, gh);
    k_bscan<<<1, 512, 0, stream>>>(gh, gbase, gcur);
    k_bscatter<<<gE4, 1024, 0, stream>>>(src, dst, gcur, staging);
    k_blocal<<<NBB, 1024, 0, stream>>>(staging, gbase, deg, dinv);
    k_scan1<<<gS, 256, 0, stream>>>(deg, row_ptr, bsums);
    k_scan2<<<1, 128, 0, stream>>>(bsums, gS);
    k_scan3<<<gN1, 256, 0, stream>>>(row_ptr, bsums);
    k_bfill<<<NBB, 1024, 0, stream>>>(staging, gbase, row_ptr, csr);

    // weight fragment prep
    {
        WPrepArgs a;
        int  eoff[6] = {0, 16384, 32768, 40960, 45056, 53248};
        int  base[6] = {0, 2048, 4096, 5120, 5632, 6656};
        int  tot[6]  = {2048, 2048, 1024, 512, 1024, 2048};
        const float* Ws[6] = {g1w, f2w, g3w, f4w, g5w, f6w};
        int din[6]  = {128, 128, 128, 64, 64, 128};
        int dout[6] = {128, 128, 64, 64, 128, 128};
        int trb[6]  = {0, 1, 0, 1, 0, 1};
        for (int i = 0; i < 6; i++) {
            a.d[i] = WDesc{Ws[i], wfh + eoff[i], wfl + eoff[i],
                           din[i], dout[i], trb[i], base[i], tot[i]};
        }
        k_wprep<<<(8704 + 255) / 256, 256, 0, stream>>>(a);
    }

    // G1: h1 = bf16(dinv * (x@W1))           [fp32 in, hi-plane payload out]
    k_mgemm<128, 128, 2, 1, 1, false, false, true><<<gM, 256, 0, stream>>>(
        x, wfh + 0, wfl + 0, nullptr, dinv, bufA);
    // agg1: z1 = relu(dinv*agg(h1)+b1)       [two-plane out]
    k_agg<128, true><<<gA, 256, 0, stream>>>((const u16*)bufA, dinv, row_ptr, csr, g1b, (u16*)bufB);
    // fused fc2+G3: z1' = relu(z1 + z1@W2^T); h2 = bf16(dinv*(z1'@W3))
    k_mfused<128, 128, 64, 2, true, false, true, false, 1><<<gM, 256, 0, stream>>>(
        (const u16*)bufB, wfh + 16384, wfl + 16384, wfh + 32768, wfl + 32768,
        nullptr, dinv, bufA);
    // agg2: z2 = relu(dinv*agg(h2)+b3)       [two-plane out]
    k_agg<64, true><<<gA, 256, 0, stream>>>((const u16*)bufA, dinv, row_ptr, csr, g3b, (u16*)bufB);
    // fc4: p3 = bf16(dinv * relu(z2 + z2@W4^T)) [two-plane in+resid, payload out]
    k_mgemm<64, 64, 2, 2, 1, true, false, true><<<gM, 256, 0, stream>>>(
        bufB, wfh + 40960, wfl + 40960, nullptr, dinv, bufA);
    // agg3: a3 = agg(p3)                     [two-plane out]
    k_agg<64, false><<<gA, 256, 0, stream>>>((const u16*)bufA, dinv, row_ptr, csr, nullptr, (u16*)bufB);
    // fused G5+fc6: z3 = relu(a3@W5+b5); out = relu(z3 + z3@W6^T)  [fp32 out]
    k_mfused<64, 128, 128, 2, false, true, false, true, 0><<<gM, 256, 0, stream>>>(
        (const u16*)bufB, wfh + 45056, wfl + 45056, wfh + 53248, wfl + 53248,
        g5b, nullptr, out);
}

// Round 6
// 501.864 us; speedup vs baseline: 1.0130x; 1.0130x over previous
//
#include <hip/hip_runtime.h>
#include <cstdint>
#include <cstddef>

#define NN 100000
#define NE 1600000
#define NBB 391   // dst buckets of 256 nodes: ceil(100000/256)

typedef short short8 __attribute__((ext_vector_type(8)));
typedef float floatx4 __attribute__((ext_vector_type(4)));
typedef unsigned short u16;
typedef uint32_t u32;

// ---------------- graph preprocessing (bucketed, atomic-light) ----------------

static __global__ void k_zero(int* __restrict__ gh) {
    int i = threadIdx.x;
    if (i < NBB + 1) gh[i] = 0;
}

// histogram of dst>>8 ; 1024 thr x 4 edges/block -> 391 global atomics/block
static __global__ __launch_bounds__(1024) void k_bhist(const int* __restrict__ dst,
                                                       int* __restrict__ gh) {
    __shared__ int h[NBB + 1];
    int t = threadIdx.x;
    for (int i = t; i < NBB; i += 1024) h[i] = 0;
    __syncthreads();
    int e0 = blockIdx.x * 4096;
#pragma unroll
    for (int j = 0; j < 4; j++) {
        int e = e0 + j * 1024 + t;
        if (e < NE) atomicAdd(&h[dst[e] >> 8], 1);
    }
    __syncthreads();
    for (int i = t; i < NBB; i += 1024)
        if (h[i]) atomicAdd(&gh[i], h[i]);
}

// parallel single-block scan over NBB=391 bucket counts
static __global__ void k_bscan(const int* __restrict__ gh, int* __restrict__ gbase,
                               int* __restrict__ gcur) {
    __shared__ int sd[512];
    int t = threadIdx.x;
    int v = (t < NBB) ? gh[t] : 0;
    sd[t] = v;
    __syncthreads();
    for (int off = 1; off < 512; off <<= 1) {
        int x = (t >= off) ? sd[t - off] : 0;
        __syncthreads();
        sd[t] += x;
        __syncthreads();
    }
    int excl = (t > 0) ? sd[t - 1] : 0;
    if (t < NBB) {
        gbase[t] = excl;
        gcur[t] = excl;
    }
    if (t == NBB) gbase[NBB] = excl;  // == NE
}

// scatter edges into bucket-ordered staging (int2 = src,dst)
static __global__ __launch_bounds__(1024) void k_bscatter(const int* __restrict__ src,
                                                          const int* __restrict__ dst,
                                                          int* __restrict__ gcur,
                                                          int2* __restrict__ staging) {
    __shared__ int h[NBB + 1];
    __shared__ int base[NBB + 1];
    int t = threadIdx.x;
    for (int i = t; i < NBB; i += 1024) h[i] = 0;
    __syncthreads();
    int e0 = blockIdx.x * 4096;
    int b[4], l[4], sv[4], dv[4];
#pragma unroll
    for (int j = 0; j < 4; j++) {
        int e = e0 + j * 1024 + t;
        b[j] = -1;
        if (e < NE) {
            sv[j] = src[e];
            dv[j] = dst[e];
            b[j] = dv[j] >> 8;
            l[j] = atomicAdd(&h[b[j]], 1);
        }
    }
    __syncthreads();
    for (int i = t; i < NBB; i += 1024)
        if (h[i]) base[i] = atomicAdd(&gcur[i], h[i]);
    __syncthreads();
#pragma unroll
    for (int j = 0; j < 4; j++)
        if (b[j] >= 0) staging[base[b[j]] + l[j]] = make_int2(sv[j], dv[j]);
}

// per-bucket degree count via LDS -> deg/dinv written coalesced, no global atomics
static __global__ __launch_bounds__(1024) void k_blocal(const int2* __restrict__ staging,
                                                        const int* __restrict__ gbase,
                                                        int* __restrict__ deg,
                                                        float* __restrict__ dinv) {
    __shared__ int cnt[256];
    int b = blockIdx.x;
    int t = threadIdx.x;
    if (t < 256) cnt[t] = 0;
    __syncthreads();
    int end = gbase[b + 1];
    for (int i = gbase[b] + t; i < end; i += 1024)
        atomicAdd(&cnt[staging[i].y & 255], 1);
    __syncthreads();
    if (t < 256) {
        int node = (b << 8) + t;
        if (node < NN) {
            int d = cnt[t] + 1;  // +1 self loop
            deg[node] = d;
            dinv[node] = rsqrtf((float)d);
        }
    }
}

// exclusive scan of (deg[i]-1) -> row_ptr, chunk=1024/block
static __global__ void k_scan1(const int* __restrict__ deg, int* __restrict__ row_ptr,
                               int* __restrict__ bsums) {
    __shared__ int sd[256];
    int t = threadIdx.x;
    int base = blockIdx.x * 1024;
    int v[4];
    int s = 0;
#pragma unroll
    for (int j = 0; j < 4; j++) {
        int i = base + t * 4 + j;
        int c = (i < NN) ? (deg[i] - 1) : 0;
        v[j] = s;
        s += c;
    }
    sd[t] = s;
    __syncthreads();
    for (int off = 1; off < 256; off <<= 1) {
        int x = (t >= off) ? sd[t - off] : 0;
        __syncthreads();
        sd[t] += x;
        __syncthreads();
    }
    int excl = (t > 0) ? sd[t - 1] : 0;
#pragma unroll
    for (int j = 0; j < 4; j++) {
        int i = base + t * 4 + j;
        if (i < NN) row_ptr[i] = excl + v[j];
    }
    if (t == 255) bsums[blockIdx.x] = sd[255];
}

// parallel single-block scan over nb<=128 block sums
static __global__ void k_scan2(int* __restrict__ bsums, int nb) {
    __shared__ int sd[128];
    int t = threadIdx.x;
    int v = (t < nb) ? bsums[t] : 0;
    sd[t] = v;
    __syncthreads();
    for (int off = 1; off < 128; off <<= 1) {
        int x = (t >= off) ? sd[t - off] : 0;
        __syncthreads();
        sd[t] += x;
        __syncthreads();
    }
    if (t < nb) bsums[t] = sd[t] - v;  // exclusive
}

static __global__ void k_scan3(int* __restrict__ row_ptr, const int* __restrict__ bsums) {
    int i = blockIdx.x * 256 + threadIdx.x;
    if (i < NN) {
        row_ptr[i] += bsums[i >> 10];
    } else if (i == NN) {
        row_ptr[NN] = NE;
    }
}

// per-bucket CSR fill: ranks via LDS atomics
static __global__ __launch_bounds__(1024) void k_bfill(const int2* __restrict__ staging,
                                                       const int* __restrict__ gbase,
                                                       const int* __restrict__ row_ptr,
                                                       int* __restrict__ csr_src) {
    __shared__ int cnt[256];
    int b = blockIdx.x;
    int t = threadIdx.x;
    if (t < 256) cnt[t] = 0;
    __syncthreads();
    int end = gbase[b + 1];
    for (int i = gbase[b] + t; i < end; i += 1024) {
        int2 ed = staging[i];
        int r = atomicAdd(&cnt[ed.y & 255], 1);
        csr_src[row_ptr[ed.y] + r] = ed.x;
    }
}

// ---------------- bf16 helpers ----------------
__device__ __forceinline__ void split_bf16(float f, short& hi, short& lo) {
    union { float f; uint32_t u; } x;
    x.f = f;
    uint32_t uh = x.u + 0x7FFFu + ((x.u >> 16) & 1u);
    hi = (short)(uh >> 16);
    union { uint32_t u; float f; } hf;
    hf.u = (uh >> 16) << 16;
    float r = f - hf.f;
    union { float f; uint32_t u; } y;
    y.f = r;
    uint32_t ul = y.u + 0x7FFFu + ((y.u >> 16) & 1u);
    lo = (short)(ul >> 16);
}

__device__ __forceinline__ u16 f2bf(float f) {  // RNE (== hi part of split)
    union { float f; uint32_t u; } x;
    x.f = f;
    uint32_t r = x.u + 0x7FFFu + ((x.u >> 16) & 1u);
    return (u16)(r >> 16);
}

__device__ __forceinline__ float bf2f(u16 h) {
    union { uint32_t u; float f; } x;
    x.u = ((uint32_t)h) << 16;
    return x.f;
}

// accumulate a packed pair of bf16 channels (low half -> a0, high half -> a1)
__device__ __forceinline__ void acc2(uint32_t u, float& a0, float& a1) {
    union { uint32_t u; float f; } lo, hi;
    lo.u = u << 16;
    hi.u = u & 0xFFFF0000u;
    a0 += lo.f;
    a1 += hi.f;
}

// ---------------- weight pre-split into MFMA B-fragment layout ----------------
struct WDesc {
    const float* W;
    short* fh;
    short* fl;
    int din, dout, transb, base, total;  // base/total in short8 groups
};
struct WPrepArgs { WDesc d[6]; };

static __global__ void k_wprep(WPrepArgs args) {
    int tid = blockIdx.x * 256 + threadIdx.x;
#pragma unroll
    for (int i = 0; i < 6; i++) {
        const WDesc& D = args.d[i];
        if (tid >= D.base && tid < D.base + D.total) {
            int local = tid - D.base;
            int lane = local & 63;
            int rest = local >> 6;
            int kst = D.din >> 5;
            int ks = rest % kst;
            int ntile = rest / kst;
            int n = ntile * 16 + (lane & 15);
            int k0 = ks * 32 + (lane >> 4) * 8;
#pragma unroll
            for (int j = 0; j < 8; j++) {
                int k = k0 + j;
                float v = D.transb ? D.W[(size_t)n * D.din + k]
                                   : D.W[(size_t)k * D.dout + n];
                short h, l;
                split_bf16(v, h, l);
                D.fh[(size_t)local * 8 + j] = h;
                D.fl[(size_t)local * 8 + j] = l;
            }
        }
    }
}

// ---------------- MFMA GEMM: LDS-free, B in registers ------------------------
// Round-5 post-mortem: VGPR_Count=68 on earlier rounds proves the 64-96 VGPR
// B-fragment arrays were NOT register-resident — the allocator (targeting high
// occupancy without guidance) rematerialized B loads inside the K-loop,
// serializing on L2 latency every few MFMAs (explains MfmaUtil 4.5%, all pipes
// idle, and the null results of MT=2 / unpack removal).
// __launch_bounds__(256, 3): 3 waves/SIMD -> 170-VGPR cap; est. need ~110-150
// -> B fragments stay resident, K-loop issues only streaming A loads.
// MT loop fully unrolled (MT=2): tile-1 A-loads pipeline under tile-0 MFMAs.
// AMODE: 1 = fp32 input, on-the-fly RNE, 2 MFMAs/K-step (G1 only)
//        2 = two-plane split input (3 MFMAs, lossless vs fp32 to 2^-16)
// OMODE: 0 = fp32 out, 1 = hi plane only (payload), 2 = hi+lo planes
template <int DIN, int DOUT, int MT, int AMODE, int OMODE, bool RESID, bool BIAS, bool SCALE>
__global__ __launch_bounds__(256, 3) void k_mgemm(const void* __restrict__ Av,
                                                  const short* __restrict__ fh,
                                                  const short* __restrict__ fl,
                                                  const float* __restrict__ bias,
                                                  const float* __restrict__ dinv,
                                                  void* __restrict__ C) {
    static_assert(!RESID || DIN == DOUT, "residual needs square");
    constexpr int KST = DIN / 32;
    constexpr int NTW = DOUT / 64;  // N-tiles per wave (block: 4 waves = DOUT/16 tiles)
    const int t = threadIdx.x;
    const int wave = t >> 6;
    const int lane = t & 63;
    const int r16 = lane & 15;
    const int kq = lane >> 4;

    const float* Af = (const float*)Av;
    const u16*   Ah = (const u16*)Av;
    const u16*   Al = Ah + (size_t)NN * DIN;

    short8 bh[NTW][KST], bl[NTW][KST];
#pragma unroll
    for (int nt = 0; nt < NTW; nt++) {
        int ntile = wave * NTW + nt;
#pragma unroll
        for (int ks = 0; ks < KST; ks++) {
            size_t o = ((size_t)(ntile * KST + ks) * 64 + lane) * 8;
            bh[nt][ks] = *(const short8*)(fh + o);
            bl[nt][ks] = *(const short8*)(fl + o);
        }
    }

    const int m0b = blockIdx.x * (MT * 16);
#pragma unroll
    for (int mt = 0; mt < MT; mt++) {
        const int m0 = m0b + mt * 16;
        if (m0 >= NN) break;
        const int ra = min(m0 + r16, NN - 1);  // clamp; stores guarded

        floatx4 acc[NTW];
#pragma unroll
        for (int nt = 0; nt < NTW; nt++) acc[nt] = (floatx4){0.f, 0.f, 0.f, 0.f};

        if constexpr (AMODE == 1) {
            const float* Ap = Af + (size_t)ra * DIN + kq * 8;
#pragma unroll
            for (int ks = 0; ks < KST; ks++) {
                float4 f0 = *(const float4*)(Ap + ks * 32);
                float4 f1 = *(const float4*)(Ap + ks * 32 + 4);
                float fe[8] = {f0.x, f0.y, f0.z, f0.w, f1.x, f1.y, f1.z, f1.w};
                short8 ah;
#pragma unroll
                for (int j = 0; j < 8; j++) ah[j] = (short)f2bf(fe[j]);
#pragma unroll
                for (int nt = 0; nt < NTW; nt++) {
                    acc[nt] = __builtin_amdgcn_mfma_f32_16x16x32_bf16(ah, bh[nt][ks], acc[nt], 0, 0, 0);
                    acc[nt] = __builtin_amdgcn_mfma_f32_16x16x32_bf16(ah, bl[nt][ks], acc[nt], 0, 0, 0);
                }
            }
        } else {
            const u16* Aph = Ah + (size_t)ra * DIN + kq * 8;
            const u16* Apl = Al + (size_t)ra * DIN + kq * 8;
#pragma unroll
            for (int ks = 0; ks < KST; ks++) {
                short8 ah = *(const short8*)(Aph + ks * 32);
                short8 al = *(const short8*)(Apl + ks * 32);
#pragma unroll
                for (int nt = 0; nt < NTW; nt++) {
                    acc[nt] = __builtin_amdgcn_mfma_f32_16x16x32_bf16(ah, bh[nt][ks], acc[nt], 0, 0, 0);
                    acc[nt] = __builtin_amdgcn_mfma_f32_16x16x32_bf16(ah, bl[nt][ks], acc[nt], 0, 0, 0);
                    acc[nt] = __builtin_amdgcn_mfma_f32_16x16x32_bf16(al, bh[nt][ks], acc[nt], 0, 0, 0);
                }
            }
        }

        // C/D layout: row = kq*4 + r, col = r16 (verified)
#pragma unroll
        for (int nt = 0; nt < NTW; nt++) {
            int col = (wave * NTW + nt) * 16 + r16;
#pragma unroll
            for (int r = 0; r < 4; r++) {
                int row = m0 + kq * 4 + r;
                if (row < NN) {
                    float v = acc[nt][r];
                    if constexpr (RESID) {
                        size_t ri = (size_t)row * DIN + col;
                        v = fmaxf(v + bf2f(Ah[ri]) + bf2f(Al[ri]), 0.f);
                    }
                    if constexpr (BIAS) v = fmaxf(v + bias[col], 0.f);
                    if constexpr (SCALE) v *= dinv[row];
                    size_t oi = (size_t)row * DOUT + col;
                    if constexpr (OMODE == 0) {
                        ((float*)C)[oi] = v;
                    } else if constexpr (OMODE == 1) {
                        ((u16*)C)[oi] = f2bf(v);
                    } else {
                        short h, l;
                        split_bf16(v, h, l);
                        ((u16*)C)[oi] = (u16)h;
                        ((u16*)C)[(size_t)NN * DOUT + oi] = (u16)l;
                    }
                }
            }
        }
    }
}

// ---------------- fused GEMM pair: C = ep2( ep1(A@W1') @ W2' ) ---------------
// Stages the 16xDMID intermediate through LDS as two u16 planes (split-bf16,
// numerically identical to the global two-plane path). Row stride DMID+8 u16
// = 272B (for DMID=128): 16B-aligned, rows advance 4 banks -> reads at the
// 2-lanes/bank wave64 minimum. A-frag from LDS = two short8 ds_reads, no unpack.
// __launch_bounds__(256, 3): B1+B2 fragments (up to 96 VGPR) must be resident
// (see k_mgemm note) — est. total ~140-150 VGPR, under the 170 cap.
template <int DIN, int DMID, int DOUT, int MT, bool RESID1, bool BIAS1,
          bool SCALE2, bool RESID2, int OMODE2>
__global__ __launch_bounds__(256, 3) void k_mfused(const u16* __restrict__ Ahp,
                                                   const short* __restrict__ f1h,
                                                   const short* __restrict__ f1l,
                                                   const short* __restrict__ f2h,
                                                   const short* __restrict__ f2l,
                                                   const float* __restrict__ bias1,
                                                   const float* __restrict__ dinv,
                                                   void* __restrict__ C) {
    static_assert(!RESID1 || DIN == DMID, "resid1 needs square stage1");
    static_assert(!RESID2 || DMID == DOUT, "resid2 needs square stage2");
    constexpr int KST1 = DIN / 32;
    constexpr int NTW1 = DMID / 64;
    constexpr int KST2 = DMID / 32;
    constexpr int NTW2 = DOUT / 64;
    constexpr int LDW = DMID + 8;  // u16 stride: 16B-aligned rows, 4-bank skew
    __shared__ u16 ldsh[16][LDW];
    __shared__ u16 ldsl[16][LDW];

    const u16* Alp = Ahp + (size_t)NN * DIN;

    const int t = threadIdx.x;
    const int wave = t >> 6;
    const int lane = t & 63;
    const int r16 = lane & 15;
    const int kq = lane >> 4;

    short8 b1h[NTW1][KST1], b1l[NTW1][KST1];
#pragma unroll
    for (int nt = 0; nt < NTW1; nt++) {
        int ntile = wave * NTW1 + nt;
#pragma unroll
        for (int ks = 0; ks < KST1; ks++) {
            size_t o = ((size_t)(ntile * KST1 + ks) * 64 + lane) * 8;
            b1h[nt][ks] = *(const short8*)(f1h + o);
            b1l[nt][ks] = *(const short8*)(f1l + o);
        }
    }
    short8 b2h[NTW2][KST2], b2l[NTW2][KST2];
#pragma unroll
    for (int nt = 0; nt < NTW2; nt++) {
        int ntile = wave * NTW2 + nt;
#pragma unroll
        for (int ks = 0; ks < KST2; ks++) {
            size_t o = ((size_t)(ntile * KST2 + ks) * 64 + lane) * 8;
            b2h[nt][ks] = *(const short8*)(f2h + o);
            b2l[nt][ks] = *(const short8*)(f2l + o);
        }
    }

    const int m0b = blockIdx.x * (MT * 16);
#pragma unroll 1
    for (int mt = 0; mt < MT; mt++) {
        const int m0 = m0b + mt * 16;
        if (m0 >= NN) break;
        const int ra = min(m0 + r16, NN - 1);

        // ---- stage 1: acc1 = A @ W1' ----
        floatx4 acc1[NTW1];
#pragma unroll
        for (int nt = 0; nt < NTW1; nt++) acc1[nt] = (floatx4){0.f, 0.f, 0.f, 0.f};
        {
            const u16* Aph = Ahp + (size_t)ra * DIN + kq * 8;
            const u16* Apl = Alp + (size_t)ra * DIN + kq * 8;
#pragma unroll
            for (int ks = 0; ks < KST1; ks++) {
                short8 ah = *(const short8*)(Aph + ks * 32);
                short8 al = *(const short8*)(Apl + ks * 32);
#pragma unroll
                for (int nt = 0; nt < NTW1; nt++) {
                    acc1[nt] = __builtin_amdgcn_mfma_f32_16x16x32_bf16(ah, b1h[nt][ks], acc1[nt], 0, 0, 0);
                    acc1[nt] = __builtin_amdgcn_mfma_f32_16x16x32_bf16(ah, b1l[nt][ks], acc1[nt], 0, 0, 0);
                    acc1[nt] = __builtin_amdgcn_mfma_f32_16x16x32_bf16(al, b1h[nt][ks], acc1[nt], 0, 0, 0);
                }
            }
        }
        // ---- epilogue 1 -> LDS planes (split) ----
#pragma unroll
        for (int nt = 0; nt < NTW1; nt++) {
            int col = (wave * NTW1 + nt) * 16 + r16;
#pragma unroll
            for (int r = 0; r < 4; r++) {
                int row = m0 + kq * 4 + r;
                float v = acc1[nt][r];
                if constexpr (RESID1) {
                    if (row < NN) {
                        size_t ri = (size_t)row * DIN + col;
                        v = fmaxf(v + bf2f(Ahp[ri]) + bf2f(Alp[ri]), 0.f);
                    }
                }
                if constexpr (BIAS1) v = fmaxf(v + bias1[col], 0.f);
                short h, l;
                split_bf16(v, h, l);
                ldsh[kq * 4 + r][col] = (u16)h;
                ldsl[kq * 4 + r][col] = (u16)l;
            }
        }
        __syncthreads();

        // ---- stage 2: acc2 = mid @ W2' (A-frags from LDS planes) ----
        floatx4 acc2[NTW2];
#pragma unroll
        for (int nt = 0; nt < NTW2; nt++) acc2[nt] = (floatx4){0.f, 0.f, 0.f, 0.f};
#pragma unroll
        for (int ks = 0; ks < KST2; ks++) {
            short8 ah = *(const short8*)&ldsh[r16][ks * 32 + kq * 8];
            short8 al = *(const short8*)&ldsl[r16][ks * 32 + kq * 8];
#pragma unroll
            for (int nt = 0; nt < NTW2; nt++) {
                acc2[nt] = __builtin_amdgcn_mfma_f32_16x16x32_bf16(ah, b2h[nt][ks], acc2[nt], 0, 0, 0);
                acc2[nt] = __builtin_amdgcn_mfma_f32_16x16x32_bf16(ah, b2l[nt][ks], acc2[nt], 0, 0, 0);
                acc2[nt] = __builtin_amdgcn_mfma_f32_16x16x32_bf16(al, b2h[nt][ks], acc2[nt], 0, 0, 0);
            }
        }

        // ---- epilogue 2 -> C ----
#pragma unroll
        for (int nt = 0; nt < NTW2; nt++) {
            int col = (wave * NTW2 + nt) * 16 + r16;
#pragma unroll
            for (int r = 0; r < 4; r++) {
                int row = m0 + kq * 4 + r;
                if (row < NN) {
                    float v = acc2[nt][r];
                    if constexpr (RESID2)
                        v = fmaxf(v + bf2f(ldsh[kq * 4 + r][col]) + bf2f(ldsl[kq * 4 + r][col]), 0.f);
                    if constexpr (SCALE2) v *= dinv[row];
                    size_t oi = (size_t)row * DOUT + col;
                    if constexpr (OMODE2 == 0) {
                        ((float*)C)[oi] = v;
                    } else if constexpr (OMODE2 == 1) {
                        ((u16*)C)[oi] = f2bf(v);
                    } else {
                        short h, l;
                        split_bf16(v, h, l);
                        ((u16*)C)[oi] = (u16)h;
                        ((u16*)C)[(size_t)NN * DOUT + oi] = (u16)l;
                    }
                }
            }
        }
        __syncthreads();  // protect LDS before next mt overwrites
    }
}

// ---------------- GCN aggregation: bf16 gather payload, fp32 accumulate -------
// Output written as two u16 planes (hi = RNE bf16, lo = residual) for the
// consumer GEMM. D=64: split-wave scheme — halves process alternating edges,
// each lane reads a u32 (2 ch) so gather transactions are full 128B rows
// (was 2B/lane half-width); one shfl_xor(32) combines halves.
template <int D, bool BIAS_RELU>
__global__ __launch_bounds__(256) void k_agg(const u16* __restrict__ hs,
                                             const float* __restrict__ dinv,
                                             const int* __restrict__ row_ptr,
                                             const int* __restrict__ csr_src,
                                             const float* __restrict__ bias,
                                             u16* __restrict__ outh) {
    u16* outl = outh + (size_t)NN * D;
    int node = blockIdx.x * 4 + (threadIdx.x >> 6);
    int lane = threadIdx.x & 63;
    if (node >= NN) return;

    if constexpr (D == 128) {
        const int off = lane * 2;
        float a0 = 0.f, a1 = 0.f;
        {
            uint32_t u = ((const uint32_t*)(hs + (size_t)node * D))[lane];
            acc2(u, a0, a1);
        }
        int e = row_ptr[node];
        const int end = row_ptr[node + 1];
        for (; e + 8 <= end; e += 8) {
            int s[8];
#pragma unroll
            for (int i = 0; i < 8; i++) s[i] = csr_src[e + i];
            uint32_t v[8];
#pragma unroll
            for (int i = 0; i < 8; i++) v[i] = ((const uint32_t*)(hs + (size_t)s[i] * D))[lane];
#pragma unroll
            for (int i = 0; i < 8; i++) acc2(v[i], a0, a1);
        }
        for (; e + 4 <= end; e += 4) {
            int s[4];
#pragma unroll
            for (int i = 0; i < 4; i++) s[i] = csr_src[e + i];
            uint32_t v[4];
#pragma unroll
            for (int i = 0; i < 4; i++) v[i] = ((const uint32_t*)(hs + (size_t)s[i] * D))[lane];
#pragma unroll
            for (int i = 0; i < 4; i++) acc2(v[i], a0, a1);
        }
        for (; e < end; e++) {
            int s = csr_src[e];
            uint32_t u = ((const uint32_t*)(hs + (size_t)s * D))[lane];
            acc2(u, a0, a1);
        }
        const float di = dinv[node];
        a0 *= di;
        a1 *= di;
        if constexpr (BIAS_RELU) {
            a0 = fmaxf(a0 + bias[off], 0.f);
            a1 = fmaxf(a1 + bias[off + 1], 0.f);
        }
        short h0, l0, h1, l1;
        split_bf16(a0, h0, l0);
        split_bf16(a1, h1, l1);
        ushort2 wh, wl;
        wh.x = (u16)h0; wh.y = (u16)h1;
        wl.x = (u16)l0; wl.y = (u16)l1;
        *(ushort2*)(outh + (size_t)node * D + off) = wh;
        *(ushort2*)(outl + (size_t)node * D + off) = wl;
    } else {
        // D == 64: halves handle alternating edges; lane owns ch {2*l32, 2*l32+1}
        const int half = lane >> 5;
        const int l32 = lane & 31;
        float a0 = 0.f, a1 = 0.f;
        if (half == 0) {
            uint32_t u = ((const uint32_t*)(hs + (size_t)node * D))[l32];
            acc2(u, a0, a1);
        }
        int e = row_ptr[node];
        const int end = row_ptr[node + 1];
        for (; e + 8 <= end; e += 8) {
            int s[4];
#pragma unroll
            for (int i = 0; i < 4; i++) s[i] = csr_src[e + half + 2 * i];
            uint32_t v[4];
#pragma unroll
            for (int i = 0; i < 4; i++) v[i] = ((const uint32_t*)(hs + (size_t)s[i] * D))[l32];
#pragma unroll
            for (int i = 0; i < 4; i++) acc2(v[i], a0, a1);
        }
        for (; e + 2 <= end; e += 2) {
            int s = csr_src[e + half];
            uint32_t u = ((const uint32_t*)(hs + (size_t)s * D))[l32];
            acc2(u, a0, a1);
        }
        if (e < end && half == 0) {
            int s = csr_src[e];
            uint32_t u = ((const uint32_t*)(hs + (size_t)s * D))[l32];
            acc2(u, a0, a1);
        }
        a0 += __shfl_xor(a0, 32, 64);
        a1 += __shfl_xor(a1, 32, 64);
        if (half == 0) {
            const int off = l32 * 2;
            const float di = dinv[node];
            a0 *= di;
            a1 *= di;
            if constexpr (BIAS_RELU) {
                a0 = fmaxf(a0 + bias[off], 0.f);
                a1 = fmaxf(a1 + bias[off + 1], 0.f);
            }
            short h0, l0, h1, l1;
            split_bf16(a0, h0, l0);
            split_bf16(a1, h1, l1);
            ushort2 wh, wl;
            wh.x = (u16)h0; wh.y = (u16)h1;
            wl.x = (u16)l0; wl.y = (u16)l1;
            *(ushort2*)(outh + (size_t)node * D + off) = wh;
            *(ushort2*)(outl + (size_t)node * D + off) = wl;
        }
    }
}

// ---------------- launch ----------------

extern "C" void kernel_launch(void* const* d_in, const int* in_sizes, int n_in,
                              void* d_out, int out_size, void* d_ws, size_t ws_size,
                              hipStream_t stream) {
    const float* x   = (const float*)d_in[0];
    const int*   ei  = (const int*)d_in[1];
    const float* g1w = (const float*)d_in[2];
    const float* g1b = (const float*)d_in[3];
    const float* f2w = (const float*)d_in[4];
    const float* g3w = (const float*)d_in[5];
    const float* g3b = (const float*)d_in[6];
    const float* f4w = (const float*)d_in[7];
    const float* g5w = (const float*)d_in[8];
    const float* g5b = (const float*)d_in[9];
    const float* f6w = (const float*)d_in[10];
    float* out = (float*)d_out;

    const int* src = ei;       // edge_index[0]
    const int* dst = ei + NE;  // edge_index[1]

    char* p = (char*)d_ws;
    auto alloc = [&](size_t bytes) -> void* {
        void* r = (void*)p;
        p += (bytes + 255) & ~(size_t)255;
        return r;
    };
    int*   deg     = (int*)alloc(NN * 4);
    float* dinv    = (float*)alloc(NN * 4);
    int*   row_ptr = (int*)alloc((NN + 1) * 4);
    int*   bsums   = (int*)alloc(512);
    int*   gh      = (int*)alloc((NBB + 1) * 4);
    int*   gbase   = (int*)alloc((NBB + 1) * 4);
    int*   gcur    = (int*)alloc((NBB + 1) * 4);
    int*   csr     = (int*)alloc(NE * 4);
    short* wfh     = (short*)alloc(69632 * 2);
    short* wfl     = (short*)alloc(69632 * 2);
    // bufA/bufB: 4B/elem budget = room for hi+lo u16 planes at D=128
    char* bufA = (char*)alloc((size_t)NN * 128 * 4);
    char* bufB = (char*)alloc((size_t)NN * 128 * 4);
    // edge staging (12.8 MB) aliases bufB: fully consumed by k_blocal/k_bfill
    // before agg1 writes bufB (stream-ordered).
    int2* staging  = (int2*)bufB;

    const int gE4 = (NE + 4095) / 4096;      // 391
    const int gS  = (NN + 1023) / 1024;      // 98
    const int gN1 = (NN + 1 + 255) / 256;
    const int gA  = NN / 4;                  // 25000
    const int gM  = (NN + 31) / 32;          // 3125 (MT=2: 32 rows/block, exact)

    // graph preprocessing
    k_zero<<<1, 512, 0, stream>>>(gh);
    k_bhist<<<gE4, 1024, 0, stream>>>(dst, gh);
    k_bscan<<<1, 512, 0, stream>>>(gh, gbase, gcur);
    k_bscatter<<<gE4, 1024, 0, stream>>>(src, dst, gcur, staging);
    k_blocal<<<NBB, 1024, 0, stream>>>(staging, gbase, deg, dinv);
    k_scan1<<<gS, 256, 0, stream>>>(deg, row_ptr, bsums);
    k_scan2<<<1, 128, 0, stream>>>(bsums, gS);
    k_scan3<<<gN1, 256, 0, stream>>>(row_ptr, bsums);
    k_bfill<<<NBB, 1024, 0, stream>>>(staging, gbase, row_ptr, csr);

    // weight fragment prep
    {
        WPrepArgs a;
        int  eoff[6] = {0, 16384, 32768, 40960, 45056, 53248};
        int  base[6] = {0, 2048, 4096, 5120, 5632, 6656};
        int  tot[6]  = {2048, 2048, 1024, 512, 1024, 2048};
        const float* Ws[6] = {g1w, f2w, g3w, f4w, g5w, f6w};
        int din[6]  = {128, 128, 128, 64, 64, 128};
        int dout[6] = {128, 128, 64, 64, 128, 128};
        int trb[6]  = {0, 1, 0, 1, 0, 1};
        for (int i = 0; i < 6; i++) {
            a.d[i] = WDesc{Ws[i], wfh + eoff[i], wfl + eoff[i],
                           din[i], dout[i], trb[i], base[i], tot[i]};
        }
        k_wprep<<<(8704 + 255) / 256, 256, 0, stream>>>(a);
    }

    // G1: h1 = bf16(dinv * (x@W1))           [fp32 in, hi-plane payload out]
    k_mgemm<128, 128, 2, 1, 1, false, false, true><<<gM, 256, 0, stream>>>(
        x, wfh + 0, wfl + 0, nullptr, dinv, bufA);
    // agg1: z1 = relu(dinv*agg(h1)+b1)       [two-plane out]
    k_agg<128, true><<<gA, 256, 0, stream>>>((const u16*)bufA, dinv, row_ptr, csr, g1b, (u16*)bufB);
    // fused fc2+G3: z1' = relu(z1 + z1@W2^T); h2 = bf16(dinv*(z1'@W3))
    k_mfused<128, 128, 64, 2, true, false, true, false, 1><<<gM, 256, 0, stream>>>(
        (const u16*)bufB, wfh + 16384, wfl + 16384, wfh + 32768, wfl + 32768,
        nullptr, dinv, bufA);
    // agg2: z2 = relu(dinv*agg(h2)+b3)       [two-plane out]
    k_agg<64, true><<<gA, 256, 0, stream>>>((const u16*)bufA, dinv, row_ptr, csr, g3b, (u16*)bufB);
    // fc4: p3 = bf16(dinv * relu(z2 + z2@W4^T)) [two-plane in+resid, payload out]
    k_mgemm<64, 64, 2, 2, 1, true, false, true><<<gM, 256, 0, stream>>>(
        bufB, wfh + 40960, wfl + 40960, nullptr, dinv, bufA);
    // agg3: a3 = agg(p3)                     [two-plane out]
    k_agg<64, false><<<gA, 256, 0, stream>>>((const u16*)bufA, dinv, row_ptr, csr, nullptr, (u16*)bufB);
    // fused G5+fc6: z3 = relu(a3@W5+b5); out = relu(z3 + z3@W6^T)  [fp32 out]
    k_mfused<64, 128, 128, 2, false, true, false, true, 0><<<gM, 256, 0, stream>>>(
        (const u16*)bufB, wfh + 45056, wfl + 45056, wfh + 53248, wfl + 53248,
        g5b, nullptr, out);
}

// Round 7
// 479.970 us; speedup vs baseline: 1.0592x; 1.0456x over previous
//
#include <hip/hip_runtime.h>
#include <cstdint>
#include <cstddef>

#define NN 100000
#define NE 1600000
#define NBB 391      // dst buckets of 256 nodes: ceil(100000/256)
#define BSTRIDE 5120 // staging slots per bucket; E[cnt]=4092, sd=64 -> 16-sigma margin

typedef short short8 __attribute__((ext_vector_type(8)));
typedef float floatx4 __attribute__((ext_vector_type(4)));
typedef unsigned short u16;
typedef uint32_t u32;

// ---------------- graph preprocessing (fixed-stride buckets, 5 dispatches) ----

static __global__ void k_zero(int* __restrict__ gcur) {
    int i = threadIdx.x;
    if (i < NBB + 1) gcur[i] = 0;
}

// scatter edges into fixed-stride bucket staging (int2 = src,dst); gcur[b]=count
static __global__ __launch_bounds__(1024) void k_bscatterF(const int* __restrict__ src,
                                                           const int* __restrict__ dst,
                                                           int* __restrict__ gcur,
                                                           int2* __restrict__ staging) {
    __shared__ int h[NBB + 1];
    __shared__ int base[NBB + 1];
    int t = threadIdx.x;
    for (int i = t; i < NBB; i += 1024) h[i] = 0;
    __syncthreads();
    int e0 = blockIdx.x * 4096;
    int b[4], l[4], sv[4], dv[4];
#pragma unroll
    for (int j = 0; j < 4; j++) {
        int e = e0 + j * 1024 + t;
        b[j] = -1;
        if (e < NE) {
            sv[j] = src[e];
            dv[j] = dst[e];
            b[j] = dv[j] >> 8;
            l[j] = atomicAdd(&h[b[j]], 1);
        }
    }
    __syncthreads();
    for (int i = t; i < NBB; i += 1024)
        if (h[i]) base[i] = atomicAdd(&gcur[i], h[i]);
    __syncthreads();
#pragma unroll
    for (int j = 0; j < 4; j++)
        if (b[j] >= 0)
            staging[(size_t)b[j] * BSTRIDE + base[b[j]] + l[j]] = make_int2(sv[j], dv[j]);
}

// per-bucket: node degree counts (LDS), dinv, LOCAL exclusive row offsets
static __global__ __launch_bounds__(1024) void k_blocal2(const int2* __restrict__ staging,
                                                         const int* __restrict__ gcur,
                                                         float* __restrict__ dinv,
                                                         int* __restrict__ row_ptr) {
    __shared__ int cnt[256];
    __shared__ int sc[256];
    int b = blockIdx.x;
    int t = threadIdx.x;
    if (t < 256) cnt[t] = 0;
    __syncthreads();
    const int n = gcur[b];
    const int base = b * BSTRIDE;
    for (int i = base + t; i < base + n; i += 1024)
        atomicAdd(&cnt[staging[i].y & 255], 1);
    __syncthreads();
    int myc = (t < 256) ? cnt[t] : 0;
    if (t < 256) sc[t] = myc;
    __syncthreads();
    for (int off = 1; off < 256; off <<= 1) {
        int x = 0;
        if (t < 256 && t >= off) x = sc[t - off];
        __syncthreads();
        if (t < 256) sc[t] += x;
        __syncthreads();
    }
    if (t < 256) {
        int node = (b << 8) + t;
        if (node < NN) {
            dinv[node] = rsqrtf((float)(myc + 1));  // +1 self loop
            row_ptr[node] = sc[t] - myc;            // local exclusive offset
        }
    }
}

// single-block scan of bucket counts -> gbase; also row_ptr[NN] = NE
static __global__ void k_bscanB(const int* __restrict__ gcur, int* __restrict__ gbase,
                                int* __restrict__ row_ptr) {
    __shared__ int sd[512];
    int t = threadIdx.x;
    int v = (t < NBB) ? gcur[t] : 0;
    sd[t] = v;
    __syncthreads();
    for (int off = 1; off < 512; off <<= 1) {
        int x = (t >= off) ? sd[t - off] : 0;
        __syncthreads();
        sd[t] += x;
        __syncthreads();
    }
    int excl = (t > 0) ? sd[t - 1] : 0;
    if (t < NBB) gbase[t] = excl;
    if (t == NBB) gbase[NBB] = excl;  // == NE
    if (t == 0) row_ptr[NN] = NE;
}

// per-bucket CSR fill (ranks via LDS atomics) + absolutize row_ptr
static __global__ __launch_bounds__(1024) void k_bfill2(const int2* __restrict__ staging,
                                                        const int* __restrict__ gcur,
                                                        const int* __restrict__ gbase,
                                                        int* __restrict__ row_ptr,
                                                        int* __restrict__ csr_src) {
    __shared__ int cnt[256];
    __shared__ int lrp[256];
    int b = blockIdx.x;
    int t = threadIdx.x;
    if (t < 256) {
        cnt[t] = 0;
        int node = (b << 8) + t;
        lrp[t] = (node < NN) ? row_ptr[node] : 0;
    }
    __syncthreads();
    const int bb = gbase[b];
    const int n = gcur[b];
    const int base = b * BSTRIDE;
    for (int i = base + t; i < base + n; i += 1024) {
        int2 ed = staging[i];
        int loc = ed.y & 255;
        int r = atomicAdd(&cnt[loc], 1);
        csr_src[bb + lrp[loc] + r] = ed.x;
    }
    if (t < 256) {
        int node = (b << 8) + t;
        if (node < NN) row_ptr[node] = bb + lrp[t];
    }
}

// ---------------- bf16 helpers ----------------
__device__ __forceinline__ void split_bf16(float f, short& hi, short& lo) {
    union { float f; uint32_t u; } x;
    x.f = f;
    uint32_t uh = x.u + 0x7FFFu + ((x.u >> 16) & 1u);
    hi = (short)(uh >> 16);
    union { uint32_t u; float f; } hf;
    hf.u = (uh >> 16) << 16;
    float r = f - hf.f;
    union { float f; uint32_t u; } y;
    y.f = r;
    uint32_t ul = y.u + 0x7FFFu + ((y.u >> 16) & 1u);
    lo = (short)(ul >> 16);
}

__device__ __forceinline__ u16 f2bf(float f) {  // RNE (== hi part of split)
    union { float f; uint32_t u; } x;
    x.f = f;
    uint32_t r = x.u + 0x7FFFu + ((x.u >> 16) & 1u);
    return (u16)(r >> 16);
}

__device__ __forceinline__ float bf2f(u16 h) {
    union { uint32_t u; float f; } x;
    x.u = ((uint32_t)h) << 16;
    return x.f;
}

// accumulate a packed pair of bf16 channels (low half -> a0, high half -> a1)
__device__ __forceinline__ void acc2(uint32_t u, float& a0, float& a1) {
    union { uint32_t u; float f; } lo, hi;
    lo.u = u << 16;
    hi.u = u & 0xFFFF0000u;
    a0 += lo.f;
    a1 += hi.f;
}

// ---------------- weight pre-split into MFMA B-fragment layout ----------------
struct WDesc {
    const float* W;
    short* fh;
    short* fl;
    int din, dout, transb, base, total;  // base/total in short8 groups
};
struct WPrepArgs { WDesc d[6]; };

static __global__ void k_wprep(WPrepArgs args) {
    int tid = blockIdx.x * 256 + threadIdx.x;
#pragma unroll
    for (int i = 0; i < 6; i++) {
        const WDesc& D = args.d[i];
        if (tid >= D.base && tid < D.base + D.total) {
            int local = tid - D.base;
            int lane = local & 63;
            int rest = local >> 6;
            int kst = D.din >> 5;
            int ks = rest % kst;
            int ntile = rest / kst;
            int n = ntile * 16 + (lane & 15);
            int k0 = ks * 32 + (lane >> 4) * 8;
#pragma unroll
            for (int j = 0; j < 8; j++) {
                int k = k0 + j;
                float v = D.transb ? D.W[(size_t)n * D.din + k]
                                   : D.W[(size_t)k * D.dout + n];
                short h, l;
                split_bf16(v, h, l);
                D.fh[(size_t)local * 8 + j] = h;
                D.fl[(size_t)local * 8 + j] = l;
            }
        }
    }
}

// ---------------- MFMA GEMM: LDS-free, B in registers ------------------------
// AMODE: 1 = fp32 input, on-the-fly RNE, 2 MFMAs/K-step (G1 only)
//        2 = two-plane split input (3 MFMAs, lossless vs fp32 to 2^-16)
// OMODE: 0 = fp32 out, 1 = hi plane only (payload), 2 = hi+lo planes
template <int DIN, int DOUT, int MT, int AMODE, int OMODE, bool RESID, bool BIAS, bool SCALE>
__global__ __launch_bounds__(256, 3) void k_mgemm(const void* __restrict__ Av,
                                                  const short* __restrict__ fh,
                                                  const short* __restrict__ fl,
                                                  const float* __restrict__ bias,
                                                  const float* __restrict__ dinv,
                                                  void* __restrict__ C) {
    static_assert(!RESID || DIN == DOUT, "residual needs square");
    constexpr int KST = DIN / 32;
    constexpr int NTW = DOUT / 64;
    const int t = threadIdx.x;
    const int wave = t >> 6;
    const int lane = t & 63;
    const int r16 = lane & 15;
    const int kq = lane >> 4;

    const float* Af = (const float*)Av;
    const u16*   Ah = (const u16*)Av;
    const u16*   Al = Ah + (size_t)NN * DIN;

    short8 bh[NTW][KST], bl[NTW][KST];
#pragma unroll
    for (int nt = 0; nt < NTW; nt++) {
        int ntile = wave * NTW + nt;
#pragma unroll
        for (int ks = 0; ks < KST; ks++) {
            size_t o = ((size_t)(ntile * KST + ks) * 64 + lane) * 8;
            bh[nt][ks] = *(const short8*)(fh + o);
            bl[nt][ks] = *(const short8*)(fl + o);
        }
    }

    const int m0b = blockIdx.x * (MT * 16);
#pragma unroll
    for (int mt = 0; mt < MT; mt++) {
        const int m0 = m0b + mt * 16;
        if (m0 >= NN) break;
        const int ra = min(m0 + r16, NN - 1);  // clamp; stores guarded

        floatx4 acc[NTW];
#pragma unroll
        for (int nt = 0; nt < NTW; nt++) acc[nt] = (floatx4){0.f, 0.f, 0.f, 0.f};

        if constexpr (AMODE == 1) {
            const float* Ap = Af + (size_t)ra * DIN + kq * 8;
#pragma unroll
            for (int ks = 0; ks < KST; ks++) {
                float4 f0 = *(const float4*)(Ap + ks * 32);
                float4 f1 = *(const float4*)(Ap + ks * 32 + 4);
                float fe[8] = {f0.x, f0.y, f0.z, f0.w, f1.x, f1.y, f1.z, f1.w};
                short8 ah;
#pragma unroll
                for (int j = 0; j < 8; j++) ah[j] = (short)f2bf(fe[j]);
#pragma unroll
                for (int nt = 0; nt < NTW; nt++) {
                    acc[nt] = __builtin_amdgcn_mfma_f32_16x16x32_bf16(ah, bh[nt][ks], acc[nt], 0, 0, 0);
                    acc[nt] = __builtin_amdgcn_mfma_f32_16x16x32_bf16(ah, bl[nt][ks], acc[nt], 0, 0, 0);
                }
            }
        } else {
            const u16* Aph = Ah + (size_t)ra * DIN + kq * 8;
            const u16* Apl = Al + (size_t)ra * DIN + kq * 8;
#pragma unroll
            for (int ks = 0; ks < KST; ks++) {
                short8 ah = *(const short8*)(Aph + ks * 32);
                short8 al = *(const short8*)(Apl + ks * 32);
#pragma unroll
                for (int nt = 0; nt < NTW; nt++) {
                    acc[nt] = __builtin_amdgcn_mfma_f32_16x16x32_bf16(ah, bh[nt][ks], acc[nt], 0, 0, 0);
                    acc[nt] = __builtin_amdgcn_mfma_f32_16x16x32_bf16(ah, bl[nt][ks], acc[nt], 0, 0, 0);
                    acc[nt] = __builtin_amdgcn_mfma_f32_16x16x32_bf16(al, bh[nt][ks], acc[nt], 0, 0, 0);
                }
            }
        }

        // C/D layout: row = kq*4 + r, col = r16 (verified)
#pragma unroll
        for (int nt = 0; nt < NTW; nt++) {
            int col = (wave * NTW + nt) * 16 + r16;
#pragma unroll
            for (int r = 0; r < 4; r++) {
                int row = m0 + kq * 4 + r;
                if (row < NN) {
                    float v = acc[nt][r];
                    if constexpr (RESID) {
                        size_t ri = (size_t)row * DIN + col;
                        v = fmaxf(v + bf2f(Ah[ri]) + bf2f(Al[ri]), 0.f);
                    }
                    if constexpr (BIAS) v = fmaxf(v + bias[col], 0.f);
                    if constexpr (SCALE) v *= dinv[row];
                    size_t oi = (size_t)row * DOUT + col;
                    if constexpr (OMODE == 0) {
                        ((float*)C)[oi] = v;
                    } else if constexpr (OMODE == 1) {
                        ((u16*)C)[oi] = f2bf(v);
                    } else {
                        short h, l;
                        split_bf16(v, h, l);
                        ((u16*)C)[oi] = (u16)h;
                        ((u16*)C)[(size_t)NN * DOUT + oi] = (u16)l;
                    }
                }
            }
        }
    }
}

// ---------------- fused GEMM pair: C = ep2( ep1(A@W1') @ W2' ) ---------------
template <int DIN, int DMID, int DOUT, int MT, bool RESID1, bool BIAS1,
          bool SCALE2, bool RESID2, int OMODE2>
__global__ __launch_bounds__(256, 3) void k_mfused(const u16* __restrict__ Ahp,
                                                   const short* __restrict__ f1h,
                                                   const short* __restrict__ f1l,
                                                   const short* __restrict__ f2h,
                                                   const short* __restrict__ f2l,
                                                   const float* __restrict__ bias1,
                                                   const float* __restrict__ dinv,
                                                   void* __restrict__ C) {
    static_assert(!RESID1 || DIN == DMID, "resid1 needs square stage1");
    static_assert(!RESID2 || DMID == DOUT, "resid2 needs square stage2");
    constexpr int KST1 = DIN / 32;
    constexpr int NTW1 = DMID / 64;
    constexpr int KST2 = DMID / 32;
    constexpr int NTW2 = DOUT / 64;
    constexpr int LDW = DMID + 8;  // u16 stride: 16B-aligned rows, 4-bank skew
    __shared__ u16 ldsh[16][LDW];
    __shared__ u16 ldsl[16][LDW];

    const u16* Alp = Ahp + (size_t)NN * DIN;

    const int t = threadIdx.x;
    const int wave = t >> 6;
    const int lane = t & 63;
    const int r16 = lane & 15;
    const int kq = lane >> 4;

    short8 b1h[NTW1][KST1], b1l[NTW1][KST1];
#pragma unroll
    for (int nt = 0; nt < NTW1; nt++) {
        int ntile = wave * NTW1 + nt;
#pragma unroll
        for (int ks = 0; ks < KST1; ks++) {
            size_t o = ((size_t)(ntile * KST1 + ks) * 64 + lane) * 8;
            b1h[nt][ks] = *(const short8*)(f1h + o);
            b1l[nt][ks] = *(const short8*)(f1l + o);
        }
    }
    short8 b2h[NTW2][KST2], b2l[NTW2][KST2];
#pragma unroll
    for (int nt = 0; nt < NTW2; nt++) {
        int ntile = wave * NTW2 + nt;
#pragma unroll
        for (int ks = 0; ks < KST2; ks++) {
            size_t o = ((size_t)(ntile * KST2 + ks) * 64 + lane) * 8;
            b2h[nt][ks] = *(const short8*)(f2h + o);
            b2l[nt][ks] = *(const short8*)(f2l + o);
        }
    }

    const int m0b = blockIdx.x * (MT * 16);
#pragma unroll 1
    for (int mt = 0; mt < MT; mt++) {
        const int m0 = m0b + mt * 16;
        if (m0 >= NN) break;
        const int ra = min(m0 + r16, NN - 1);

        // ---- stage 1: acc1 = A @ W1' ----
        floatx4 acc1[NTW1];
#pragma unroll
        for (int nt = 0; nt < NTW1; nt++) acc1[nt] = (floatx4){0.f, 0.f, 0.f, 0.f};
        {
            const u16* Aph = Ahp + (size_t)ra * DIN + kq * 8;
            const u16* Apl = Alp + (size_t)ra * DIN + kq * 8;
#pragma unroll
            for (int ks = 0; ks < KST1; ks++) {
                short8 ah = *(const short8*)(Aph + ks * 32);
                short8 al = *(const short8*)(Apl + ks * 32);
#pragma unroll
                for (int nt = 0; nt < NTW1; nt++) {
                    acc1[nt] = __builtin_amdgcn_mfma_f32_16x16x32_bf16(ah, b1h[nt][ks], acc1[nt], 0, 0, 0);
                    acc1[nt] = __builtin_amdgcn_mfma_f32_16x16x32_bf16(ah, b1l[nt][ks], acc1[nt], 0, 0, 0);
                    acc1[nt] = __builtin_amdgcn_mfma_f32_16x16x32_bf16(al, b1h[nt][ks], acc1[nt], 0, 0, 0);
                }
            }
        }
        // ---- epilogue 1 -> LDS planes (split) ----
#pragma unroll
        for (int nt = 0; nt < NTW1; nt++) {
            int col = (wave * NTW1 + nt) * 16 + r16;
#pragma unroll
            for (int r = 0; r < 4; r++) {
                int row = m0 + kq * 4 + r;
                float v = acc1[nt][r];
                if constexpr (RESID1) {
                    if (row < NN) {
                        size_t ri = (size_t)row * DIN + col;
                        v = fmaxf(v + bf2f(Ahp[ri]) + bf2f(Alp[ri]), 0.f);
                    }
                }
                if constexpr (BIAS1) v = fmaxf(v + bias1[col], 0.f);
                short h, l;
                split_bf16(v, h, l);
                ldsh[kq * 4 + r][col] = (u16)h;
                ldsl[kq * 4 + r][col] = (u16)l;
            }
        }
        __syncthreads();

        // ---- stage 2: acc2 = mid @ W2' (A-frags from LDS planes) ----
        floatx4 acc2[NTW2];
#pragma unroll
        for (int nt = 0; nt < NTW2; nt++) acc2[nt] = (floatx4){0.f, 0.f, 0.f, 0.f};
#pragma unroll
        for (int ks = 0; ks < KST2; ks++) {
            short8 ah = *(const short8*)&ldsh[r16][ks * 32 + kq * 8];
            short8 al = *(const short8*)&ldsl[r16][ks * 32 + kq * 8];
#pragma unroll
            for (int nt = 0; nt < NTW2; nt++) {
                acc2[nt] = __builtin_amdgcn_mfma_f32_16x16x32_bf16(ah, b2h[nt][ks], acc2[nt], 0, 0, 0);
                acc2[nt] = __builtin_amdgcn_mfma_f32_16x16x32_bf16(ah, b2l[nt][ks], acc2[nt], 0, 0, 0);
                acc2[nt] = __builtin_amdgcn_mfma_f32_16x16x32_bf16(al, b2h[nt][ks], acc2[nt], 0, 0, 0);
            }
        }

        // ---- epilogue 2 -> C ----
#pragma unroll
        for (int nt = 0; nt < NTW2; nt++) {
            int col = (wave * NTW2 + nt) * 16 + r16;
#pragma unroll
            for (int r = 0; r < 4; r++) {
                int row = m0 + kq * 4 + r;
                if (row < NN) {
                    float v = acc2[nt][r];
                    if constexpr (RESID2)
                        v = fmaxf(v + bf2f(ldsh[kq * 4 + r][col]) + bf2f(ldsl[kq * 4 + r][col]), 0.f);
                    if constexpr (SCALE2) v *= dinv[row];
                    size_t oi = (size_t)row * DOUT + col;
                    if constexpr (OMODE2 == 0) {
                        ((float*)C)[oi] = v;
                    } else if constexpr (OMODE2 == 1) {
                        ((u16*)C)[oi] = f2bf(v);
                    } else {
                        short h, l;
                        split_bf16(v, h, l);
                        ((u16*)C)[oi] = (u16)h;
                        ((u16*)C)[(size_t)NN * DOUT + oi] = (u16)l;
                    }
                }
            }
        }
        __syncthreads();  // protect LDS before next mt overwrites
    }
}

// ---------------- GCN aggregation: bf16 gather payload, fp32 accumulate -------
// Round-7: gather unroll deepened 8 -> 16 outstanding loads per wave (VGPR was
// 20 — far under budget; agg was latency-starved at 3.6 TB/s). Sum order per
// node is unchanged (strictly increasing e), so results are bit-identical.
template <int D, bool BIAS_RELU>
__global__ __launch_bounds__(256) void k_agg(const u16* __restrict__ hs,
                                             const float* __restrict__ dinv,
                                             const int* __restrict__ row_ptr,
                                             const int* __restrict__ csr_src,
                                             const float* __restrict__ bias,
                                             u16* __restrict__ outh) {
    u16* outl = outh + (size_t)NN * D;
    int node = blockIdx.x * 4 + (threadIdx.x >> 6);
    int lane = threadIdx.x & 63;
    if (node >= NN) return;

    if constexpr (D == 128) {
        const int off = lane * 2;
        float a0 = 0.f, a1 = 0.f;
        {
            uint32_t u = ((const uint32_t*)(hs + (size_t)node * D))[lane];
            acc2(u, a0, a1);
        }
        int e = row_ptr[node];
        const int end = row_ptr[node + 1];
        for (; e + 16 <= end; e += 16) {
            int s[16];
#pragma unroll
            for (int i = 0; i < 16; i++) s[i] = csr_src[e + i];
            uint32_t v[16];
#pragma unroll
            for (int i = 0; i < 16; i++) v[i] = ((const uint32_t*)(hs + (size_t)s[i] * D))[lane];
#pragma unroll
            for (int i = 0; i < 16; i++) acc2(v[i], a0, a1);
        }
        for (; e + 8 <= end; e += 8) {
            int s[8];
#pragma unroll
            for (int i = 0; i < 8; i++) s[i] = csr_src[e + i];
            uint32_t v[8];
#pragma unroll
            for (int i = 0; i < 8; i++) v[i] = ((const uint32_t*)(hs + (size_t)s[i] * D))[lane];
#pragma unroll
            for (int i = 0; i < 8; i++) acc2(v[i], a0, a1);
        }
        for (; e + 4 <= end; e += 4) {
            int s[4];
#pragma unroll
            for (int i = 0; i < 4; i++) s[i] = csr_src[e + i];
            uint32_t v[4];
#pragma unroll
            for (int i = 0; i < 4; i++) v[i] = ((const uint32_t*)(hs + (size_t)s[i] * D))[lane];
#pragma unroll
            for (int i = 0; i < 4; i++) acc2(v[i], a0, a1);
        }
        for (; e < end; e++) {
            int s = csr_src[e];
            uint32_t u = ((const uint32_t*)(hs + (size_t)s * D))[lane];
            acc2(u, a0, a1);
        }
        const float di = dinv[node];
        a0 *= di;
        a1 *= di;
        if constexpr (BIAS_RELU) {
            a0 = fmaxf(a0 + bias[off], 0.f);
            a1 = fmaxf(a1 + bias[off + 1], 0.f);
        }
        short h0, l0, h1, l1;
        split_bf16(a0, h0, l0);
        split_bf16(a1, h1, l1);
        ushort2 wh, wl;
        wh.x = (u16)h0; wh.y = (u16)h1;
        wl.x = (u16)l0; wl.y = (u16)l1;
        *(ushort2*)(outh + (size_t)node * D + off) = wh;
        *(ushort2*)(outl + (size_t)node * D + off) = wl;
    } else {
        // D == 64: halves handle alternating edges; lane owns ch {2*l32, 2*l32+1}
        const int half = lane >> 5;
        const int l32 = lane & 31;
        float a0 = 0.f, a1 = 0.f;
        if (half == 0) {
            uint32_t u = ((const uint32_t*)(hs + (size_t)node * D))[l32];
            acc2(u, a0, a1);
        }
        int e = row_ptr[node];
        const int end = row_ptr[node + 1];
        for (; e + 16 <= end; e += 16) {
            int s[8];
#pragma unroll
            for (int i = 0; i < 8; i++) s[i] = csr_src[e + half + 2 * i];
            uint32_t v[8];
#pragma unroll
            for (int i = 0; i < 8; i++) v[i] = ((const uint32_t*)(hs + (size_t)s[i] * D))[l32];
#pragma unroll
            for (int i = 0; i < 8; i++) acc2(v[i], a0, a1);
        }
        for (; e + 8 <= end; e += 8) {
            int s[4];
#pragma unroll
            for (int i = 0; i < 4; i++) s[i] = csr_src[e + half + 2 * i];
            uint32_t v[4];
#pragma unroll
            for (int i = 0; i < 4; i++) v[i] = ((const uint32_t*)(hs + (size_t)s[i] * D))[l32];
#pragma unroll
            for (int i = 0; i < 4; i++) acc2(v[i], a0, a1);
        }
        for (; e + 2 <= end; e += 2) {
            int s = csr_src[e + half];
            uint32_t u = ((const uint32_t*)(hs + (size_t)s * D))[l32];
            acc2(u, a0, a1);
        }
        if (e < end && half == 0) {
            int s = csr_src[e];
            uint32_t u = ((const uint32_t*)(hs + (size_t)s * D))[l32];
            acc2(u, a0, a1);
        }
        a0 += __shfl_xor(a0, 32, 64);
        a1 += __shfl_xor(a1, 32, 64);
        if (half == 0) {
            const int off = l32 * 2;
            const float di = dinv[node];
            a0 *= di;
            a1 *= di;
            if constexpr (BIAS_RELU) {
                a0 = fmaxf(a0 + bias[off], 0.f);
                a1 = fmaxf(a1 + bias[off + 1], 0.f);
            }
            short h0, l0, h1, l1;
            split_bf16(a0, h0, l0);
            split_bf16(a1, h1, l1);
            ushort2 wh, wl;
            wh.x = (u16)h0; wh.y = (u16)h1;
            wl.x = (u16)l0; wl.y = (u16)l1;
            *(ushort2*)(outh + (size_t)node * D + off) = wh;
            *(ushort2*)(outl + (size_t)node * D + off) = wl;
        }
    }
}

// ---------------- launch ----------------

extern "C" void kernel_launch(void* const* d_in, const int* in_sizes, int n_in,
                              void* d_out, int out_size, void* d_ws, size_t ws_size,
                              hipStream_t stream) {
    const float* x   = (const float*)d_in[0];
    const int*   ei  = (const int*)d_in[1];
    const float* g1w = (const float*)d_in[2];
    const float* g1b = (const float*)d_in[3];
    const float* f2w = (const float*)d_in[4];
    const float* g3w = (const float*)d_in[5];
    const float* g3b = (const float*)d_in[6];
    const float* f4w = (const float*)d_in[7];
    const float* g5w = (const float*)d_in[8];
    const float* g5b = (const float*)d_in[9];
    const float* f6w = (const float*)d_in[10];
    float* out = (float*)d_out;

    const int* src = ei;       // edge_index[0]
    const int* dst = ei + NE;  // edge_index[1]

    char* p = (char*)d_ws;
    auto alloc = [&](size_t bytes) -> void* {
        void* r = (void*)p;
        p += (bytes + 255) & ~(size_t)255;
        return r;
    };
    float* dinv    = (float*)alloc(NN * 4);
    int*   row_ptr = (int*)alloc((NN + 1) * 4);
    int*   gcur    = (int*)alloc((NBB + 1) * 4);
    int*   gbase   = (int*)alloc((NBB + 1) * 4);
    int*   csr     = (int*)alloc(NE * 4);
    short* wfh     = (short*)alloc(69632 * 2);
    short* wfl     = (short*)alloc(69632 * 2);
    // bufA/bufB: 4B/elem budget = room for hi+lo u16 planes at D=128
    char* bufA = (char*)alloc((size_t)NN * 128 * 4);
    char* bufB = (char*)alloc((size_t)NN * 128 * 4);
    // fixed-stride edge staging (391*5120*8B = 16.0 MB) aliases bufB: fully
    // consumed by k_blocal2/k_bfill2 before agg1 writes bufB (stream-ordered).
    int2* staging  = (int2*)bufB;

    const int gE4 = (NE + 4095) / 4096;      // 391
    const int gA  = NN / 4;                  // 25000
    const int gM  = (NN + 31) / 32;          // 3125 (MT=2: 32 rows/block, exact)

    // graph preprocessing (5 dispatches; was 9)
    k_zero<<<1, 512, 0, stream>>>(gcur);
    k_bscatterF<<<gE4, 1024, 0, stream>>>(src, dst, gcur, staging);
    k_blocal2<<<NBB, 1024, 0, stream>>>(staging, gcur, dinv, row_ptr);
    k_bscanB<<<1, 512, 0, stream>>>(gcur, gbase, row_ptr);
    k_bfill2<<<NBB, 1024, 0, stream>>>(staging, gcur, gbase, row_ptr, csr);

    // weight fragment prep
    {
        WPrepArgs a;
        int  eoff[6] = {0, 16384, 32768, 40960, 45056, 53248};
        int  base[6] = {0, 2048, 4096, 5120, 5632, 6656};
        int  tot[6]  = {2048, 2048, 1024, 512, 1024, 2048};
        const float* Ws[6] = {g1w, f2w, g3w, f4w, g5w, f6w};
        int din[6]  = {128, 128, 128, 64, 64, 128};
        int dout[6] = {128, 128, 64, 64, 128, 128};
        int trb[6]  = {0, 1, 0, 1, 0, 1};
        for (int i = 0; i < 6; i++) {
            a.d[i] = WDesc{Ws[i], wfh + eoff[i], wfl + eoff[i],
                           din[i], dout[i], trb[i], base[i], tot[i]};
        }
        k_wprep<<<(8704 + 255) / 256, 256, 0, stream>>>(a);
    }

    // G1: h1 = bf16(dinv * (x@W1))           [fp32 in, hi-plane payload out]
    k_mgemm<128, 128, 2, 1, 1, false, false, true><<<gM, 256, 0, stream>>>(
        x, wfh + 0, wfl + 0, nullptr, dinv, bufA);
    // agg1: z1 = relu(dinv*agg(h1)+b1)       [two-plane out]
    k_agg<128, true><<<gA, 256, 0, stream>>>((const u16*)bufA, dinv, row_ptr, csr, g1b, (u16*)bufB);
    // fused fc2+G3: z1' = relu(z1 + z1@W2^T); h2 = bf16(dinv*(z1'@W3))
    k_mfused<128, 128, 64, 2, true, false, true, false, 1><<<gM, 256, 0, stream>>>(
        (const u16*)bufB, wfh + 16384, wfl + 16384, wfh + 32768, wfl + 32768,
        nullptr, dinv, bufA);
    // agg2: z2 = relu(dinv*agg(h2)+b3)       [two-plane out]
    k_agg<64, true><<<gA, 256, 0, stream>>>((const u16*)bufA, dinv, row_ptr, csr, g3b, (u16*)bufB);
    // fc4: p3 = bf16(dinv * relu(z2 + z2@W4^T)) [two-plane in+resid, payload out]
    k_mgemm<64, 64, 2, 2, 1, true, false, true><<<gM, 256, 0, stream>>>(
        bufB, wfh + 40960, wfl + 40960, nullptr, dinv, bufA);
    // agg3: a3 = agg(p3)                     [two-plane out]
    k_agg<64, false><<<gA, 256, 0, stream>>>((const u16*)bufA, dinv, row_ptr, csr, nullptr, (u16*)bufB);
    // fused G5+fc6: z3 = relu(a3@W5+b5); out = relu(z3 + z3@W6^T)  [fp32 out]
    k_mfused<64, 128, 128, 2, false, true, false, true, 0><<<gM, 256, 0, stream>>>(
        (const u16*)bufB, wfh + 45056, wfl + 45056, wfh + 53248, wfl + 53248,
        g5b, nullptr, out);
}

// Round 8
// 447.356 us; speedup vs baseline: 1.1365x; 1.0729x over previous
//
#include <hip/hip_runtime.h>
#include <cstdint>
#include <cstddef>

#define NN 100000
#define NE 1600000
#define NBB 391      // dst buckets of 256 nodes: ceil(100000/256)
#define BSTRIDE 5120 // staging/csr slots per bucket; E[cnt]=4092, sd=64 -> 16-sigma margin

typedef short short8 __attribute__((ext_vector_type(8)));
typedef float floatx4 __attribute__((ext_vector_type(4)));
typedef unsigned short u16;
typedef uint32_t u32;

// ---------------- bf16 helpers ----------------
__device__ __forceinline__ void split_bf16(float f, short& hi, short& lo) {
    union { float f; uint32_t u; } x;
    x.f = f;
    uint32_t uh = x.u + 0x7FFFu + ((x.u >> 16) & 1u);
    hi = (short)(uh >> 16);
    union { uint32_t u; float f; } hf;
    hf.u = (uh >> 16) << 16;
    float r = f - hf.f;
    union { float f; uint32_t u; } y;
    y.f = r;
    uint32_t ul = y.u + 0x7FFFu + ((y.u >> 16) & 1u);
    lo = (short)(ul >> 16);
}

__device__ __forceinline__ u16 f2bf(float f) {  // RNE (== hi part of split)
    union { float f; uint32_t u; } x;
    x.f = f;
    uint32_t r = x.u + 0x7FFFu + ((x.u >> 16) & 1u);
    return (u16)(r >> 16);
}

__device__ __forceinline__ float bf2f(u16 h) {
    union { uint32_t u; float f; } x;
    x.u = ((uint32_t)h) << 16;
    return x.f;
}

// accumulate a packed pair of bf16 channels (low half -> a0, high half -> a1)
__device__ __forceinline__ void acc2(uint32_t u, float& a0, float& a1) {
    union { uint32_t u; float f; } lo, hi;
    lo.u = u << 16;
    hi.u = u & 0xFFFF0000u;
    a0 += lo.f;
    a1 += hi.f;
}

// ---------------- weight pre-split + gcur zero (merged; runs first) ----------
struct WDesc {
    const float* W;
    short* fh;
    short* fl;
    int din, dout, transb, base, total;  // base/total in short8 groups
};
struct WPrepArgs { WDesc d[6]; int* gcur; };

static __global__ void k_wprep(WPrepArgs args) {
    int tid = blockIdx.x * 256 + threadIdx.x;
    if (tid <= NBB) args.gcur[tid] = 0;  // merged k_zero
#pragma unroll
    for (int i = 0; i < 6; i++) {
        const WDesc& D = args.d[i];
        if (tid >= D.base && tid < D.base + D.total) {
            int local = tid - D.base;
            int lane = local & 63;
            int rest = local >> 6;
            int kst = D.din >> 5;
            int ks = rest % kst;
            int ntile = rest / kst;
            int n = ntile * 16 + (lane & 15);
            int k0 = ks * 32 + (lane >> 4) * 8;
#pragma unroll
            for (int j = 0; j < 8; j++) {
                int k = k0 + j;
                float v = D.transb ? D.W[(size_t)n * D.din + k]
                                   : D.W[(size_t)k * D.dout + n];
                short h, l;
                split_bf16(v, h, l);
                D.fh[(size_t)local * 8 + j] = h;
                D.fl[(size_t)local * 8 + j] = l;
            }
        }
    }
}

// ---------------- graph preprocessing (fixed-stride buckets + fixed-stride CSR)

// scatter edges into fixed-stride bucket staging (int2 = src,dst); gcur[b]=count
static __global__ __launch_bounds__(1024) void k_bscatterF(const int* __restrict__ src,
                                                           const int* __restrict__ dst,
                                                           int* __restrict__ gcur,
                                                           int2* __restrict__ staging) {
    __shared__ int h[NBB + 1];
    __shared__ int base[NBB + 1];
    int t = threadIdx.x;
    for (int i = t; i < NBB; i += 1024) h[i] = 0;
    __syncthreads();
    int e0 = blockIdx.x * 4096;
    int b[4], l[4], sv[4], dv[4];
#pragma unroll
    for (int j = 0; j < 4; j++) {
        int e = e0 + j * 1024 + t;
        b[j] = -1;
        if (e < NE) {
            sv[j] = src[e];
            dv[j] = dst[e];
            b[j] = dv[j] >> 8;
            l[j] = atomicAdd(&h[b[j]], 1);
        }
    }
    __syncthreads();
    for (int i = t; i < NBB; i += 1024)
        if (h[i]) base[i] = atomicAdd(&gcur[i], h[i]);
    __syncthreads();
#pragma unroll
    for (int j = 0; j < 4; j++)
        if (b[j] >= 0)
            staging[(size_t)b[j] * BSTRIDE + base[b[j]] + l[j]] = make_int2(sv[j], dv[j]);
}

// per-bucket: degree counts (LDS), dinv, ABSOLUTE fixed-stride row_ptr/row_end
static __global__ __launch_bounds__(1024) void k_blocal2(const int2* __restrict__ staging,
                                                         const int* __restrict__ gcur,
                                                         float* __restrict__ dinv,
                                                         int* __restrict__ row_ptr,
                                                         int* __restrict__ row_end) {
    __shared__ int cnt[256];
    __shared__ int sc[256];
    int b = blockIdx.x;
    int t = threadIdx.x;
    if (t < 256) cnt[t] = 0;
    __syncthreads();
    const int n = gcur[b];
    const int base = b * BSTRIDE;
    for (int i = base + t; i < base + n; i += 1024)
        atomicAdd(&cnt[staging[i].y & 255], 1);
    __syncthreads();
    int myc = (t < 256) ? cnt[t] : 0;
    if (t < 256) sc[t] = myc;
    __syncthreads();
    for (int off = 1; off < 256; off <<= 1) {
        int x = 0;
        if (t < 256 && t >= off) x = sc[t - off];
        __syncthreads();
        if (t < 256) sc[t] += x;
        __syncthreads();
    }
    if (t < 256) {
        int node = (b << 8) + t;
        if (node < NN) {
            dinv[node] = rsqrtf((float)(myc + 1));  // +1 self loop
            int st = base + sc[t] - myc;            // absolute (fixed-stride CSR)
            row_ptr[node] = st;
            row_end[node] = st + myc;
        }
    }
}

// per-bucket CSR fill into fixed-stride csr (ranks via LDS atomics)
static __global__ __launch_bounds__(1024) void k_bfill2(const int2* __restrict__ staging,
                                                        const int* __restrict__ gcur,
                                                        const int* __restrict__ row_ptr,
                                                        int* __restrict__ csr_src) {
    __shared__ int cnt[256];
    __shared__ int lrp[256];
    int b = blockIdx.x;
    int t = threadIdx.x;
    if (t < 256) {
        cnt[t] = 0;
        int node = (b << 8) + t;
        lrp[t] = (node < NN) ? row_ptr[node] : 0;
    }
    __syncthreads();
    const int n = gcur[b];
    const int base = b * BSTRIDE;
    for (int i = base + t; i < base + n; i += 1024) {
        int2 ed = staging[i];
        int loc = ed.y & 255;
        int r = atomicAdd(&cnt[loc], 1);
        csr_src[lrp[loc] + r] = ed.x;
    }
}

// ---------------- MFMA GEMM: LDS-free, B in registers ------------------------
// AMODE: 1 = fp32 input, on-the-fly RNE (2 MFMAs/K-step)
//        2 = two-plane split input (3 MFMAs, lossless to 2^-16)
//        3 = single-plane bf16 input (2 MFMAs) — interior activations
// OMODE: 0 = fp32 out, 1 = hi plane only (payload/single), 2 = hi+lo planes
template <int DIN, int DOUT, int MT, int AMODE, int OMODE, bool RESID, bool BIAS, bool SCALE>
__global__ __launch_bounds__(256, 3) void k_mgemm(const void* __restrict__ Av,
                                                  const short* __restrict__ fh,
                                                  const short* __restrict__ fl,
                                                  const float* __restrict__ bias,
                                                  const float* __restrict__ dinv,
                                                  void* __restrict__ C) {
    static_assert(!RESID || DIN == DOUT, "residual needs square");
    constexpr int KST = DIN / 32;
    constexpr int NTW = DOUT / 64;
    const int t = threadIdx.x;
    const int wave = t >> 6;
    const int lane = t & 63;
    const int r16 = lane & 15;
    const int kq = lane >> 4;

    const float* Af = (const float*)Av;
    const u16*   Ah = (const u16*)Av;
    const u16*   Al = Ah + (size_t)NN * DIN;

    short8 bh[NTW][KST], bl[NTW][KST];
#pragma unroll
    for (int nt = 0; nt < NTW; nt++) {
        int ntile = wave * NTW + nt;
#pragma unroll
        for (int ks = 0; ks < KST; ks++) {
            size_t o = ((size_t)(ntile * KST + ks) * 64 + lane) * 8;
            bh[nt][ks] = *(const short8*)(fh + o);
            bl[nt][ks] = *(const short8*)(fl + o);
        }
    }

    const int m0b = blockIdx.x * (MT * 16);
#pragma unroll
    for (int mt = 0; mt < MT; mt++) {
        const int m0 = m0b + mt * 16;
        if (m0 >= NN) break;
        const int ra = min(m0 + r16, NN - 1);  // clamp; stores guarded

        floatx4 acc[NTW];
#pragma unroll
        for (int nt = 0; nt < NTW; nt++) acc[nt] = (floatx4){0.f, 0.f, 0.f, 0.f};

        if constexpr (AMODE == 1) {
            const float* Ap = Af + (size_t)ra * DIN + kq * 8;
#pragma unroll
            for (int ks = 0; ks < KST; ks++) {
                float4 f0 = *(const float4*)(Ap + ks * 32);
                float4 f1 = *(const float4*)(Ap + ks * 32 + 4);
                float fe[8] = {f0.x, f0.y, f0.z, f0.w, f1.x, f1.y, f1.z, f1.w};
                short8 ah;
#pragma unroll
                for (int j = 0; j < 8; j++) ah[j] = (short)f2bf(fe[j]);
#pragma unroll
                for (int nt = 0; nt < NTW; nt++) {
                    acc[nt] = __builtin_amdgcn_mfma_f32_16x16x32_bf16(ah, bh[nt][ks], acc[nt], 0, 0, 0);
                    acc[nt] = __builtin_amdgcn_mfma_f32_16x16x32_bf16(ah, bl[nt][ks], acc[nt], 0, 0, 0);
                }
            }
        } else if constexpr (AMODE == 3) {
            const u16* Aph = Ah + (size_t)ra * DIN + kq * 8;
#pragma unroll
            for (int ks = 0; ks < KST; ks++) {
                short8 ah = *(const short8*)(Aph + ks * 32);
#pragma unroll
                for (int nt = 0; nt < NTW; nt++) {
                    acc[nt] = __builtin_amdgcn_mfma_f32_16x16x32_bf16(ah, bh[nt][ks], acc[nt], 0, 0, 0);
                    acc[nt] = __builtin_amdgcn_mfma_f32_16x16x32_bf16(ah, bl[nt][ks], acc[nt], 0, 0, 0);
                }
            }
        } else {
            const u16* Aph = Ah + (size_t)ra * DIN + kq * 8;
            const u16* Apl = Al + (size_t)ra * DIN + kq * 8;
#pragma unroll
            for (int ks = 0; ks < KST; ks++) {
                short8 ah = *(const short8*)(Aph + ks * 32);
                short8 al = *(const short8*)(Apl + ks * 32);
#pragma unroll
                for (int nt = 0; nt < NTW; nt++) {
                    acc[nt] = __builtin_amdgcn_mfma_f32_16x16x32_bf16(ah, bh[nt][ks], acc[nt], 0, 0, 0);
                    acc[nt] = __builtin_amdgcn_mfma_f32_16x16x32_bf16(ah, bl[nt][ks], acc[nt], 0, 0, 0);
                    acc[nt] = __builtin_amdgcn_mfma_f32_16x16x32_bf16(al, bh[nt][ks], acc[nt], 0, 0, 0);
                }
            }
        }

        // C/D layout: row = kq*4 + r, col = r16 (verified)
#pragma unroll
        for (int nt = 0; nt < NTW; nt++) {
            int col = (wave * NTW + nt) * 16 + r16;
#pragma unroll
            for (int r = 0; r < 4; r++) {
                int row = m0 + kq * 4 + r;
                if (row < NN) {
                    float v = acc[nt][r];
                    if constexpr (RESID) {
                        size_t ri = (size_t)row * DIN + col;
                        if constexpr (AMODE == 3)
                            v = fmaxf(v + bf2f(Ah[ri]), 0.f);
                        else
                            v = fmaxf(v + bf2f(Ah[ri]) + bf2f(Al[ri]), 0.f);
                    }
                    if constexpr (BIAS) v = fmaxf(v + bias[col], 0.f);
                    if constexpr (SCALE) v *= dinv[row];
                    size_t oi = (size_t)row * DOUT + col;
                    if constexpr (OMODE == 0) {
                        ((float*)C)[oi] = v;
                    } else if constexpr (OMODE == 1) {
                        ((u16*)C)[oi] = f2bf(v);
                    } else {
                        short h, l;
                        split_bf16(v, h, l);
                        ((u16*)C)[oi] = (u16)h;
                        ((u16*)C)[(size_t)NN * DOUT + oi] = (u16)l;
                    }
                }
            }
        }
    }
}

// ---------------- fused GEMM pair: C = ep2( ep1(A@W1') @ W2' ) ---------------
// A1S: stage-1 A is single-plane bf16 (2 MFMAs); MIDS: LDS mid single-plane.
template <int DIN, int DMID, int DOUT, int MT, bool A1S, bool MIDS, bool RESID1,
          bool BIAS1, bool SCALE2, bool RESID2, int OMODE2>
__global__ __launch_bounds__(256, 3) void k_mfused(const u16* __restrict__ Ahp,
                                                   const short* __restrict__ f1h,
                                                   const short* __restrict__ f1l,
                                                   const short* __restrict__ f2h,
                                                   const short* __restrict__ f2l,
                                                   const float* __restrict__ bias1,
                                                   const float* __restrict__ dinv,
                                                   void* __restrict__ C) {
    static_assert(!RESID1 || DIN == DMID, "resid1 needs square stage1");
    static_assert(!RESID2 || DMID == DOUT, "resid2 needs square stage2");
    constexpr int KST1 = DIN / 32;
    constexpr int NTW1 = DMID / 64;
    constexpr int KST2 = DMID / 32;
    constexpr int NTW2 = DOUT / 64;
    constexpr int LDW = DMID + 8;  // u16 stride: 16B-aligned rows, 4-bank skew
    __shared__ u16 ldsh[16][LDW];
    __shared__ u16 ldsl[MIDS ? 1 : 16][LDW];

    const u16* Alp = Ahp + (size_t)NN * DIN;

    const int t = threadIdx.x;
    const int wave = t >> 6;
    const int lane = t & 63;
    const int r16 = lane & 15;
    const int kq = lane >> 4;

    short8 b1h[NTW1][KST1], b1l[NTW1][KST1];
#pragma unroll
    for (int nt = 0; nt < NTW1; nt++) {
        int ntile = wave * NTW1 + nt;
#pragma unroll
        for (int ks = 0; ks < KST1; ks++) {
            size_t o = ((size_t)(ntile * KST1 + ks) * 64 + lane) * 8;
            b1h[nt][ks] = *(const short8*)(f1h + o);
            b1l[nt][ks] = *(const short8*)(f1l + o);
        }
    }
    short8 b2h[NTW2][KST2], b2l[NTW2][KST2];
#pragma unroll
    for (int nt = 0; nt < NTW2; nt++) {
        int ntile = wave * NTW2 + nt;
#pragma unroll
        for (int ks = 0; ks < KST2; ks++) {
            size_t o = ((size_t)(ntile * KST2 + ks) * 64 + lane) * 8;
            b2h[nt][ks] = *(const short8*)(f2h + o);
            b2l[nt][ks] = *(const short8*)(f2l + o);
        }
    }

    const int m0b = blockIdx.x * (MT * 16);
#pragma unroll 1
    for (int mt = 0; mt < MT; mt++) {
        const int m0 = m0b + mt * 16;
        if (m0 >= NN) break;
        const int ra = min(m0 + r16, NN - 1);

        // ---- stage 1: acc1 = A @ W1' ----
        floatx4 acc1[NTW1];
#pragma unroll
        for (int nt = 0; nt < NTW1; nt++) acc1[nt] = (floatx4){0.f, 0.f, 0.f, 0.f};
        {
            const u16* Aph = Ahp + (size_t)ra * DIN + kq * 8;
            const u16* Apl = Alp + (size_t)ra * DIN + kq * 8;
#pragma unroll
            for (int ks = 0; ks < KST1; ks++) {
                short8 ah = *(const short8*)(Aph + ks * 32);
#pragma unroll
                for (int nt = 0; nt < NTW1; nt++) {
                    acc1[nt] = __builtin_amdgcn_mfma_f32_16x16x32_bf16(ah, b1h[nt][ks], acc1[nt], 0, 0, 0);
                    acc1[nt] = __builtin_amdgcn_mfma_f32_16x16x32_bf16(ah, b1l[nt][ks], acc1[nt], 0, 0, 0);
                }
                if constexpr (!A1S) {
                    short8 al = *(const short8*)(Apl + ks * 32);
#pragma unroll
                    for (int nt = 0; nt < NTW1; nt++)
                        acc1[nt] = __builtin_amdgcn_mfma_f32_16x16x32_bf16(al, b1h[nt][ks], acc1[nt], 0, 0, 0);
                }
            }
        }
        // ---- epilogue 1 -> LDS ----
#pragma unroll
        for (int nt = 0; nt < NTW1; nt++) {
            int col = (wave * NTW1 + nt) * 16 + r16;
#pragma unroll
            for (int r = 0; r < 4; r++) {
                int row = m0 + kq * 4 + r;
                float v = acc1[nt][r];
                if constexpr (RESID1) {
                    if (row < NN) {
                        size_t ri = (size_t)row * DIN + col;
                        if constexpr (A1S)
                            v = fmaxf(v + bf2f(Ahp[ri]), 0.f);
                        else
                            v = fmaxf(v + bf2f(Ahp[ri]) + bf2f(Alp[ri]), 0.f);
                    }
                }
                if constexpr (BIAS1) v = fmaxf(v + bias1[col], 0.f);
                if constexpr (MIDS) {
                    ldsh[kq * 4 + r][col] = f2bf(v);
                } else {
                    short h, l;
                    split_bf16(v, h, l);
                    ldsh[kq * 4 + r][col] = (u16)h;
                    ldsl[kq * 4 + r][col] = (u16)l;
                }
            }
        }
        __syncthreads();

        // ---- stage 2: acc2 = mid @ W2' (A-frags from LDS) ----
        floatx4 acc2[NTW2];
#pragma unroll
        for (int nt = 0; nt < NTW2; nt++) acc2[nt] = (floatx4){0.f, 0.f, 0.f, 0.f};
#pragma unroll
        for (int ks = 0; ks < KST2; ks++) {
            short8 ah = *(const short8*)&ldsh[r16][ks * 32 + kq * 8];
#pragma unroll
            for (int nt = 0; nt < NTW2; nt++) {
                acc2[nt] = __builtin_amdgcn_mfma_f32_16x16x32_bf16(ah, b2h[nt][ks], acc2[nt], 0, 0, 0);
                acc2[nt] = __builtin_amdgcn_mfma_f32_16x16x32_bf16(ah, b2l[nt][ks], acc2[nt], 0, 0, 0);
            }
            if constexpr (!MIDS) {
                short8 al = *(const short8*)&ldsl[r16][ks * 32 + kq * 8];
#pragma unroll
                for (int nt = 0; nt < NTW2; nt++)
                    acc2[nt] = __builtin_amdgcn_mfma_f32_16x16x32_bf16(al, b2h[nt][ks], acc2[nt], 0, 0, 0);
            }
        }

        // ---- epilogue 2 -> C ----
#pragma unroll
        for (int nt = 0; nt < NTW2; nt++) {
            int col = (wave * NTW2 + nt) * 16 + r16;
#pragma unroll
            for (int r = 0; r < 4; r++) {
                int row = m0 + kq * 4 + r;
                if (row < NN) {
                    float v = acc2[nt][r];
                    if constexpr (RESID2) {
                        if constexpr (MIDS)
                            v = fmaxf(v + bf2f(ldsh[kq * 4 + r][col]), 0.f);
                        else
                            v = fmaxf(v + bf2f(ldsh[kq * 4 + r][col]) + bf2f(ldsl[kq * 4 + r][col]), 0.f);
                    }
                    if constexpr (SCALE2) v *= dinv[row];
                    size_t oi = (size_t)row * DOUT + col;
                    if constexpr (OMODE2 == 0) {
                        ((float*)C)[oi] = v;
                    } else if constexpr (OMODE2 == 1) {
                        ((u16*)C)[oi] = f2bf(v);
                    } else {
                        short h, l;
                        split_bf16(v, h, l);
                        ((u16*)C)[oi] = (u16)h;
                        ((u16*)C)[(size_t)NN * DOUT + oi] = (u16)l;
                    }
                }
            }
        }
        __syncthreads();  // protect LDS before next mt overwrites
    }
}

// ---------------- GCN aggregation: bf16 gather payload, fp32 accumulate -------
// OPL=1: single-plane bf16 out (interior); OPL=2: hi+lo planes (near-output).
template <int D, bool BIAS_RELU, int OPL>
__global__ __launch_bounds__(256) void k_agg(const u16* __restrict__ hs,
                                             const float* __restrict__ dinv,
                                             const int* __restrict__ row_ptr,
                                             const int* __restrict__ row_end,
                                             const int* __restrict__ csr_src,
                                             const float* __restrict__ bias,
                                             u16* __restrict__ outh) {
    u16* outl = outh + (size_t)NN * D;
    int node = blockIdx.x * 4 + (threadIdx.x >> 6);
    int lane = threadIdx.x & 63;
    if (node >= NN) return;

    if constexpr (D == 128) {
        const int off = lane * 2;
        float a0 = 0.f, a1 = 0.f;
        {
            uint32_t u = ((const uint32_t*)(hs + (size_t)node * D))[lane];
            acc2(u, a0, a1);
        }
        int e = row_ptr[node];
        const int end = row_end[node];
        for (; e + 16 <= end; e += 16) {
            int s[16];
#pragma unroll
            for (int i = 0; i < 16; i++) s[i] = csr_src[e + i];
            uint32_t v[16];
#pragma unroll
            for (int i = 0; i < 16; i++) v[i] = ((const uint32_t*)(hs + (size_t)s[i] * D))[lane];
#pragma unroll
            for (int i = 0; i < 16; i++) acc2(v[i], a0, a1);
        }
        for (; e + 8 <= end; e += 8) {
            int s[8];
#pragma unroll
            for (int i = 0; i < 8; i++) s[i] = csr_src[e + i];
            uint32_t v[8];
#pragma unroll
            for (int i = 0; i < 8; i++) v[i] = ((const uint32_t*)(hs + (size_t)s[i] * D))[lane];
#pragma unroll
            for (int i = 0; i < 8; i++) acc2(v[i], a0, a1);
        }
        for (; e + 4 <= end; e += 4) {
            int s[4];
#pragma unroll
            for (int i = 0; i < 4; i++) s[i] = csr_src[e + i];
            uint32_t v[4];
#pragma unroll
            for (int i = 0; i < 4; i++) v[i] = ((const uint32_t*)(hs + (size_t)s[i] * D))[lane];
#pragma unroll
            for (int i = 0; i < 4; i++) acc2(v[i], a0, a1);
        }
        for (; e < end; e++) {
            int s = csr_src[e];
            uint32_t u = ((const uint32_t*)(hs + (size_t)s * D))[lane];
            acc2(u, a0, a1);
        }
        const float di = dinv[node];
        a0 *= di;
        a1 *= di;
        if constexpr (BIAS_RELU) {
            a0 = fmaxf(a0 + bias[off], 0.f);
            a1 = fmaxf(a1 + bias[off + 1], 0.f);
        }
        if constexpr (OPL == 1) {
            ushort2 wh;
            wh.x = f2bf(a0); wh.y = f2bf(a1);
            *(ushort2*)(outh + (size_t)node * D + off) = wh;
        } else {
            short h0, l0, h1, l1;
            split_bf16(a0, h0, l0);
            split_bf16(a1, h1, l1);
            ushort2 wh, wl;
            wh.x = (u16)h0; wh.y = (u16)h1;
            wl.x = (u16)l0; wl.y = (u16)l1;
            *(ushort2*)(outh + (size_t)node * D + off) = wh;
            *(ushort2*)(outl + (size_t)node * D + off) = wl;
        }
    } else {
        // D == 64: halves handle alternating edges; lane owns ch {2*l32, 2*l32+1}
        const int half = lane >> 5;
        const int l32 = lane & 31;
        float a0 = 0.f, a1 = 0.f;
        if (half == 0) {
            uint32_t u = ((const uint32_t*)(hs + (size_t)node * D))[l32];
            acc2(u, a0, a1);
        }
        int e = row_ptr[node];
        const int end = row_end[node];
        for (; e + 16 <= end; e += 16) {
            int s[8];
#pragma unroll
            for (int i = 0; i < 8; i++) s[i] = csr_src[e + half + 2 * i];
            uint32_t v[8];
#pragma unroll
            for (int i = 0; i < 8; i++) v[i] = ((const uint32_t*)(hs + (size_t)s[i] * D))[l32];
#pragma unroll
            for (int i = 0; i < 8; i++) acc2(v[i], a0, a1);
        }
        for (; e + 8 <= end; e += 8) {
            int s[4];
#pragma unroll
            for (int i = 0; i < 4; i++) s[i] = csr_src[e + half + 2 * i];
            uint32_t v[4];
#pragma unroll
            for (int i = 0; i < 4; i++) v[i] = ((const uint32_t*)(hs + (size_t)s[i] * D))[l32];
#pragma unroll
            for (int i = 0; i < 4; i++) acc2(v[i], a0, a1);
        }
        for (; e + 2 <= end; e += 2) {
            int s = csr_src[e + half];
            uint32_t u = ((const uint32_t*)(hs + (size_t)s * D))[l32];
            acc2(u, a0, a1);
        }
        if (e < end && half == 0) {
            int s = csr_src[e];
            uint32_t u = ((const uint32_t*)(hs + (size_t)s * D))[l32];
            acc2(u, a0, a1);
        }
        a0 += __shfl_xor(a0, 32, 64);
        a1 += __shfl_xor(a1, 32, 64);
        if (half == 0) {
            const int off = l32 * 2;
            const float di = dinv[node];
            a0 *= di;
            a1 *= di;
            if constexpr (BIAS_RELU) {
                a0 = fmaxf(a0 + bias[off], 0.f);
                a1 = fmaxf(a1 + bias[off + 1], 0.f);
            }
            if constexpr (OPL == 1) {
                ushort2 wh;
                wh.x = f2bf(a0); wh.y = f2bf(a1);
                *(ushort2*)(outh + (size_t)node * D + off) = wh;
            } else {
                short h0, l0, h1, l1;
                split_bf16(a0, h0, l0);
                split_bf16(a1, h1, l1);
                ushort2 wh, wl;
                wh.x = (u16)h0; wh.y = (u16)h1;
                wl.x = (u16)l0; wl.y = (u16)l1;
                *(ushort2*)(outh + (size_t)node * D + off) = wh;
                *(ushort2*)(outl + (size_t)node * D + off) = wl;
            }
        }
    }
}

// ---------------- launch ----------------

extern "C" void kernel_launch(void* const* d_in, const int* in_sizes, int n_in,
                              void* d_out, int out_size, void* d_ws, size_t ws_size,
                              hipStream_t stream) {
    const float* x   = (const float*)d_in[0];
    const int*   ei  = (const int*)d_in[1];
    const float* g1w = (const float*)d_in[2];
    const float* g1b = (const float*)d_in[3];
    const float* f2w = (const float*)d_in[4];
    const float* g3w = (const float*)d_in[5];
    const float* g3b = (const float*)d_in[6];
    const float* f4w = (const float*)d_in[7];
    const float* g5w = (const float*)d_in[8];
    const float* g5b = (const float*)d_in[9];
    const float* f6w = (const float*)d_in[10];
    float* out = (float*)d_out;

    const int* src = ei;       // edge_index[0]
    const int* dst = ei + NE;  // edge_index[1]

    char* p = (char*)d_ws;
    auto alloc = [&](size_t bytes) -> void* {
        void* r = (void*)p;
        p += (bytes + 255) & ~(size_t)255;
        return r;
    };
    float* dinv    = (float*)alloc(NN * 4);
    int*   row_ptr = (int*)alloc(NN * 4);
    int*   row_end = (int*)alloc(NN * 4);
    int*   gcur    = (int*)alloc((NBB + 1) * 4);
    int*   csr     = (int*)alloc((size_t)NBB * BSTRIDE * 4);  // fixed-stride CSR (8 MB)
    short* wfh     = (short*)alloc(69632 * 2);
    short* wfl     = (short*)alloc(69632 * 2);
    // bufA/bufB: 4B/elem budget = room for hi+lo u16 planes at D=128
    char* bufA = (char*)alloc((size_t)NN * 128 * 4);
    char* bufB = (char*)alloc((size_t)NN * 128 * 4);
    // fixed-stride edge staging (391*5120*8B = 16.0 MB) aliases bufB: fully
    // consumed by k_blocal2/k_bfill2 before agg1 writes bufB (stream-ordered).
    int2* staging  = (int2*)bufB;

    const int gE4 = (NE + 4095) / 4096;      // 391
    const int gA  = NN / 4;                  // 25000
    const int gM  = (NN + 31) / 32;          // 3125 (MT=2: 32 rows/block, exact)

    // weight fragment prep + gcur zero (first dispatch)
    {
        WPrepArgs a;
        int  eoff[6] = {0, 16384, 32768, 40960, 45056, 53248};
        int  base[6] = {0, 2048, 4096, 5120, 5632, 6656};
        int  tot[6]  = {2048, 2048, 1024, 512, 1024, 2048};
        const float* Ws[6] = {g1w, f2w, g3w, f4w, g5w, f6w};
        int din[6]  = {128, 128, 128, 64, 64, 128};
        int dout[6] = {128, 128, 64, 64, 128, 128};
        int trb[6]  = {0, 1, 0, 1, 0, 1};
        for (int i = 0; i < 6; i++) {
            a.d[i] = WDesc{Ws[i], wfh + eoff[i], wfl + eoff[i],
                           din[i], dout[i], trb[i], base[i], tot[i]};
        }
        a.gcur = gcur;
        k_wprep<<<(8704 + 255) / 256, 256, 0, stream>>>(a);
    }

    // graph preprocessing (3 more dispatches)
    k_bscatterF<<<gE4, 1024, 0, stream>>>(src, dst, gcur, staging);
    k_blocal2<<<NBB, 1024, 0, stream>>>(staging, gcur, dinv, row_ptr, row_end);
    k_bfill2<<<NBB, 1024, 0, stream>>>(staging, gcur, row_ptr, csr);

    // G1: h1 = bf16(dinv * (x@W1))           [fp32 in, payload out]
    k_mgemm<128, 128, 2, 1, 1, false, false, true><<<gM, 256, 0, stream>>>(
        x, wfh + 0, wfl + 0, nullptr, dinv, bufA);
    // agg1: z1 = relu(dinv*agg(h1)+b1)       [single-plane out]
    k_agg<128, true, 1><<<gA, 256, 0, stream>>>((const u16*)bufA, dinv, row_ptr, row_end, csr, g1b, (u16*)bufB);
    // fused fc2+G3: z1' = relu(z1 + z1@W2^T); h2 = bf16(dinv*(z1'@W3))
    //   [single-plane A, single-plane mid, payload out]
    k_mfused<128, 128, 64, 2, true, true, true, false, true, false, 1><<<gM, 256, 0, stream>>>(
        (const u16*)bufB, wfh + 16384, wfl + 16384, wfh + 32768, wfl + 32768,
        nullptr, dinv, bufA);
    // agg2: z2 = relu(dinv*agg(h2)+b3)       [single-plane out]
    k_agg<64, true, 1><<<gA, 256, 0, stream>>>((const u16*)bufA, dinv, row_ptr, row_end, csr, g3b, (u16*)bufB);
    // fc4: p3 = bf16(dinv * relu(z2 + z2@W4^T)) [single-plane in+resid, payload out]
    k_mgemm<64, 64, 2, 3, 1, true, false, true><<<gM, 256, 0, stream>>>(
        bufB, wfh + 40960, wfl + 40960, nullptr, dinv, bufA);
    // agg3: a3 = agg(p3)                     [two-plane out: near-output precision]
    k_agg<64, false, 2><<<gA, 256, 0, stream>>>((const u16*)bufA, dinv, row_ptr, row_end, csr, nullptr, (u16*)bufB);
    // fused G5+fc6: z3 = relu(a3@W5+b5); out = relu(z3 + z3@W6^T)  [fp32 out]
    k_mfused<64, 128, 128, 2, false, false, false, true, false, true, 0><<<gM, 256, 0, stream>>>(
        (const u16*)bufB, wfh + 45056, wfl + 45056, wfh + 53248, wfl + 53248,
        g5b, nullptr, out);
}

// Round 9
// 444.155 us; speedup vs baseline: 1.1447x; 1.0072x over previous
//
#include <hip/hip_runtime.h>
#include <cstdint>
#include <cstddef>

#define NN 100000
#define NE 1600000
#define NBB 391      // dst buckets of 256 nodes: ceil(100000/256)
#define BSTRIDE 5120 // staging/csr slots per bucket; E[cnt]=4092, sd=64 -> 16-sigma margin

typedef short short8 __attribute__((ext_vector_type(8)));
typedef float floatx4 __attribute__((ext_vector_type(4)));
typedef float floatx2 __attribute__((ext_vector_type(2)));
typedef uint32_t u32x4 __attribute__((ext_vector_type(4)));
typedef unsigned short u16;
typedef uint32_t u32;

// ---------------- bf16 helpers (hardware cvt_pk, RNE — bit-identical to soft RNE)
__device__ __forceinline__ u32 cvtpk_bf16(float a, float b) {
    // D.lo16 = bf16(a), D.hi16 = bf16(b)
    u32 r;
    asm("v_cvt_pk_bf16_f32 %0, %1, %2" : "=v"(r) : "v"(a), "v"(b));
    return r;
}

__device__ __forceinline__ u16 f2bf(float f) {  // RNE via hw cvt
    return (u16)(cvtpk_bf16(f, 0.f) & 0xFFFFu);
}

__device__ __forceinline__ float bf2f(u16 h) {
    union { uint32_t u; float f; } x;
    x.u = ((uint32_t)h) << 16;
    return x.f;
}

__device__ __forceinline__ void split_bf16(float f, short& hi, short& lo) {
    u32 h = cvtpk_bf16(f, 0.f) & 0xFFFFu;
    union { uint32_t u; float f; } hf;
    hf.u = h << 16;
    float r = f - hf.f;
    hi = (short)h;
    lo = (short)(cvtpk_bf16(r, 0.f) & 0xFFFFu);
}

// packed-pair split: hi word of (a0,a1) and lo word of (a0,a1), 6 VALU total
__device__ __forceinline__ void split_pair(float a0, float a1, u32& wh, u32& wl) {
    wh = cvtpk_bf16(a0, a1);
    union { uint32_t u; float f; } h0, h1;
    h0.u = wh << 16;
    h1.u = wh & 0xFFFF0000u;
    wl = cvtpk_bf16(a0 - h0.f, a1 - h1.f);
}

// accumulate a packed pair of bf16 channels into a float2 (v_pk_add_f32)
__device__ __forceinline__ void acc2v(uint32_t u, floatx2& a) {
    union { uint32_t u; float f; } lo, hi;
    lo.u = u << 16;
    hi.u = u & 0xFFFF0000u;
    a += (floatx2){lo.f, hi.f};
}

// ---------------- weight fragment prep (runs inside k_bscatterF blocks 0-8) ---
struct WDesc {
    const float* W;
    short* fh;
    short* fl;
    int din, dout, transb, base, total;  // base/total in short8 groups
};
struct WPrepArgs { WDesc d[6]; };

__device__ __forceinline__ void wprep_work(const WPrepArgs& args, int tid) {
#pragma unroll
    for (int i = 0; i < 6; i++) {
        const WDesc& D = args.d[i];
        if (tid >= D.base && tid < D.base + D.total) {
            int local = tid - D.base;
            int lane = local & 63;
            int rest = local >> 6;
            int kst = D.din >> 5;
            int ks = rest % kst;
            int ntile = rest / kst;
            int n = ntile * 16 + (lane & 15);
            int k0 = ks * 32 + (lane >> 4) * 8;
#pragma unroll
            for (int j = 0; j < 8; j++) {
                int k = k0 + j;
                float v = D.transb ? D.W[(size_t)n * D.din + k]
                                   : D.W[(size_t)k * D.dout + n];
                short h, l;
                split_bf16(v, h, l);
                D.fh[(size_t)local * 8 + j] = h;
                D.fl[(size_t)local * 8 + j] = l;
            }
        }
    }
}

// ---------------- graph preprocessing ----------------------------------------
// scatter edges into fixed-stride bucket staging; blocks 0-8 also run wprep
struct ScatArgs {
    const int* src;
    const int* dst;
    int* gcur;        // pre-zeroed via hipMemsetAsync
    int2* staging;
    WPrepArgs wp;
};

static __global__ __launch_bounds__(1024) void k_bscatterF(ScatArgs a) {
    __shared__ int h[NBB + 1];
    __shared__ int base[NBB + 1];
    int t = threadIdx.x;
    int wtid = blockIdx.x * 1024 + t;
    if (wtid < 8704) wprep_work(a.wp, wtid);
    for (int i = t; i < NBB; i += 1024) h[i] = 0;
    __syncthreads();
    int e0 = blockIdx.x * 4096;
    int b[4], l[4], sv[4], dv[4];
#pragma unroll
    for (int j = 0; j < 4; j++) {
        int e = e0 + j * 1024 + t;
        b[j] = -1;
        if (e < NE) {
            sv[j] = a.src[e];
            dv[j] = a.dst[e];
            b[j] = dv[j] >> 8;
            l[j] = atomicAdd(&h[b[j]], 1);
        }
    }
    __syncthreads();
    for (int i = t; i < NBB; i += 1024)
        if (h[i]) base[i] = atomicAdd(&a.gcur[i], h[i]);
    __syncthreads();
#pragma unroll
    for (int j = 0; j < 4; j++)
        if (b[j] >= 0)
            a.staging[(size_t)b[j] * BSTRIDE + base[b[j]] + l[j]] = make_int2(sv[j], dv[j]);
}

// per-bucket: degree count + scan + dinv + row_ptr/row_end + CSR fill (merged).
// Second staging pass hits L1/L2 (32KB/bucket resident after the count pass).
static __global__ __launch_bounds__(1024) void k_bprep(const int2* __restrict__ staging,
                                                       const int* __restrict__ gcur,
                                                       float* __restrict__ dinv,
                                                       int* __restrict__ row_ptr,
                                                       int* __restrict__ row_end,
                                                       int* __restrict__ csr_src) {
    __shared__ int cnt[256];
    __shared__ int sc[256];
    __shared__ int lrp[256];
    int b = blockIdx.x;
    int t = threadIdx.x;
    if (t < 256) cnt[t] = 0;
    __syncthreads();
    const int n = gcur[b];
    const int base = b * BSTRIDE;
    for (int i = base + t; i < base + n; i += 1024)
        atomicAdd(&cnt[staging[i].y & 255], 1);
    __syncthreads();
    int myc = (t < 256) ? cnt[t] : 0;
    if (t < 256) sc[t] = myc;
    __syncthreads();
    for (int off = 1; off < 256; off <<= 1) {
        int x = 0;
        if (t < 256 && t >= off) x = sc[t - off];
        __syncthreads();
        if (t < 256) sc[t] += x;
        __syncthreads();
    }
    if (t < 256) {
        int st = base + sc[t] - myc;  // absolute fixed-stride CSR start
        lrp[t] = st;
        cnt[t] = 0;                   // reset ranks for fill pass
        int node = (b << 8) + t;
        if (node < NN) {
            dinv[node] = rsqrtf((float)(myc + 1));  // +1 self loop
            row_ptr[node] = st;
            row_end[node] = st + myc;
        }
    }
    __syncthreads();
    for (int i = base + t; i < base + n; i += 1024) {
        int2 ed = staging[i];
        int loc = ed.y & 255;
        int r = atomicAdd(&cnt[loc], 1);
        csr_src[lrp[loc] + r] = ed.x;
    }
}

// ---------------- MFMA GEMM: LDS-free, B in registers ------------------------
// AMODE: 1 = fp32 input, on-the-fly hw cvt_pk RNE (2 MFMAs/K-step)
//        2 = two-plane split input (3 MFMAs, lossless to 2^-16)
//        3 = single-plane bf16 input (2 MFMAs) — interior activations
// OMODE: 0 = fp32 out, 1 = hi plane only (payload/single), 2 = hi+lo planes
template <int DIN, int DOUT, int MT, int AMODE, int OMODE, bool RESID, bool BIAS, bool SCALE>
__global__ __launch_bounds__(256, 3) void k_mgemm(const void* __restrict__ Av,
                                                  const short* __restrict__ fh,
                                                  const short* __restrict__ fl,
                                                  const float* __restrict__ bias,
                                                  const float* __restrict__ dinv,
                                                  void* __restrict__ C) {
    static_assert(!RESID || DIN == DOUT, "residual needs square");
    constexpr int KST = DIN / 32;
    constexpr int NTW = DOUT / 64;
    const int t = threadIdx.x;
    const int wave = t >> 6;
    const int lane = t & 63;
    const int r16 = lane & 15;
    const int kq = lane >> 4;

    const float* Af = (const float*)Av;
    const u16*   Ah = (const u16*)Av;
    const u16*   Al = Ah + (size_t)NN * DIN;

    short8 bh[NTW][KST], bl[NTW][KST];
#pragma unroll
    for (int nt = 0; nt < NTW; nt++) {
        int ntile = wave * NTW + nt;
#pragma unroll
        for (int ks = 0; ks < KST; ks++) {
            size_t o = ((size_t)(ntile * KST + ks) * 64 + lane) * 8;
            bh[nt][ks] = *(const short8*)(fh + o);
            bl[nt][ks] = *(const short8*)(fl + o);
        }
    }

    const int m0b = blockIdx.x * (MT * 16);
#pragma unroll
    for (int mt = 0; mt < MT; mt++) {
        const int m0 = m0b + mt * 16;
        if (m0 >= NN) break;
        const int ra = min(m0 + r16, NN - 1);  // clamp; stores guarded

        floatx4 acc[NTW];
#pragma unroll
        for (int nt = 0; nt < NTW; nt++) acc[nt] = (floatx4){0.f, 0.f, 0.f, 0.f};

        if constexpr (AMODE == 1) {
            const float* Ap = Af + (size_t)ra * DIN + kq * 8;
#pragma unroll
            for (int ks = 0; ks < KST; ks++) {
                float4 f0 = *(const float4*)(Ap + ks * 32);
                float4 f1 = *(const float4*)(Ap + ks * 32 + 4);
                u32x4 w;
                w[0] = cvtpk_bf16(f0.x, f0.y);
                w[1] = cvtpk_bf16(f0.z, f0.w);
                w[2] = cvtpk_bf16(f1.x, f1.y);
                w[3] = cvtpk_bf16(f1.z, f1.w);
                short8 ah = *(const short8*)&w;
#pragma unroll
                for (int nt = 0; nt < NTW; nt++) {
                    acc[nt] = __builtin_amdgcn_mfma_f32_16x16x32_bf16(ah, bh[nt][ks], acc[nt], 0, 0, 0);
                    acc[nt] = __builtin_amdgcn_mfma_f32_16x16x32_bf16(ah, bl[nt][ks], acc[nt], 0, 0, 0);
                }
            }
        } else if constexpr (AMODE == 3) {
            const u16* Aph = Ah + (size_t)ra * DIN + kq * 8;
#pragma unroll
            for (int ks = 0; ks < KST; ks++) {
                short8 ah = *(const short8*)(Aph + ks * 32);
#pragma unroll
                for (int nt = 0; nt < NTW; nt++) {
                    acc[nt] = __builtin_amdgcn_mfma_f32_16x16x32_bf16(ah, bh[nt][ks], acc[nt], 0, 0, 0);
                    acc[nt] = __builtin_amdgcn_mfma_f32_16x16x32_bf16(ah, bl[nt][ks], acc[nt], 0, 0, 0);
                }
            }
        } else {
            const u16* Aph = Ah + (size_t)ra * DIN + kq * 8;
            const u16* Apl = Al + (size_t)ra * DIN + kq * 8;
#pragma unroll
            for (int ks = 0; ks < KST; ks++) {
                short8 ah = *(const short8*)(Aph + ks * 32);
                short8 al = *(const short8*)(Apl + ks * 32);
#pragma unroll
                for (int nt = 0; nt < NTW; nt++) {
                    acc[nt] = __builtin_amdgcn_mfma_f32_16x16x32_bf16(ah, bh[nt][ks], acc[nt], 0, 0, 0);
                    acc[nt] = __builtin_amdgcn_mfma_f32_16x16x32_bf16(ah, bl[nt][ks], acc[nt], 0, 0, 0);
                    acc[nt] = __builtin_amdgcn_mfma_f32_16x16x32_bf16(al, bh[nt][ks], acc[nt], 0, 0, 0);
                }
            }
        }

        // C/D layout: row = kq*4 + r, col = r16 (verified)
#pragma unroll
        for (int nt = 0; nt < NTW; nt++) {
            int col = (wave * NTW + nt) * 16 + r16;
#pragma unroll
            for (int r = 0; r < 4; r++) {
                int row = m0 + kq * 4 + r;
                if (row < NN) {
                    float v = acc[nt][r];
                    if constexpr (RESID) {
                        size_t ri = (size_t)row * DIN + col;
                        if constexpr (AMODE == 3)
                            v = fmaxf(v + bf2f(Ah[ri]), 0.f);
                        else
                            v = fmaxf(v + bf2f(Ah[ri]) + bf2f(Al[ri]), 0.f);
                    }
                    if constexpr (BIAS) v = fmaxf(v + bias[col], 0.f);
                    if constexpr (SCALE) v *= dinv[row];
                    size_t oi = (size_t)row * DOUT + col;
                    if constexpr (OMODE == 0) {
                        ((float*)C)[oi] = v;
                    } else if constexpr (OMODE == 1) {
                        ((u16*)C)[oi] = f2bf(v);
                    } else {
                        short h, l;
                        split_bf16(v, h, l);
                        ((u16*)C)[oi] = (u16)h;
                        ((u16*)C)[(size_t)NN * DOUT + oi] = (u16)l;
                    }
                }
            }
        }
    }
}

// ---------------- fused GEMM pair: C = ep2( ep1(A@W1') @ W2' ) ---------------
// A1S: stage-1 A is single-plane bf16 (2 MFMAs); MIDS: LDS mid single-plane.
template <int DIN, int DMID, int DOUT, int MT, bool A1S, bool MIDS, bool RESID1,
          bool BIAS1, bool SCALE2, bool RESID2, int OMODE2>
__global__ __launch_bounds__(256, 3) void k_mfused(const u16* __restrict__ Ahp,
                                                   const short* __restrict__ f1h,
                                                   const short* __restrict__ f1l,
                                                   const short* __restrict__ f2h,
                                                   const short* __restrict__ f2l,
                                                   const float* __restrict__ bias1,
                                                   const float* __restrict__ dinv,
                                                   void* __restrict__ C) {
    static_assert(!RESID1 || DIN == DMID, "resid1 needs square stage1");
    static_assert(!RESID2 || DMID == DOUT, "resid2 needs square stage2");
    constexpr int KST1 = DIN / 32;
    constexpr int NTW1 = DMID / 64;
    constexpr int KST2 = DMID / 32;
    constexpr int NTW2 = DOUT / 64;
    constexpr int LDW = DMID + 8;  // u16 stride: 16B-aligned rows, 4-bank skew
    __shared__ u16 ldsh[16][LDW];
    __shared__ u16 ldsl[MIDS ? 1 : 16][LDW];

    const u16* Alp = Ahp + (size_t)NN * DIN;

    const int t = threadIdx.x;
    const int wave = t >> 6;
    const int lane = t & 63;
    const int r16 = lane & 15;
    const int kq = lane >> 4;

    short8 b1h[NTW1][KST1], b1l[NTW1][KST1];
#pragma unroll
    for (int nt = 0; nt < NTW1; nt++) {
        int ntile = wave * NTW1 + nt;
#pragma unroll
        for (int ks = 0; ks < KST1; ks++) {
            size_t o = ((size_t)(ntile * KST1 + ks) * 64 + lane) * 8;
            b1h[nt][ks] = *(const short8*)(f1h + o);
            b1l[nt][ks] = *(const short8*)(f1l + o);
        }
    }
    short8 b2h[NTW2][KST2], b2l[NTW2][KST2];
#pragma unroll
    for (int nt = 0; nt < NTW2; nt++) {
        int ntile = wave * NTW2 + nt;
#pragma unroll
        for (int ks = 0; ks < KST2; ks++) {
            size_t o = ((size_t)(ntile * KST2 + ks) * 64 + lane) * 8;
            b2h[nt][ks] = *(const short8*)(f2h + o);
            b2l[nt][ks] = *(const short8*)(f2l + o);
        }
    }

    const int m0b = blockIdx.x * (MT * 16);
#pragma unroll 1
    for (int mt = 0; mt < MT; mt++) {
        const int m0 = m0b + mt * 16;
        if (m0 >= NN) break;
        const int ra = min(m0 + r16, NN - 1);

        // ---- stage 1: acc1 = A @ W1' ----
        floatx4 acc1[NTW1];
#pragma unroll
        for (int nt = 0; nt < NTW1; nt++) acc1[nt] = (floatx4){0.f, 0.f, 0.f, 0.f};
        {
            const u16* Aph = Ahp + (size_t)ra * DIN + kq * 8;
            const u16* Apl = Alp + (size_t)ra * DIN + kq * 8;
#pragma unroll
            for (int ks = 0; ks < KST1; ks++) {
                short8 ah = *(const short8*)(Aph + ks * 32);
#pragma unroll
                for (int nt = 0; nt < NTW1; nt++) {
                    acc1[nt] = __builtin_amdgcn_mfma_f32_16x16x32_bf16(ah, b1h[nt][ks], acc1[nt], 0, 0, 0);
                    acc1[nt] = __builtin_amdgcn_mfma_f32_16x16x32_bf16(ah, b1l[nt][ks], acc1[nt], 0, 0, 0);
                }
                if constexpr (!A1S) {
                    short8 al = *(const short8*)(Apl + ks * 32);
#pragma unroll
                    for (int nt = 0; nt < NTW1; nt++)
                        acc1[nt] = __builtin_amdgcn_mfma_f32_16x16x32_bf16(al, b1h[nt][ks], acc1[nt], 0, 0, 0);
                }
            }
        }
        // ---- epilogue 1 -> LDS ----
#pragma unroll
        for (int nt = 0; nt < NTW1; nt++) {
            int col = (wave * NTW1 + nt) * 16 + r16;
#pragma unroll
            for (int r = 0; r < 4; r++) {
                int row = m0 + kq * 4 + r;
                float v = acc1[nt][r];
                if constexpr (RESID1) {
                    if (row < NN) {
                        size_t ri = (size_t)row * DIN + col;
                        if constexpr (A1S)
                            v = fmaxf(v + bf2f(Ahp[ri]), 0.f);
                        else
                            v = fmaxf(v + bf2f(Ahp[ri]) + bf2f(Alp[ri]), 0.f);
                    }
                }
                if constexpr (BIAS1) v = fmaxf(v + bias1[col], 0.f);
                if constexpr (MIDS) {
                    ldsh[kq * 4 + r][col] = f2bf(v);
                } else {
                    short h, l;
                    split_bf16(v, h, l);
                    ldsh[kq * 4 + r][col] = (u16)h;
                    ldsl[kq * 4 + r][col] = (u16)l;
                }
            }
        }
        __syncthreads();

        // ---- stage 2: acc2 = mid @ W2' (A-frags from LDS) ----
        floatx4 acc2[NTW2];
#pragma unroll
        for (int nt = 0; nt < NTW2; nt++) acc2[nt] = (floatx4){0.f, 0.f, 0.f, 0.f};
#pragma unroll
        for (int ks = 0; ks < KST2; ks++) {
            short8 ah = *(const short8*)&ldsh[r16][ks * 32 + kq * 8];
#pragma unroll
            for (int nt = 0; nt < NTW2; nt++) {
                acc2[nt] = __builtin_amdgcn_mfma_f32_16x16x32_bf16(ah, b2h[nt][ks], acc2[nt], 0, 0, 0);
                acc2[nt] = __builtin_amdgcn_mfma_f32_16x16x32_bf16(ah, b2l[nt][ks], acc2[nt], 0, 0, 0);
            }
            if constexpr (!MIDS) {
                short8 al = *(const short8*)&ldsl[r16][ks * 32 + kq * 8];
#pragma unroll
                for (int nt = 0; nt < NTW2; nt++)
                    acc2[nt] = __builtin_amdgcn_mfma_f32_16x16x32_bf16(al, b2h[nt][ks], acc2[nt], 0, 0, 0);
            }
        }

        // ---- epilogue 2 -> C ----
#pragma unroll
        for (int nt = 0; nt < NTW2; nt++) {
            int col = (wave * NTW2 + nt) * 16 + r16;
#pragma unroll
            for (int r = 0; r < 4; r++) {
                int row = m0 + kq * 4 + r;
                if (row < NN) {
                    float v = acc2[nt][r];
                    if constexpr (RESID2) {
                        if constexpr (MIDS)
                            v = fmaxf(v + bf2f(ldsh[kq * 4 + r][col]), 0.f);
                        else
                            v = fmaxf(v + bf2f(ldsh[kq * 4 + r][col]) + bf2f(ldsl[kq * 4 + r][col]), 0.f);
                    }
                    if constexpr (SCALE2) v *= dinv[row];
                    size_t oi = (size_t)row * DOUT + col;
                    if constexpr (OMODE2 == 0) {
                        ((float*)C)[oi] = v;
                    } else if constexpr (OMODE2 == 1) {
                        ((u16*)C)[oi] = f2bf(v);
                    } else {
                        short h, l;
                        split_bf16(v, h, l);
                        ((u16*)C)[oi] = (u16)h;
                        ((u16*)C)[(size_t)NN * DOUT + oi] = (u16)l;
                    }
                }
            }
        }
        __syncthreads();  // protect LDS before next mt overwrites
    }
}

// ---------------- GCN aggregation: bf16 gather payload, fp32 accumulate -------
// packed v_pk_add_f32 accumulate; OPL=1: single-plane out, OPL=2: hi+lo planes.
template <int D, bool BIAS_RELU, int OPL>
__global__ __launch_bounds__(256) void k_agg(const u16* __restrict__ hs,
                                             const float* __restrict__ dinv,
                                             const int* __restrict__ row_ptr,
                                             const int* __restrict__ row_end,
                                             const int* __restrict__ csr_src,
                                             const float* __restrict__ bias,
                                             u16* __restrict__ outh) {
    u16* outl = outh + (size_t)NN * D;
    int node = blockIdx.x * 4 + (threadIdx.x >> 6);
    int lane = threadIdx.x & 63;
    if (node >= NN) return;

    if constexpr (D == 128) {
        const int off = lane * 2;
        floatx2 a = (floatx2){0.f, 0.f};
        {
            uint32_t u = ((const uint32_t*)(hs + (size_t)node * D))[lane];
            acc2v(u, a);
        }
        int e = row_ptr[node];
        const int end = row_end[node];
        for (; e + 16 <= end; e += 16) {
            int s[16];
#pragma unroll
            for (int i = 0; i < 16; i++) s[i] = csr_src[e + i];
            uint32_t v[16];
#pragma unroll
            for (int i = 0; i < 16; i++) v[i] = ((const uint32_t*)(hs + (size_t)s[i] * D))[lane];
#pragma unroll
            for (int i = 0; i < 16; i++) acc2v(v[i], a);
        }
        for (; e + 8 <= end; e += 8) {
            int s[8];
#pragma unroll
            for (int i = 0; i < 8; i++) s[i] = csr_src[e + i];
            uint32_t v[8];
#pragma unroll
            for (int i = 0; i < 8; i++) v[i] = ((const uint32_t*)(hs + (size_t)s[i] * D))[lane];
#pragma unroll
            for (int i = 0; i < 8; i++) acc2v(v[i], a);
        }
        for (; e + 4 <= end; e += 4) {
            int s[4];
#pragma unroll
            for (int i = 0; i < 4; i++) s[i] = csr_src[e + i];
            uint32_t v[4];
#pragma unroll
            for (int i = 0; i < 4; i++) v[i] = ((const uint32_t*)(hs + (size_t)s[i] * D))[lane];
#pragma unroll
            for (int i = 0; i < 4; i++) acc2v(v[i], a);
        }
        for (; e < end; e++) {
            int s = csr_src[e];
            uint32_t u = ((const uint32_t*)(hs + (size_t)s * D))[lane];
            acc2v(u, a);
        }
        const float di = dinv[node];
        float a0 = a[0] * di, a1 = a[1] * di;
        if constexpr (BIAS_RELU) {
            a0 = fmaxf(a0 + bias[off], 0.f);
            a1 = fmaxf(a1 + bias[off + 1], 0.f);
        }
        if constexpr (OPL == 1) {
            *(u32*)(outh + (size_t)node * D + off) = cvtpk_bf16(a0, a1);
        } else {
            u32 wh, wl;
            split_pair(a0, a1, wh, wl);
            *(u32*)(outh + (size_t)node * D + off) = wh;
            *(u32*)(outl + (size_t)node * D + off) = wl;
        }
    } else {
        // D == 64: halves handle alternating edges; lane owns ch {2*l32, 2*l32+1}
        const int half = lane >> 5;
        const int l32 = lane & 31;
        floatx2 a = (floatx2){0.f, 0.f};
        if (half == 0) {
            uint32_t u = ((const uint32_t*)(hs + (size_t)node * D))[l32];
            acc2v(u, a);
        }
        int e = row_ptr[node];
        const int end = row_end[node];
        for (; e + 16 <= end; e += 16) {
            int s[8];
#pragma unroll
            for (int i = 0; i < 8; i++) s[i] = csr_src[e + half + 2 * i];
            uint32_t v[8];
#pragma unroll
            for (int i = 0; i < 8; i++) v[i] = ((const uint32_t*)(hs + (size_t)s[i] * D))[l32];
#pragma unroll
            for (int i = 0; i < 8; i++) acc2v(v[i], a);
        }
        for (; e + 8 <= end; e += 8) {
            int s[4];
#pragma unroll
            for (int i = 0; i < 4; i++) s[i] = csr_src[e + half + 2 * i];
            uint32_t v[4];
#pragma unroll
            for (int i = 0; i < 4; i++) v[i] = ((const uint32_t*)(hs + (size_t)s[i] * D))[l32];
#pragma unroll
            for (int i = 0; i < 4; i++) acc2v(v[i], a);
        }
        for (; e + 2 <= end; e += 2) {
            int s = csr_src[e + half];
            uint32_t u = ((const uint32_t*)(hs + (size_t)s * D))[l32];
            acc2v(u, a);
        }
        if (e < end && half == 0) {
            int s = csr_src[e];
            uint32_t u = ((const uint32_t*)(hs + (size_t)s * D))[l32];
            acc2v(u, a);
        }
        float a0 = a[0], a1 = a[1];
        a0 += __shfl_xor(a0, 32, 64);
        a1 += __shfl_xor(a1, 32, 64);
        if (half == 0) {
            const int off = l32 * 2;
            const float di = dinv[node];
            a0 *= di;
            a1 *= di;
            if constexpr (BIAS_RELU) {
                a0 = fmaxf(a0 + bias[off], 0.f);
                a1 = fmaxf(a1 + bias[off + 1], 0.f);
            }
            if constexpr (OPL == 1) {
                *(u32*)(outh + (size_t)node * D + off) = cvtpk_bf16(a0, a1);
            } else {
                u32 wh, wl;
                split_pair(a0, a1, wh, wl);
                *(u32*)(outh + (size_t)node * D + off) = wh;
                *(u32*)(outl + (size_t)node * D + off) = wl;
            }
        }
    }
}

// ---------------- launch ----------------

extern "C" void kernel_launch(void* const* d_in, const int* in_sizes, int n_in,
                              void* d_out, int out_size, void* d_ws, size_t ws_size,
                              hipStream_t stream) {
    const float* x   = (const float*)d_in[0];
    const int*   ei  = (const int*)d_in[1];
    const float* g1w = (const float*)d_in[2];
    const float* g1b = (const float*)d_in[3];
    const float* f2w = (const float*)d_in[4];
    const float* g3w = (const float*)d_in[5];
    const float* g3b = (const float*)d_in[6];
    const float* f4w = (const float*)d_in[7];
    const float* g5w = (const float*)d_in[8];
    const float* g5b = (const float*)d_in[9];
    const float* f6w = (const float*)d_in[10];
    float* out = (float*)d_out;

    const int* src = ei;       // edge_index[0]
    const int* dst = ei + NE;  // edge_index[1]

    char* p = (char*)d_ws;
    auto alloc = [&](size_t bytes) -> void* {
        void* r = (void*)p;
        p += (bytes + 255) & ~(size_t)255;
        return r;
    };
    float* dinv    = (float*)alloc(NN * 4);
    int*   row_ptr = (int*)alloc(NN * 4);
    int*   row_end = (int*)alloc(NN * 4);
    int*   gcur    = (int*)alloc((NBB + 1) * 4);
    int*   csr     = (int*)alloc((size_t)NBB * BSTRIDE * 4);  // fixed-stride CSR (8 MB)
    short* wfh     = (short*)alloc(69632 * 2);
    short* wfl     = (short*)alloc(69632 * 2);
    // bufA/bufB: 4B/elem budget = room for hi+lo u16 planes at D=128
    char* bufA = (char*)alloc((size_t)NN * 128 * 4);
    char* bufB = (char*)alloc((size_t)NN * 128 * 4);
    // fixed-stride edge staging (391*5120*8B = 16.0 MB) aliases bufB: fully
    // consumed by k_bprep before agg1 writes bufB (stream-ordered).
    int2* staging  = (int2*)bufB;

    const int gE4 = (NE + 4095) / 4096;      // 391
    const int gA  = NN / 4;                  // 25000
    const int gM  = (NN + 31) / 32;          // 3125 (MT=2: 32 rows/block, exact)

    // zero bucket counters (graph-capture-safe async memset)
    hipMemsetAsync(gcur, 0, (NBB + 1) * 4, stream);

    // scatter + weight prep (merged; blocks 0-8 also run wprep)
    {
        ScatArgs sa;
        sa.src = src;
        sa.dst = dst;
        sa.gcur = gcur;
        sa.staging = staging;
        int  eoff[6] = {0, 16384, 32768, 40960, 45056, 53248};
        int  base[6] = {0, 2048, 4096, 5120, 5632, 6656};
        int  tot[6]  = {2048, 2048, 1024, 512, 1024, 2048};
        const float* Ws[6] = {g1w, f2w, g3w, f4w, g5w, f6w};
        int din[6]  = {128, 128, 128, 64, 64, 128};
        int dout[6] = {128, 128, 64, 64, 128, 128};
        int trb[6]  = {0, 1, 0, 1, 0, 1};
        for (int i = 0; i < 6; i++) {
            sa.wp.d[i] = WDesc{Ws[i], wfh + eoff[i], wfl + eoff[i],
                               din[i], dout[i], trb[i], base[i], tot[i]};
        }
        k_bscatterF<<<gE4, 1024, 0, stream>>>(sa);
    }

    // per-bucket count + scan + dinv + CSR fill (merged)
    k_bprep<<<NBB, 1024, 0, stream>>>(staging, gcur, dinv, row_ptr, row_end, csr);

    // G1: h1 = bf16(dinv * (x@W1))           [fp32 in via hw cvt_pk, payload out]
    k_mgemm<128, 128, 2, 1, 1, false, false, true><<<gM, 256, 0, stream>>>(
        x, wfh + 0, wfl + 0, nullptr, dinv, bufA);
    // agg1: z1 = relu(dinv*agg(h1)+b1)       [single-plane out]
    k_agg<128, true, 1><<<gA, 256, 0, stream>>>((const u16*)bufA, dinv, row_ptr, row_end, csr, g1b, (u16*)bufB);
    // fused fc2+G3: z1' = relu(z1 + z1@W2^T); h2 = bf16(dinv*(z1'@W3))
    k_mfused<128, 128, 64, 2, true, true, true, false, true, false, 1><<<gM, 256, 0, stream>>>(
        (const u16*)bufB, wfh + 16384, wfl + 16384, wfh + 32768, wfl + 32768,
        nullptr, dinv, bufA);
    // agg2: z2 = relu(dinv*agg(h2)+b3)       [single-plane out]
    k_agg<64, true, 1><<<gA, 256, 0, stream>>>((const u16*)bufA, dinv, row_ptr, row_end, csr, g3b, (u16*)bufB);
    // fc4: p3 = bf16(dinv * relu(z2 + z2@W4^T)) [single-plane in+resid, payload out]
    k_mgemm<64, 64, 2, 3, 1, true, false, true><<<gM, 256, 0, stream>>>(
        bufB, wfh + 40960, wfl + 40960, nullptr, dinv, bufA);
    // agg3: a3 = agg(p3)                     [two-plane out: near-output precision]
    k_agg<64, false, 2><<<gA, 256, 0, stream>>>((const u16*)bufA, dinv, row_ptr, row_end, csr, nullptr, (u16*)bufB);
    // fused G5+fc6: z3 = relu(a3@W5+b5); out = relu(z3 + z3@W6^T)  [fp32 out]
    k_mfused<64, 128, 128, 2, false, false, false, true, false, true, 0><<<gM, 256, 0, stream>>>(
        (const u16*)bufB, wfh + 45056, wfl + 45056, wfh + 53248, wfl + 53248,
        g5b, nullptr, out);
}

// Round 10
// 437.573 us; speedup vs baseline: 1.1619x; 1.0150x over previous
//
#include <hip/hip_runtime.h>
#include <cstdint>
#include <cstddef>

#define NN 100000
#define NE 1600000
#define NBB 391      // dst buckets of 256 nodes: ceil(100000/256)
#define BSTRIDE 5120 // staging/csr slots per bucket; E[cnt]=4092, sd=64 -> 16-sigma margin

typedef short short8 __attribute__((ext_vector_type(8)));
typedef float floatx4 __attribute__((ext_vector_type(4)));
typedef float floatx2 __attribute__((ext_vector_type(2)));
typedef uint32_t u32x4 __attribute__((ext_vector_type(4)));
typedef unsigned short u16;
typedef uint32_t u32;

// ---------------- bf16 helpers (hardware cvt_pk, RNE — bit-identical to soft RNE)
__device__ __forceinline__ u32 cvtpk_bf16(float a, float b) {
    // D.lo16 = bf16(a), D.hi16 = bf16(b)
    u32 r;
    asm("v_cvt_pk_bf16_f32 %0, %1, %2" : "=v"(r) : "v"(a), "v"(b));
    return r;
}

__device__ __forceinline__ u16 f2bf(float f) {  // RNE via hw cvt
    return (u16)(cvtpk_bf16(f, 0.f) & 0xFFFFu);
}

__device__ __forceinline__ float bf2f(u16 h) {
    union { uint32_t u; float f; } x;
    x.u = ((uint32_t)h) << 16;
    return x.f;
}

__device__ __forceinline__ void split_bf16(float f, short& hi, short& lo) {
    u32 h = cvtpk_bf16(f, 0.f) & 0xFFFFu;
    union { uint32_t u; float f; } hf;
    hf.u = h << 16;
    float r = f - hf.f;
    hi = (short)h;
    lo = (short)(cvtpk_bf16(r, 0.f) & 0xFFFFu);
}

// packed-pair split: hi word of (a0,a1) and lo word of (a0,a1)
__device__ __forceinline__ void split_pair(float a0, float a1, u32& wh, u32& wl) {
    wh = cvtpk_bf16(a0, a1);
    union { uint32_t u; float f; } h0, h1;
    h0.u = wh << 16;
    h1.u = wh & 0xFFFF0000u;
    wl = cvtpk_bf16(a0 - h0.f, a1 - h1.f);
}

// accumulate a packed pair of bf16 channels into a float2 (v_pk_add_f32)
__device__ __forceinline__ void acc2v(uint32_t u, floatx2& a) {
    union { uint32_t u; float f; } lo, hi;
    lo.u = u << 16;
    hi.u = u & 0xFFFF0000u;
    a += (floatx2){lo.f, hi.f};
}

// ---------------- weight fragment prep (runs inside k_bscatterF blocks 0-8) ---
struct WDesc {
    const float* W;
    short* fh;
    short* fl;
    int din, dout, transb, base, total;  // base/total in short8 groups
};
struct WPrepArgs { WDesc d[6]; };

__device__ __forceinline__ void wprep_work(const WPrepArgs& args, int tid) {
#pragma unroll
    for (int i = 0; i < 6; i++) {
        const WDesc& D = args.d[i];
        if (tid >= D.base && tid < D.base + D.total) {
            int local = tid - D.base;
            int lane = local & 63;
            int rest = local >> 6;
            int kst = D.din >> 5;
            int ks = rest % kst;
            int ntile = rest / kst;
            int n = ntile * 16 + (lane & 15);
            int k0 = ks * 32 + (lane >> 4) * 8;
#pragma unroll
            for (int j = 0; j < 8; j++) {
                int k = k0 + j;
                float v = D.transb ? D.W[(size_t)n * D.din + k]
                                   : D.W[(size_t)k * D.dout + n];
                short h, l;
                split_bf16(v, h, l);
                D.fh[(size_t)local * 8 + j] = h;
                D.fl[(size_t)local * 8 + j] = l;
            }
        }
    }
}

// ---------------- graph preprocessing ----------------------------------------
// scatter edges into fixed-stride bucket staging; blocks 0-8 also run wprep
struct ScatArgs {
    const int* src;
    const int* dst;
    int* gcur;        // pre-zeroed via hipMemsetAsync
    int2* staging;
    WPrepArgs wp;
};

static __global__ __launch_bounds__(1024) void k_bscatterF(ScatArgs a) {
    __shared__ int h[NBB + 1];
    __shared__ int base[NBB + 1];
    int t = threadIdx.x;
    int wtid = blockIdx.x * 1024 + t;
    if (wtid < 8704) wprep_work(a.wp, wtid);
    for (int i = t; i < NBB; i += 1024) h[i] = 0;
    __syncthreads();
    int e0 = blockIdx.x * 4096;
    int b[4], l[4], sv[4], dv[4];
#pragma unroll
    for (int j = 0; j < 4; j++) {
        int e = e0 + j * 1024 + t;
        b[j] = -1;
        if (e < NE) {
            sv[j] = a.src[e];
            dv[j] = a.dst[e];
            b[j] = dv[j] >> 8;
            l[j] = atomicAdd(&h[b[j]], 1);
        }
    }
    __syncthreads();
    for (int i = t; i < NBB; i += 1024)
        if (h[i]) base[i] = atomicAdd(&a.gcur[i], h[i]);
    __syncthreads();
#pragma unroll
    for (int j = 0; j < 4; j++)
        if (b[j] >= 0)
            a.staging[(size_t)b[j] * BSTRIDE + base[b[j]] + l[j]] = make_int2(sv[j], dv[j]);
}

// per-bucket: degree count + scan + dinv + row_ptr/row_end + CSR fill (merged).
static __global__ __launch_bounds__(1024) void k_bprep(const int2* __restrict__ staging,
                                                       const int* __restrict__ gcur,
                                                       float* __restrict__ dinv,
                                                       int* __restrict__ row_ptr,
                                                       int* __restrict__ row_end,
                                                       int* __restrict__ csr_src) {
    __shared__ int cnt[256];
    __shared__ int sc[256];
    __shared__ int lrp[256];
    int b = blockIdx.x;
    int t = threadIdx.x;
    if (t < 256) cnt[t] = 0;
    __syncthreads();
    const int n = gcur[b];
    const int base = b * BSTRIDE;
    for (int i = base + t; i < base + n; i += 1024)
        atomicAdd(&cnt[staging[i].y & 255], 1);
    __syncthreads();
    int myc = (t < 256) ? cnt[t] : 0;
    if (t < 256) sc[t] = myc;
    __syncthreads();
    for (int off = 1; off < 256; off <<= 1) {
        int x = 0;
        if (t < 256 && t >= off) x = sc[t - off];
        __syncthreads();
        if (t < 256) sc[t] += x;
        __syncthreads();
    }
    if (t < 256) {
        int st = base + sc[t] - myc;  // absolute fixed-stride CSR start
        lrp[t] = st;
        cnt[t] = 0;                   // reset ranks for fill pass
        int node = (b << 8) + t;
        if (node < NN) {
            dinv[node] = rsqrtf((float)(myc + 1));  // +1 self loop
            row_ptr[node] = st;
            row_end[node] = st + myc;
        }
    }
    __syncthreads();
    for (int i = base + t; i < base + n; i += 1024) {
        int2 ed = staging[i];
        int loc = ed.y & 255;
        int r = atomicAdd(&cnt[loc], 1);
        csr_src[lrp[loc] + r] = ed.x;
    }
}

// ---------------- MFMA GEMM: LDS-free, B in registers ------------------------
// AMODE: 1 = fp32 input, on-the-fly hw cvt_pk RNE (2 MFMAs/K-step)
//        2 = two-plane split input (3 MFMAs, lossless to 2^-16)
//        3 = single-plane bf16 input (2 MFMAs) — interior activations
// OMODE: 0 = fp32 out, 1 = hi plane only (payload/single), 2 = hi+lo planes
template <int DIN, int DOUT, int MT, int AMODE, int OMODE, bool RESID, bool BIAS, bool SCALE>
__global__ __launch_bounds__(256, 3) void k_mgemm(const void* __restrict__ Av,
                                                  const short* __restrict__ fh,
                                                  const short* __restrict__ fl,
                                                  const float* __restrict__ bias,
                                                  const float* __restrict__ dinv,
                                                  void* __restrict__ C) {
    static_assert(!RESID || DIN == DOUT, "residual needs square");
    constexpr int KST = DIN / 32;
    constexpr int NTW = DOUT / 64;
    const int t = threadIdx.x;
    const int wave = t >> 6;
    const int lane = t & 63;
    const int r16 = lane & 15;
    const int kq = lane >> 4;

    const float* Af = (const float*)Av;
    const u16*   Ah = (const u16*)Av;
    const u16*   Al = Ah + (size_t)NN * DIN;

    short8 bh[NTW][KST], bl[NTW][KST];
#pragma unroll
    for (int nt = 0; nt < NTW; nt++) {
        int ntile = wave * NTW + nt;
#pragma unroll
        for (int ks = 0; ks < KST; ks++) {
            size_t o = ((size_t)(ntile * KST + ks) * 64 + lane) * 8;
            bh[nt][ks] = *(const short8*)(fh + o);
            bl[nt][ks] = *(const short8*)(fl + o);
        }
    }

    const int m0b = blockIdx.x * (MT * 16);
#pragma unroll
    for (int mt = 0; mt < MT; mt++) {
        const int m0 = m0b + mt * 16;
        if (m0 >= NN) break;
        const int ra = min(m0 + r16, NN - 1);  // clamp; stores guarded

        floatx4 acc[NTW];
#pragma unroll
        for (int nt = 0; nt < NTW; nt++) acc[nt] = (floatx4){0.f, 0.f, 0.f, 0.f};

        if constexpr (AMODE == 1) {
            const float* Ap = Af + (size_t)ra * DIN + kq * 8;
#pragma unroll
            for (int ks = 0; ks < KST; ks++) {
                float4 f0 = *(const float4*)(Ap + ks * 32);
                float4 f1 = *(const float4*)(Ap + ks * 32 + 4);
                u32x4 w;
                w[0] = cvtpk_bf16(f0.x, f0.y);
                w[1] = cvtpk_bf16(f0.z, f0.w);
                w[2] = cvtpk_bf16(f1.x, f1.y);
                w[3] = cvtpk_bf16(f1.z, f1.w);
                short8 ah = *(const short8*)&w;
#pragma unroll
                for (int nt = 0; nt < NTW; nt++) {
                    acc[nt] = __builtin_amdgcn_mfma_f32_16x16x32_bf16(ah, bh[nt][ks], acc[nt], 0, 0, 0);
                    acc[nt] = __builtin_amdgcn_mfma_f32_16x16x32_bf16(ah, bl[nt][ks], acc[nt], 0, 0, 0);
                }
            }
        } else if constexpr (AMODE == 3) {
            const u16* Aph = Ah + (size_t)ra * DIN + kq * 8;
#pragma unroll
            for (int ks = 0; ks < KST; ks++) {
                short8 ah = *(const short8*)(Aph + ks * 32);
#pragma unroll
                for (int nt = 0; nt < NTW; nt++) {
                    acc[nt] = __builtin_amdgcn_mfma_f32_16x16x32_bf16(ah, bh[nt][ks], acc[nt], 0, 0, 0);
                    acc[nt] = __builtin_amdgcn_mfma_f32_16x16x32_bf16(ah, bl[nt][ks], acc[nt], 0, 0, 0);
                }
            }
        } else {
            const u16* Aph = Ah + (size_t)ra * DIN + kq * 8;
            const u16* Apl = Al + (size_t)ra * DIN + kq * 8;
#pragma unroll
            for (int ks = 0; ks < KST; ks++) {
                short8 ah = *(const short8*)(Aph + ks * 32);
                short8 al = *(const short8*)(Apl + ks * 32);
#pragma unroll
                for (int nt = 0; nt < NTW; nt++) {
                    acc[nt] = __builtin_amdgcn_mfma_f32_16x16x32_bf16(ah, bh[nt][ks], acc[nt], 0, 0, 0);
                    acc[nt] = __builtin_amdgcn_mfma_f32_16x16x32_bf16(ah, bl[nt][ks], acc[nt], 0, 0, 0);
                    acc[nt] = __builtin_amdgcn_mfma_f32_16x16x32_bf16(al, bh[nt][ks], acc[nt], 0, 0, 0);
                }
            }
        }

        // C/D layout: row = kq*4 + r, col = r16 (verified)
#pragma unroll
        for (int nt = 0; nt < NTW; nt++) {
            int col = (wave * NTW + nt) * 16 + r16;
#pragma unroll
            for (int r = 0; r < 4; r++) {
                int row = m0 + kq * 4 + r;
                if (row < NN) {
                    float v = acc[nt][r];
                    if constexpr (RESID) {
                        size_t ri = (size_t)row * DIN + col;
                        if constexpr (AMODE == 3)
                            v = fmaxf(v + bf2f(Ah[ri]), 0.f);
                        else
                            v = fmaxf(v + bf2f(Ah[ri]) + bf2f(Al[ri]), 0.f);
                    }
                    if constexpr (BIAS) v = fmaxf(v + bias[col], 0.f);
                    if constexpr (SCALE) v *= dinv[row];
                    size_t oi = (size_t)row * DOUT + col;
                    if constexpr (OMODE == 0) {
                        ((float*)C)[oi] = v;
                    } else if constexpr (OMODE == 1) {
                        ((u16*)C)[oi] = f2bf(v);
                    } else {
                        short h, l;
                        split_bf16(v, h, l);
                        ((u16*)C)[oi] = (u16)h;
                        ((u16*)C)[(size_t)NN * DOUT + oi] = (u16)l;
                    }
                }
            }
        }
    }
}

// ---------------- fused GEMM pair: C = ep2( ep1(A@W1') @ W2' ) ---------------
template <int DIN, int DMID, int DOUT, int MT, bool A1S, bool MIDS, bool RESID1,
          bool BIAS1, bool SCALE2, bool RESID2, int OMODE2>
__global__ __launch_bounds__(256, 3) void k_mfused(const u16* __restrict__ Ahp,
                                                   const short* __restrict__ f1h,
                                                   const short* __restrict__ f1l,
                                                   const short* __restrict__ f2h,
                                                   const short* __restrict__ f2l,
                                                   const float* __restrict__ bias1,
                                                   const float* __restrict__ dinv,
                                                   void* __restrict__ C) {
    static_assert(!RESID1 || DIN == DMID, "resid1 needs square stage1");
    static_assert(!RESID2 || DMID == DOUT, "resid2 needs square stage2");
    constexpr int KST1 = DIN / 32;
    constexpr int NTW1 = DMID / 64;
    constexpr int KST2 = DMID / 32;
    constexpr int NTW2 = DOUT / 64;
    constexpr int LDW = DMID + 8;  // u16 stride: 16B-aligned rows, 4-bank skew
    __shared__ u16 ldsh[16][LDW];
    __shared__ u16 ldsl[MIDS ? 1 : 16][LDW];

    const u16* Alp = Ahp + (size_t)NN * DIN;

    const int t = threadIdx.x;
    const int wave = t >> 6;
    const int lane = t & 63;
    const int r16 = lane & 15;
    const int kq = lane >> 4;

    short8 b1h[NTW1][KST1], b1l[NTW1][KST1];
#pragma unroll
    for (int nt = 0; nt < NTW1; nt++) {
        int ntile = wave * NTW1 + nt;
#pragma unroll
        for (int ks = 0; ks < KST1; ks++) {
            size_t o = ((size_t)(ntile * KST1 + ks) * 64 + lane) * 8;
            b1h[nt][ks] = *(const short8*)(f1h + o);
            b1l[nt][ks] = *(const short8*)(f1l + o);
        }
    }
    short8 b2h[NTW2][KST2], b2l[NTW2][KST2];
#pragma unroll
    for (int nt = 0; nt < NTW2; nt++) {
        int ntile = wave * NTW2 + nt;
#pragma unroll
        for (int ks = 0; ks < KST2; ks++) {
            size_t o = ((size_t)(ntile * KST2 + ks) * 64 + lane) * 8;
            b2h[nt][ks] = *(const short8*)(f2h + o);
            b2l[nt][ks] = *(const short8*)(f2l + o);
        }
    }

    const int m0b = blockIdx.x * (MT * 16);
#pragma unroll 1
    for (int mt = 0; mt < MT; mt++) {
        const int m0 = m0b + mt * 16;
        if (m0 >= NN) break;
        const int ra = min(m0 + r16, NN - 1);

        // ---- stage 1: acc1 = A @ W1' ----
        floatx4 acc1[NTW1];
#pragma unroll
        for (int nt = 0; nt < NTW1; nt++) acc1[nt] = (floatx4){0.f, 0.f, 0.f, 0.f};
        {
            const u16* Aph = Ahp + (size_t)ra * DIN + kq * 8;
            const u16* Apl = Alp + (size_t)ra * DIN + kq * 8;
#pragma unroll
            for (int ks = 0; ks < KST1; ks++) {
                short8 ah = *(const short8*)(Aph + ks * 32);
#pragma unroll
                for (int nt = 0; nt < NTW1; nt++) {
                    acc1[nt] = __builtin_amdgcn_mfma_f32_16x16x32_bf16(ah, b1h[nt][ks], acc1[nt], 0, 0, 0);
                    acc1[nt] = __builtin_amdgcn_mfma_f32_16x16x32_bf16(ah, b1l[nt][ks], acc1[nt], 0, 0, 0);
                }
                if constexpr (!A1S) {
                    short8 al = *(const short8*)(Apl + ks * 32);
#pragma unroll
                    for (int nt = 0; nt < NTW1; nt++)
                        acc1[nt] = __builtin_amdgcn_mfma_f32_16x16x32_bf16(al, b1h[nt][ks], acc1[nt], 0, 0, 0);
                }
            }
        }
        // ---- epilogue 1 -> LDS ----
#pragma unroll
        for (int nt = 0; nt < NTW1; nt++) {
            int col = (wave * NTW1 + nt) * 16 + r16;
#pragma unroll
            for (int r = 0; r < 4; r++) {
                int row = m0 + kq * 4 + r;
                float v = acc1[nt][r];
                if constexpr (RESID1) {
                    if (row < NN) {
                        size_t ri = (size_t)row * DIN + col;
                        if constexpr (A1S)
                            v = fmaxf(v + bf2f(Ahp[ri]), 0.f);
                        else
                            v = fmaxf(v + bf2f(Ahp[ri]) + bf2f(Alp[ri]), 0.f);
                    }
                }
                if constexpr (BIAS1) v = fmaxf(v + bias1[col], 0.f);
                if constexpr (MIDS) {
                    ldsh[kq * 4 + r][col] = f2bf(v);
                } else {
                    short h, l;
                    split_bf16(v, h, l);
                    ldsh[kq * 4 + r][col] = (u16)h;
                    ldsl[kq * 4 + r][col] = (u16)l;
                }
            }
        }
        __syncthreads();

        // ---- stage 2: acc2 = mid @ W2' (A-frags from LDS) ----
        floatx4 acc2[NTW2];
#pragma unroll
        for (int nt = 0; nt < NTW2; nt++) acc2[nt] = (floatx4){0.f, 0.f, 0.f, 0.f};
#pragma unroll
        for (int ks = 0; ks < KST2; ks++) {
            short8 ah = *(const short8*)&ldsh[r16][ks * 32 + kq * 8];
#pragma unroll
            for (int nt = 0; nt < NTW2; nt++) {
                acc2[nt] = __builtin_amdgcn_mfma_f32_16x16x32_bf16(ah, b2h[nt][ks], acc2[nt], 0, 0, 0);
                acc2[nt] = __builtin_amdgcn_mfma_f32_16x16x32_bf16(ah, b2l[nt][ks], acc2[nt], 0, 0, 0);
            }
            if constexpr (!MIDS) {
                short8 al = *(const short8*)&ldsl[r16][ks * 32 + kq * 8];
#pragma unroll
                for (int nt = 0; nt < NTW2; nt++)
                    acc2[nt] = __builtin_amdgcn_mfma_f32_16x16x32_bf16(al, b2h[nt][ks], acc2[nt], 0, 0, 0);
            }
        }

        // ---- epilogue 2 -> C ----
#pragma unroll
        for (int nt = 0; nt < NTW2; nt++) {
            int col = (wave * NTW2 + nt) * 16 + r16;
#pragma unroll
            for (int r = 0; r < 4; r++) {
                int row = m0 + kq * 4 + r;
                if (row < NN) {
                    float v = acc2[nt][r];
                    if constexpr (RESID2) {
                        if constexpr (MIDS)
                            v = fmaxf(v + bf2f(ldsh[kq * 4 + r][col]), 0.f);
                        else
                            v = fmaxf(v + bf2f(ldsh[kq * 4 + r][col]) + bf2f(ldsl[kq * 4 + r][col]), 0.f);
                    }
                    if constexpr (SCALE2) v *= dinv[row];
                    size_t oi = (size_t)row * DOUT + col;
                    if constexpr (OMODE2 == 0) {
                        ((float*)C)[oi] = v;
                    } else if constexpr (OMODE2 == 1) {
                        ((u16*)C)[oi] = f2bf(v);
                    } else {
                        short h, l;
                        split_bf16(v, h, l);
                        ((u16*)C)[oi] = (u16)h;
                        ((u16*)C)[(size_t)NN * DOUT + oi] = (u16)l;
                    }
                }
            }
        }
        __syncthreads();  // protect LDS before next mt overwrites
    }
}

// ---------------- GCN aggregation (D=128 payload / D=64 two-plane) -----------
template <int D, bool BIAS_RELU, int OPL>
__global__ __launch_bounds__(256) void k_agg(const u16* __restrict__ hs,
                                             const float* __restrict__ dinv,
                                             const int* __restrict__ row_ptr,
                                             const int* __restrict__ row_end,
                                             const int* __restrict__ csr_src,
                                             const float* __restrict__ bias,
                                             u16* __restrict__ outh) {
    u16* outl = outh + (size_t)NN * D;
    int node = blockIdx.x * 4 + (threadIdx.x >> 6);
    int lane = threadIdx.x & 63;
    if (node >= NN) return;

    if constexpr (D == 128) {
        const int off = lane * 2;
        floatx2 a = (floatx2){0.f, 0.f};
        {
            uint32_t u = ((const uint32_t*)(hs + (size_t)node * D))[lane];
            acc2v(u, a);
        }
        int e = row_ptr[node];
        const int end = row_end[node];
        for (; e + 16 <= end; e += 16) {
            int s[16];
#pragma unroll
            for (int i = 0; i < 16; i++) s[i] = csr_src[e + i];
            uint32_t v[16];
#pragma unroll
            for (int i = 0; i < 16; i++) v[i] = ((const uint32_t*)(hs + (size_t)s[i] * D))[lane];
#pragma unroll
            for (int i = 0; i < 16; i++) acc2v(v[i], a);
        }
        for (; e + 8 <= end; e += 8) {
            int s[8];
#pragma unroll
            for (int i = 0; i < 8; i++) s[i] = csr_src[e + i];
            uint32_t v[8];
#pragma unroll
            for (int i = 0; i < 8; i++) v[i] = ((const uint32_t*)(hs + (size_t)s[i] * D))[lane];
#pragma unroll
            for (int i = 0; i < 8; i++) acc2v(v[i], a);
        }
        for (; e + 4 <= end; e += 4) {
            int s[4];
#pragma unroll
            for (int i = 0; i < 4; i++) s[i] = csr_src[e + i];
            uint32_t v[4];
#pragma unroll
            for (int i = 0; i < 4; i++) v[i] = ((const uint32_t*)(hs + (size_t)s[i] * D))[lane];
#pragma unroll
            for (int i = 0; i < 4; i++) acc2v(v[i], a);
        }
        for (; e < end; e++) {
            int s = csr_src[e];
            uint32_t u = ((const uint32_t*)(hs + (size_t)s * D))[lane];
            acc2v(u, a);
        }
        const float di = dinv[node];
        float a0 = a[0] * di, a1 = a[1] * di;
        if constexpr (BIAS_RELU) {
            a0 = fmaxf(a0 + bias[off], 0.f);
            a1 = fmaxf(a1 + bias[off + 1], 0.f);
        }
        if constexpr (OPL == 1) {
            *(u32*)(outh + (size_t)node * D + off) = cvtpk_bf16(a0, a1);
        } else {
            u32 wh, wl;
            split_pair(a0, a1, wh, wl);
            *(u32*)(outh + (size_t)node * D + off) = wh;
            *(u32*)(outl + (size_t)node * D + off) = wl;
        }
    } else {
        // D == 64: halves handle alternating edges; lane owns ch {2*l32, 2*l32+1}
        const int half = lane >> 5;
        const int l32 = lane & 31;
        floatx2 a = (floatx2){0.f, 0.f};
        if (half == 0) {
            uint32_t u = ((const uint32_t*)(hs + (size_t)node * D))[l32];
            acc2v(u, a);
        }
        int e = row_ptr[node];
        const int end = row_end[node];
        for (; e + 16 <= end; e += 16) {
            int s[8];
#pragma unroll
            for (int i = 0; i < 8; i++) s[i] = csr_src[e + half + 2 * i];
            uint32_t v[8];
#pragma unroll
            for (int i = 0; i < 8; i++) v[i] = ((const uint32_t*)(hs + (size_t)s[i] * D))[l32];
#pragma unroll
            for (int i = 0; i < 8; i++) acc2v(v[i], a);
        }
        for (; e + 8 <= end; e += 8) {
            int s[4];
#pragma unroll
            for (int i = 0; i < 4; i++) s[i] = csr_src[e + half + 2 * i];
            uint32_t v[4];
#pragma unroll
            for (int i = 0; i < 4; i++) v[i] = ((const uint32_t*)(hs + (size_t)s[i] * D))[l32];
#pragma unroll
            for (int i = 0; i < 4; i++) acc2v(v[i], a);
        }
        for (; e + 2 <= end; e += 2) {
            int s = csr_src[e + half];
            uint32_t u = ((const uint32_t*)(hs + (size_t)s * D))[l32];
            acc2v(u, a);
        }
        if (e < end && half == 0) {
            int s = csr_src[e];
            uint32_t u = ((const uint32_t*)(hs + (size_t)s * D))[l32];
            acc2v(u, a);
        }
        float a0 = a[0], a1 = a[1];
        a0 += __shfl_xor(a0, 32, 64);
        a1 += __shfl_xor(a1, 32, 64);
        if (half == 0) {
            const int off = l32 * 2;
            const float di = dinv[node];
            a0 *= di;
            a1 *= di;
            if constexpr (BIAS_RELU) {
                a0 = fmaxf(a0 + bias[off], 0.f);
                a1 = fmaxf(a1 + bias[off + 1], 0.f);
            }
            if constexpr (OPL == 1) {
                *(u32*)(outh + (size_t)node * D + off) = cvtpk_bf16(a0, a1);
            } else {
                u32 wh, wl;
                split_pair(a0, a1, wh, wl);
                *(u32*)(outh + (size_t)node * D + off) = wh;
                *(u32*)(outl + (size_t)node * D + off) = wl;
            }
        }
    }
}

// ---------------- agg2 + fc4 fused: p3 = bf16(dinv*relu(z2 + z2@W4^T)) -------
// z2 = relu(dinv*agg(h2)+b3) computed by gather, staged as bf16 in a 16x64 LDS
// tile (rows 4-15 garbage, discarded), then each wave runs 4 MFMAs against the
// prepped fc4 B-fragments for its 16-col slice. Arithmetic path is bit-identical
// to the standalone fc4 kernel (bf16 z2 A-frags + 2-plane W4 + bf16 resid).
static __global__ __launch_bounds__(256) void k_agg2f(const u16* __restrict__ hs,
                                                      const float* __restrict__ dinv,
                                                      const int* __restrict__ row_ptr,
                                                      const int* __restrict__ row_end,
                                                      const int* __restrict__ csr_src,
                                                      const float* __restrict__ bias,
                                                      const short* __restrict__ f4h,
                                                      const short* __restrict__ f4l,
                                                      u16* __restrict__ outp) {
    __shared__ u16 z2s[16][72];  // row stride 144B: 16B-aligned, 2-way banks (free)
    const int t = threadIdx.x;
    const int wave = t >> 6;
    const int lane = t & 63;
    const int r16 = lane & 15;
    const int kq = lane >> 4;
    const int node = blockIdx.x * 4 + wave;

    // fc4 B-fragments for this wave's 16-col slice (already in MFMA layout)
    short8 b4h[2], b4l[2];
#pragma unroll
    for (int ks = 0; ks < 2; ks++) {
        size_t o = ((size_t)(wave * 2 + ks) * 64 + lane) * 8;
        b4h[ks] = *(const short8*)(f4h + o);
        b4l[ks] = *(const short8*)(f4l + o);
    }

    // ---- gather z2 ----
    const int half = lane >> 5;
    const int l32 = lane & 31;
    floatx2 a = (floatx2){0.f, 0.f};
    if (node < NN) {
        if (half == 0) {
            uint32_t u = ((const uint32_t*)(hs + (size_t)node * 64))[l32];
            acc2v(u, a);
        }
        int e = row_ptr[node];
        const int end = row_end[node];
        for (; e + 16 <= end; e += 16) {
            int s[8];
#pragma unroll
            for (int i = 0; i < 8; i++) s[i] = csr_src[e + half + 2 * i];
            uint32_t v[8];
#pragma unroll
            for (int i = 0; i < 8; i++) v[i] = ((const uint32_t*)(hs + (size_t)s[i] * 64))[l32];
#pragma unroll
            for (int i = 0; i < 8; i++) acc2v(v[i], a);
        }
        for (; e + 8 <= end; e += 8) {
            int s[4];
#pragma unroll
            for (int i = 0; i < 4; i++) s[i] = csr_src[e + half + 2 * i];
            uint32_t v[4];
#pragma unroll
            for (int i = 0; i < 4; i++) v[i] = ((const uint32_t*)(hs + (size_t)s[i] * 64))[l32];
#pragma unroll
            for (int i = 0; i < 4; i++) acc2v(v[i], a);
        }
        for (; e + 2 <= end; e += 2) {
            int s = csr_src[e + half];
            uint32_t u = ((const uint32_t*)(hs + (size_t)s * 64))[l32];
            acc2v(u, a);
        }
        if (e < end && half == 0) {
            int s = csr_src[e];
            uint32_t u = ((const uint32_t*)(hs + (size_t)s * 64))[l32];
            acc2v(u, a);
        }
    }
    float a0 = a[0], a1 = a[1];
    a0 += __shfl_xor(a0, 32, 64);
    a1 += __shfl_xor(a1, 32, 64);
    if (node < NN && half == 0) {
        const int off = l32 * 2;
        const float di = dinv[node];
        a0 = fmaxf(a0 * di + bias[off], 0.f);
        a1 = fmaxf(a1 * di + bias[off + 1], 0.f);
        *(u32*)&z2s[wave][off] = cvtpk_bf16(a0, a1);
    }
    __syncthreads();

    // ---- fc4 mini-MFMA: rows 0-3 valid, rows 4-15 garbage (discarded) ----
    floatx4 acc = (floatx4){0.f, 0.f, 0.f, 0.f};
#pragma unroll
    for (int ks = 0; ks < 2; ks++) {
        short8 ah = *(const short8*)&z2s[r16][kq * 8 + ks * 32];
        acc = __builtin_amdgcn_mfma_f32_16x16x32_bf16(ah, b4h[ks], acc, 0, 0, 0);
        acc = __builtin_amdgcn_mfma_f32_16x16x32_bf16(ah, b4l[ks], acc, 0, 0, 0);
    }
    if (kq == 0) {
        const int col = wave * 16 + r16;
#pragma unroll
        for (int r = 0; r < 4; r++) {
            int nr = blockIdx.x * 4 + r;
            if (nr < NN) {
                float v = fmaxf(acc[r] + bf2f(z2s[r][col]), 0.f) * dinv[nr];
                outp[(size_t)nr * 64 + col] = f2bf(v);
            }
        }
    }
}

// ---------------- launch ----------------

extern "C" void kernel_launch(void* const* d_in, const int* in_sizes, int n_in,
                              void* d_out, int out_size, void* d_ws, size_t ws_size,
                              hipStream_t stream) {
    const float* x   = (const float*)d_in[0];
    const int*   ei  = (const int*)d_in[1];
    const float* g1w = (const float*)d_in[2];
    const float* g1b = (const float*)d_in[3];
    const float* f2w = (const float*)d_in[4];
    const float* g3w = (const float*)d_in[5];
    const float* g3b = (const float*)d_in[6];
    const float* f4w = (const float*)d_in[7];
    const float* g5w = (const float*)d_in[8];
    const float* g5b = (const float*)d_in[9];
    const float* f6w = (const float*)d_in[10];
    float* out = (float*)d_out;

    const int* src = ei;       // edge_index[0]
    const int* dst = ei + NE;  // edge_index[1]

    char* p = (char*)d_ws;
    auto alloc = [&](size_t bytes) -> void* {
        void* r = (void*)p;
        p += (bytes + 255) & ~(size_t)255;
        return r;
    };
    float* dinv    = (float*)alloc(NN * 4);
    int*   row_ptr = (int*)alloc(NN * 4);
    int*   row_end = (int*)alloc(NN * 4);
    int*   gcur    = (int*)alloc((NBB + 1) * 4);
    int*   csr     = (int*)alloc((size_t)NBB * BSTRIDE * 4);  // fixed-stride CSR (8 MB)
    short* wfh     = (short*)alloc(69632 * 2);
    short* wfl     = (short*)alloc(69632 * 2);
    // bufA/bufB: 4B/elem budget = room for hi+lo u16 planes at D=128
    char* bufA = (char*)alloc((size_t)NN * 128 * 4);
    char* bufB = (char*)alloc((size_t)NN * 128 * 4);
    // fixed-stride edge staging (391*5120*8B = 16.0 MB) aliases bufB: fully
    // consumed by k_bprep before agg1 writes bufB (stream-ordered).
    int2* staging  = (int2*)bufB;

    const int gE4 = (NE + 4095) / 4096;      // 391
    const int gA  = NN / 4;                  // 25000
    const int gM  = (NN + 31) / 32;          // 3125 (MT=2: 32 rows/block, exact)

    // zero bucket counters (graph-capture-safe async memset)
    hipMemsetAsync(gcur, 0, (NBB + 1) * 4, stream);

    // scatter + weight prep (merged; blocks 0-8 also run wprep)
    {
        ScatArgs sa;
        sa.src = src;
        sa.dst = dst;
        sa.gcur = gcur;
        sa.staging = staging;
        int  eoff[6] = {0, 16384, 32768, 40960, 45056, 53248};
        int  base[6] = {0, 2048, 4096, 5120, 5632, 6656};
        int  tot[6]  = {2048, 2048, 1024, 512, 1024, 2048};
        const float* Ws[6] = {g1w, f2w, g3w, f4w, g5w, f6w};
        int din[6]  = {128, 128, 128, 64, 64, 128};
        int dout[6] = {128, 128, 64, 64, 128, 128};
        int trb[6]  = {0, 1, 0, 1, 0, 1};
        for (int i = 0; i < 6; i++) {
            sa.wp.d[i] = WDesc{Ws[i], wfh + eoff[i], wfl + eoff[i],
                               din[i], dout[i], trb[i], base[i], tot[i]};
        }
        k_bscatterF<<<gE4, 1024, 0, stream>>>(sa);
    }

    // per-bucket count + scan + dinv + CSR fill (merged)
    k_bprep<<<NBB, 1024, 0, stream>>>(staging, gcur, dinv, row_ptr, row_end, csr);

    // G1: h1 = bf16(dinv * (x@W1))           [fp32 in via hw cvt_pk, payload out]
    k_mgemm<128, 128, 2, 1, 1, false, false, true><<<gM, 256, 0, stream>>>(
        x, wfh + 0, wfl + 0, nullptr, dinv, bufA);
    // agg1: z1 = relu(dinv*agg(h1)+b1)       [single-plane out]
    k_agg<128, true, 1><<<gA, 256, 0, stream>>>((const u16*)bufA, dinv, row_ptr, row_end, csr, g1b, (u16*)bufB);
    // fused fc2+G3: z1' = relu(z1 + z1@W2^T); h2 = bf16(dinv*(z1'@W3))
    k_mfused<128, 128, 64, 2, true, true, true, false, true, false, 1><<<gM, 256, 0, stream>>>(
        (const u16*)bufB, wfh + 16384, wfl + 16384, wfh + 32768, wfl + 32768,
        nullptr, dinv, bufA);
    // agg2+fc4 fused: p3 = bf16(dinv*relu(z2 + z2@W4^T)), z2 = relu(dinv*agg(h2)+b3)
    k_agg2f<<<gA, 256, 0, stream>>>((const u16*)bufA, dinv, row_ptr, row_end, csr,
                                    g3b, wfh + 40960, wfl + 40960, (u16*)bufB);
    // agg3: a3 = agg(p3)                     [two-plane out: near-output precision]
    k_agg<64, false, 2><<<gA, 256, 0, stream>>>((const u16*)bufB, dinv, row_ptr, row_end, csr, nullptr, (u16*)bufA);
    // fused G5+fc6: z3 = relu(a3@W5+b5); out = relu(z3 + z3@W6^T)  [fp32 out]
    k_mfused<64, 128, 128, 2, false, false, false, true, false, true, 0><<<gM, 256, 0, stream>>>(
        (const u16*)bufA, wfh + 45056, wfl + 45056, wfh + 53248, wfl + 53248,
        g5b, nullptr, out);
}